// Round 1
// baseline (7558.755 us; speedup 1.0000x reference)
//
#include <hip/hip_runtime.h>
#include <math.h>

#define C_RES 0.89442719f
#define C_NEW 0.4472f
#define LN_EPS 1e-5f
#define BESSEL_PREF 0.6324555320336759f  // sqrt(2/5)
#define RC_INV 0.2f

__device__ __forceinline__ float fast_tanh(float x) {
  float ax = fabsf(x);
  float e = __expf(2.0f * ax);
  float t = 1.0f - 2.0f / (e + 1.0f);
  return copysignf(t, x);
}

__device__ __forceinline__ float poly_cutoff(float x) {
  float xr = x * RC_INV;
  if (xr >= 1.0f) return 0.0f;
  float x2 = xr * xr;
  float x3 = x2 * xr;
  float x6 = x3 * x3;
  return 1.0f - 28.0f * x6 + 48.0f * x6 * xr - 21.0f * x6 * x2;
}

__global__ void zero_kernel(float* __restrict__ p, size_t n) {
  size_t i = (size_t)blockIdx.x * blockDim.x + threadIdx.x;
  size_t stride = (size_t)gridDim.x * blockDim.x;
  for (; i < n; i += stride) p[i] = 0.0f;
}

// ---------------- stage-A: features + sr/rd MLPs + LN + msg scatter ----------
// 32 rows per block, 256 threads.

#define STAGE_W(SRC, NF) do {                                                   \
    __syncthreads();                                                            \
    for (int i_ = tid; i_ < (NF); i_ += 256) wbuf[i_] = (SRC)[i_];              \
    __syncthreads();                                                            \
  } while (0)

#define MM_2x4(SRCARR, KDIM, WSTR, BIASP, DOTANH, DSTARR) do {                  \
    const int r0_ = (tid >> 4) * 2, j0_ = (tid & 15) * 4;                       \
    float a00 = (BIASP)[j0_],   a01 = (BIASP)[j0_+1];                           \
    float a02 = (BIASP)[j0_+2], a03 = (BIASP)[j0_+3];                           \
    float a10 = a00, a11 = a01, a12 = a02, a13 = a03;                           \
    for (int k_ = 0; k_ < (KDIM); ++k_) {                                       \
      const float s0_ = SRCARR[r0_][k_], s1_ = SRCARR[r0_+1][k_];               \
      const float4 w_ = *(const float4*)&wbuf[k_*(WSTR) + j0_];                 \
      a00 += s0_*w_.x; a01 += s0_*w_.y; a02 += s0_*w_.z; a03 += s0_*w_.w;       \
      a10 += s1_*w_.x; a11 += s1_*w_.y; a12 += s1_*w_.z; a13 += s1_*w_.w;       \
    }                                                                           \
    if (DOTANH) {                                                               \
      a00 = fast_tanh(a00); a01 = fast_tanh(a01);                               \
      a02 = fast_tanh(a02); a03 = fast_tanh(a03);                               \
      a10 = fast_tanh(a10); a11 = fast_tanh(a11);                               \
      a12 = fast_tanh(a12); a13 = fast_tanh(a13);                               \
    }                                                                           \
    DSTARR[r0_][j0_]   = a00; DSTARR[r0_][j0_+1]   = a01;                       \
    DSTARR[r0_][j0_+2] = a02; DSTARR[r0_][j0_+3]   = a03;                       \
    DSTARR[r0_+1][j0_]   = a10; DSTARR[r0_+1][j0_+1] = a11;                     \
    DSTARR[r0_+1][j0_+2] = a12; DSTARR[r0_+1][j0_+3] = a13;                     \
  } while (0)

template<int HAS_SR>
__launch_bounds__(256)
__global__ void feat_mlp_kernel(
    int nrows,
    const int* __restrict__ types, const float* __restrict__ lens,
    const float* __restrict__ vecs, const int* __restrict__ idx,
    const float* __restrict__ bessel_w,
    const float* __restrict__ srW1, const float* __restrict__ srb1,
    const float* __restrict__ srW2, const float* __restrict__ srb2,
    const float* __restrict__ srW3, const float* __restrict__ srb3,
    const float* __restrict__ rdW1, const float* __restrict__ rdb1,
    const float* __restrict__ rdW2, const float* __restrict__ rdb2,
    const float* __restrict__ rdW3, const float* __restrict__ rdb3,
    const float* __restrict__ eln_g, const float* __restrict__ eln_b,
    float* __restrict__ radial_out, float* __restrict__ ud_out,
    float* __restrict__ aggS, float* __restrict__ cnt)
{
  __shared__ float feat[32][25];
  __shared__ float bufA[32][65];
  __shared__ float bufB[32][65];
  __shared__ __align__(16) float wbuf[4096];
  __shared__ float sval[32][17];
  __shared__ float evud[32][3];
  __shared__ float udl[32];
  __shared__ int   i1l[32];
  __shared__ float rstat[32][2];

  const int tid = threadIdx.x;
  const int base = blockIdx.x * 32;

  if (tid < 32) {
    const int r = tid;
    const int row = base + r;
    const bool valid = row < nrows;
    float len = 1.0f, ud = 0.0f;
    int i0 = 0, i1 = 0;
    if (valid) {
      i0 = idx[row];
      i1 = idx[nrows + row];
      len = lens[row];
      ud = poly_cutoff(len);
    }
    const int t0 = valid ? types[i0] : -1;
    const int t1 = valid ? types[i1] : -1;
    #pragma unroll
    for (int a = 0; a < 4; ++a) {
      feat[r][a]     = (t0 == a) ? 1.0f : 0.0f;
      feat[r][4 + a] = (t1 == a) ? 1.0f : 0.0f;
    }
    const float invl = 1.0f / len;
    #pragma unroll
    for (int k = 0; k < 16; ++k) {
      feat[r][8 + k] = valid ? ud * BESSEL_PREF * sinf(bessel_w[k] * len * RC_INV) * invl : 0.0f;
    }
    udl[r] = ud;
    i1l[r] = i1;
    if (valid) {
      ud_out[row] = ud;
      if (HAS_SR) {
        evud[r][0] = ud * vecs[(size_t)row*3 + 0];
        evud[r][1] = ud * vecs[(size_t)row*3 + 1];
        evud[r][2] = ud * vecs[(size_t)row*3 + 2];
        atomicAdd(&cnt[i1], 1.0f);
      }
    }
  }

  if (HAS_SR) {
    STAGE_W(srW1, 24*64);
    MM_2x4(feat, 24, 64, srb1, true, bufA);
    STAGE_W(srW2, 64*64);
    MM_2x4(bufA, 64, 64, srb2, true, bufB);
    STAGE_W(srW3, 64*16);
    {
      const int r = tid & 31;
      const int j = (tid >> 5) * 2;
      float a0 = srb3[j], a1 = srb3[j + 1];
      for (int k = 0; k < 64; ++k) {
        const float v = bufB[r][k];
        a0 += v * wbuf[k*16 + j];
        a1 += v * wbuf[k*16 + j + 1];
      }
      const float u = udl[r];
      sval[r][j]   = a0 * u;
      sval[r][j+1] = a1 * u;
    }
  }

  STAGE_W(rdW1, 24*64);
  MM_2x4(feat, 24, 64, rdb1, true, bufA);
  STAGE_W(rdW2, 64*64);
  MM_2x4(bufA, 64, 64, rdb2, true, bufB);
  STAGE_W(rdW3, 64*64);
  MM_2x4(bufB, 64, 64, rdb3, false, bufA);
  __syncthreads();
  if (tid < 32) {
    float s = 0.0f, ss = 0.0f;
    for (int k = 0; k < 64; ++k) { const float v = bufA[tid][k]; s += v; ss += v*v; }
    const float m = s * (1.0f/64.0f);
    const float var = ss * (1.0f/64.0f) - m*m;
    rstat[tid][0] = m;
    rstat[tid][1] = rsqrtf(var + LN_EPS);
  }
  __syncthreads();
  {
    const int r0 = (tid >> 4) * 2, j0 = (tid & 15) * 4;
    #pragma unroll
    for (int i = 0; i < 2; ++i) {
      const int r = r0 + i, row = base + r;
      if (row < nrows) {
        const float m = rstat[r][0], inv = rstat[r][1], u = udl[r];
        float4 v;
        v.x = ((bufA[r][j0]   - m)*inv*eln_g[j0]   + eln_b[j0])   * u;
        v.y = ((bufA[r][j0+1] - m)*inv*eln_g[j0+1] + eln_b[j0+1]) * u;
        v.z = ((bufA[r][j0+2] - m)*inv*eln_g[j0+2] + eln_b[j0+2]) * u;
        v.w = ((bufA[r][j0+3] - m)*inv*eln_g[j0+3] + eln_b[j0+3]) * u;
        *(float4*)&radial_out[(size_t)row*64 + j0] = v;
      }
    }
  }
  if (HAS_SR) {
    const int r = tid >> 3, q = tid & 7;
    const int row = base + r;
    if (row < nrows) {
      const size_t bo = (size_t)i1l[r] * 48;
      #pragma unroll
      for (int m6 = 0; m6 < 6; ++m6) {
        const int id = q*6 + m6;
        const int d = id / 3, c = id - d*3;
        atomicAdd(&aggS[bo + id], sval[r][d] * evud[r][c]);
      }
    }
  }
}

// ---------------- node embedding (gram + LN) ---------------------------------

__device__ __forceinline__ void block128_stats(float x, float& m, float& inv, float* red) {
  float s = x, ss = x*x;
  #pragma unroll
  for (int o = 32; o; o >>= 1) { s += __shfl_down(s, o); ss += __shfl_down(ss, o); }
  const int t = threadIdx.x;
  if ((t & 63) == 0) { red[(t >> 6)*2] = s; red[(t >> 6)*2 + 1] = ss; }
  __syncthreads();
  const float S = red[0] + red[2], SS = red[1] + red[3];
  m = S * (1.0f/128.0f);
  const float var = SS * (1.0f/128.0f) - m*m;
  inv = rsqrtf(var + LN_EPS);
}

__launch_bounds__(128)
__global__ void node_emb_kernel(int N, const float* __restrict__ aggS,
                                const float* __restrict__ cnt,
                                const float* __restrict__ g, const float* __restrict__ b,
                                float* __restrict__ node_emb)
{
  const int n = blockIdx.x, t = threadIdx.x;
  __shared__ float S[48];
  __shared__ float red[4];
  if (t < 48) S[t] = aggS[(size_t)n*48 + t];
  __syncthreads();
  const float ic = 1.0f / fmaxf(cnt[n], 1.0f);
  const int d = t >> 3, e = t & 7;
  const float x = (S[d*3+0]*S[e*3+0] + S[d*3+1]*S[e*3+1] + S[d*3+2]*S[e*3+2]) * ic * ic;
  float m, inv;
  block128_stats(x, m, inv, red);
  node_emb[(size_t)n*128 + t] = (x - m)*inv*g[t] + b[t];
}

__launch_bounds__(128)
__global__ void node_update_kernel(int N, const float* __restrict__ aggsum,
                                   const float* __restrict__ cnt,
                                   const float* __restrict__ g, const float* __restrict__ b,
                                   float* __restrict__ node_emb)
{
  const int n = blockIdx.x, t = threadIdx.x;
  __shared__ float red[4];
  const float old = node_emb[(size_t)n*128 + t];
  const float x = old * (aggsum[(size_t)n*128 + t] / fmaxf(cnt[n], 1.0f));
  float m, inv;
  block128_stats(x, m, inv, red);
  node_emb[(size_t)n*128 + t] = C_RES*old + C_NEW*((x - m)*inv*g[t] + b[t]);
}

// ---------------- embedding GEMM (K=64 -> N=128), two epilogues --------------
// MODE 0: out = (radial@W + b) * 0.5*(ne[i0]+ne[i1])   (hidden init)
// MODE 1: atomicAdd(out[i1][:], radial@W + b)          (layer aggregation)

template<int MODE>
__launch_bounds__(256)
__global__ void emb_gemm_kernel(
    int nrows,
    const float* __restrict__ radial,
    const float* __restrict__ W, const float* __restrict__ bias,
    const int* __restrict__ idx,
    const float* __restrict__ node_emb,
    float* __restrict__ out)
{
  __shared__ float lin[32][65];
  __shared__ __align__(16) float lw[64*128];
  const int tid = threadIdx.x;
  const int base = blockIdx.x * 32;

  for (int i = tid; i < 64*128; i += 256) lw[i] = W[i];
  {
    const int rr0 = tid >> 6, k = tid & 63;
    for (int rr = rr0; rr < 32; rr += 4) {
      const int row = base + rr;
      lin[rr][k] = (row < nrows) ? radial[(size_t)row*64 + k] : 0.0f;
    }
  }
  __syncthreads();

  const int r0 = (tid >> 5) * 4, j0 = (tid & 31) * 4;
  float acc[4][4];
  #pragma unroll
  for (int j = 0; j < 4; ++j) {
    const float bj = bias[j0 + j];
    acc[0][j] = bj; acc[1][j] = bj; acc[2][j] = bj; acc[3][j] = bj;
  }
  for (int k = 0; k < 64; ++k) {
    const float4 w = *(const float4*)&lw[k*128 + j0];
    const float s0 = lin[r0][k],   s1 = lin[r0+1][k];
    const float s2 = lin[r0+2][k], s3 = lin[r0+3][k];
    acc[0][0] += s0*w.x; acc[0][1] += s0*w.y; acc[0][2] += s0*w.z; acc[0][3] += s0*w.w;
    acc[1][0] += s1*w.x; acc[1][1] += s1*w.y; acc[1][2] += s1*w.z; acc[1][3] += s1*w.w;
    acc[2][0] += s2*w.x; acc[2][1] += s2*w.y; acc[2][2] += s2*w.z; acc[2][3] += s2*w.w;
    acc[3][0] += s3*w.x; acc[3][1] += s3*w.y; acc[3][2] += s3*w.z; acc[3][3] += s3*w.w;
  }
  #pragma unroll
  for (int i = 0; i < 4; ++i) {
    const int row = base + r0 + i;
    if (row >= nrows) continue;
    if (MODE == 0) {
      const int i0 = idx[row], i1 = idx[nrows + row];
      const float4 n0 = *(const float4*)&node_emb[(size_t)i0*128 + j0];
      const float4 n1 = *(const float4*)&node_emb[(size_t)i1*128 + j0];
      float4 o;
      o.x = acc[i][0] * 0.5f * (n0.x + n1.x);
      o.y = acc[i][1] * 0.5f * (n0.y + n1.y);
      o.z = acc[i][2] * 0.5f * (n0.z + n1.z);
      o.w = acc[i][3] * 0.5f * (n0.w + n1.w);
      *(float4*)&out[(size_t)row*128 + j0] = o;
    } else {
      const int i1 = idx[nrows + row];
      float* p = &out[(size_t)i1*128 + j0];
      atomicAdd(p + 0, acc[i][0]);
      atomicAdd(p + 1, acc[i][1]);
      atomicAdd(p + 2, acc[i][2]);
      atomicAdd(p + 3, acc[i][3]);
    }
  }
}

// ---------------- hidden MLP: [256->128 tanh][128->128 tanh][128->128] -------

#define HID_FMA(SRCARR, KGLOB, KLOC) do {                                       \
    const float4 w_ = *(const float4*)&lw[(KLOC)*128 + j0];                     \
    const float s0_ = SRCARR[r0][KGLOB],   s1_ = SRCARR[r0+1][KGLOB];           \
    const float s2_ = SRCARR[r0+2][KGLOB], s3_ = SRCARR[r0+3][KGLOB];           \
    acc[0][0] += s0_*w_.x; acc[0][1] += s0_*w_.y; acc[0][2] += s0_*w_.z; acc[0][3] += s0_*w_.w; \
    acc[1][0] += s1_*w_.x; acc[1][1] += s1_*w_.y; acc[1][2] += s1_*w_.z; acc[1][3] += s1_*w_.w; \
    acc[2][0] += s2_*w_.x; acc[2][1] += s2_*w_.y; acc[2][2] += s2_*w_.z; acc[2][3] += s2_*w_.w; \
    acc[3][0] += s3_*w_.x; acc[3][1] += s3_*w_.y; acc[3][2] += s3_*w_.z; acc[3][3] += s3_*w_.w; \
  } while (0)

__launch_bounds__(256)
__global__ void hid_mlp_kernel(
    int nrows, const int* __restrict__ idx0,
    const float* __restrict__ node_emb,
    const float* __restrict__ W1, const float* __restrict__ b1,
    const float* __restrict__ W2, const float* __restrict__ b2,
    const float* __restrict__ W3, const float* __restrict__ b3,
    float* __restrict__ hidden)
{
  __shared__ float lin[32][257];
  __shared__ float lh[32][129];
  __shared__ __align__(16) float lw[32*128];
  const int tid = threadIdx.x;
  const int base = blockIdx.x * 32;

  for (int rr = 0; rr < 32; ++rr) {
    const int row = base + rr;
    float v = 0.0f;
    if (row < nrows) {
      if (tid < 128) {
        const int i0 = idx0[row];
        v = node_emb[(size_t)i0*128 + tid];
      } else {
        v = hidden[(size_t)row*128 + (tid - 128)];
      }
    }
    lin[rr][tid] = v;
  }

  const int r0 = (tid >> 5) * 4, j0 = (tid & 31) * 4;
  float acc[4][4];

  // layer 1 (K=256)
  #pragma unroll
  for (int j = 0; j < 4; ++j) {
    const float bj = b1[j0 + j];
    acc[0][j] = bj; acc[1][j] = bj; acc[2][j] = bj; acc[3][j] = bj;
  }
  for (int kc = 0; kc < 8; ++kc) {
    __syncthreads();
    for (int i = tid; i < 4096; i += 256) lw[i] = W1[kc*4096 + i];
    __syncthreads();
    #pragma unroll
    for (int kk = 0; kk < 32; ++kk) {
      const int k = kc*32 + kk;
      HID_FMA(lin, k, kk);
    }
  }
  #pragma unroll
  for (int i = 0; i < 4; ++i) {
    lh[r0+i][j0+0] = fast_tanh(acc[i][0]);
    lh[r0+i][j0+1] = fast_tanh(acc[i][1]);
    lh[r0+i][j0+2] = fast_tanh(acc[i][2]);
    lh[r0+i][j0+3] = fast_tanh(acc[i][3]);
  }

  // layer 2 (K=128)
  #pragma unroll
  for (int j = 0; j < 4; ++j) {
    const float bj = b2[j0 + j];
    acc[0][j] = bj; acc[1][j] = bj; acc[2][j] = bj; acc[3][j] = bj;
  }
  for (int kc = 0; kc < 4; ++kc) {
    __syncthreads();
    for (int i = tid; i < 4096; i += 256) lw[i] = W2[kc*4096 + i];
    __syncthreads();
    #pragma unroll
    for (int kk = 0; kk < 32; ++kk) {
      const int k = kc*32 + kk;
      HID_FMA(lh, k, kk);
    }
  }
  #pragma unroll
  for (int i = 0; i < 4; ++i) {
    lin[r0+i][j0+0] = fast_tanh(acc[i][0]);
    lin[r0+i][j0+1] = fast_tanh(acc[i][1]);
    lin[r0+i][j0+2] = fast_tanh(acc[i][2]);
    lin[r0+i][j0+3] = fast_tanh(acc[i][3]);
  }

  // layer 3 (K=128)
  #pragma unroll
  for (int j = 0; j < 4; ++j) {
    const float bj = b3[j0 + j];
    acc[0][j] = bj; acc[1][j] = bj; acc[2][j] = bj; acc[3][j] = bj;
  }
  for (int kc = 0; kc < 4; ++kc) {
    __syncthreads();
    for (int i = tid; i < 4096; i += 256) lw[i] = W3[kc*4096 + i];
    __syncthreads();
    #pragma unroll
    for (int kk = 0; kk < 32; ++kk) {
      const int k = kc*32 + kk;
      HID_FMA(lin, k, kk);
    }
  }
  #pragma unroll
  for (int i = 0; i < 4; ++i) {
    const int row = base + r0 + i;
    if (row < nrows) {
      float4 o;
      o.x = acc[i][0]; o.y = acc[i][1]; o.z = acc[i][2]; o.w = acc[i][3];
      *(float4*)&hidden[(size_t)row*128 + j0] = o;
    }
  }
}

// ---------------- radial ResNet + LN + residual-scale epilogue ---------------

#define RDL_FMA(SRCARR, KGLOB, KLOC, ACC) do {                                  \
    const float4 w_ = *(const float4*)&lw[(KLOC)*64 + j0];                      \
    const float s0_ = SRCARR[r0][KGLOB], s1_ = SRCARR[r0+1][KGLOB];             \
    ACC[0][0] += s0_*w_.x; ACC[0][1] += s0_*w_.y; ACC[0][2] += s0_*w_.z; ACC[0][3] += s0_*w_.w; \
    ACC[1][0] += s1_*w_.x; ACC[1][1] += s1_*w_.y; ACC[1][2] += s1_*w_.z; ACC[1][3] += s1_*w_.w; \
  } while (0)

__launch_bounds__(256)
__global__ void rdl_kernel(
    int nrows,
    const float* __restrict__ hidden, const float* __restrict__ ud,
    const float* __restrict__ W1, const float* __restrict__ b1,
    const float* __restrict__ W2, const float* __restrict__ b2,
    const float* __restrict__ W3, const float* __restrict__ b3,
    const float* __restrict__ eln_g, const float* __restrict__ eln_b,
    float* __restrict__ radial)
{
  __shared__ float lin[32][193];
  __shared__ float lh[32][65];
  __shared__ __align__(16) float lw[32*64];
  __shared__ float rstat[32][2];
  const int tid = threadIdx.x;
  const int base = blockIdx.x * 32;

  for (int rr = 0; rr < 32; ++rr) {
    const int row = base + rr;
    if (tid < 192) {
      float v = 0.0f;
      if (row < nrows) v = (tid < 64) ? radial[(size_t)row*64 + tid]
                                      : hidden[(size_t)row*128 + (tid - 64)];
      lin[rr][tid] = v;
    }
  }

  const int r0 = (tid >> 4) * 2, j0 = (tid & 15) * 4;
  float acc[2][4];
  float h[2][4];

  // layer 1 (K=192), tanh
  #pragma unroll
  for (int j = 0; j < 4; ++j) { const float bj = b1[j0+j]; acc[0][j] = bj; acc[1][j] = bj; }
  for (int kc = 0; kc < 6; ++kc) {
    __syncthreads();
    for (int i = tid; i < 2048; i += 256) lw[i] = W1[kc*2048 + i];
    __syncthreads();
    #pragma unroll
    for (int kk = 0; kk < 32; ++kk) {
      const int k = kc*32 + kk;
      RDL_FMA(lin, k, kk, acc);
    }
  }
  #pragma unroll
  for (int i = 0; i < 2; ++i) {
    lh[r0+i][j0+0] = fast_tanh(acc[i][0]);
    lh[r0+i][j0+1] = fast_tanh(acc[i][1]);
    lh[r0+i][j0+2] = fast_tanh(acc[i][2]);
    lh[r0+i][j0+3] = fast_tanh(acc[i][3]);
  }

  // layer 2 (K=64), no tanh -> h kept in regs (residual)
  #pragma unroll
  for (int j = 0; j < 4; ++j) { const float bj = b2[j0+j]; h[0][j] = bj; h[1][j] = bj; }
  for (int kc = 0; kc < 2; ++kc) {
    __syncthreads();
    for (int i = tid; i < 2048; i += 256) lw[i] = W2[kc*2048 + i];
    __syncthreads();
    #pragma unroll
    for (int kk = 0; kk < 32; ++kk) {
      const int k = kc*32 + kk;
      RDL_FMA(lh, k, kk, h);
    }
  }
  __syncthreads();  // all lh reads done before overwrite
  #pragma unroll
  for (int i = 0; i < 2; ++i) {
    lh[r0+i][j0+0] = fast_tanh(h[i][0]);
    lh[r0+i][j0+1] = fast_tanh(h[i][1]);
    lh[r0+i][j0+2] = fast_tanh(h[i][2]);
    lh[r0+i][j0+3] = fast_tanh(h[i][3]);
  }

  // layer 3 (K=64): o = tanh(h)@W3 + b3 + h
  #pragma unroll
  for (int j = 0; j < 4; ++j) { const float bj = b3[j0+j]; acc[0][j] = bj; acc[1][j] = bj; }
  for (int kc = 0; kc < 2; ++kc) {
    __syncthreads();
    for (int i = tid; i < 2048; i += 256) lw[i] = W3[kc*2048 + i];
    __syncthreads();
    #pragma unroll
    for (int kk = 0; kk < 32; ++kk) {
      const int k = kc*32 + kk;
      RDL_FMA(lh, k, kk, acc);
    }
  }
  #pragma unroll
  for (int i = 0; i < 2; ++i) {
    lin[r0+i][j0+0] = acc[i][0] + h[i][0];
    lin[r0+i][j0+1] = acc[i][1] + h[i][1];
    lin[r0+i][j0+2] = acc[i][2] + h[i][2];
    lin[r0+i][j0+3] = acc[i][3] + h[i][3];
  }
  __syncthreads();
  if (tid < 32) {
    float s = 0.0f, ss = 0.0f;
    for (int k = 0; k < 64; ++k) { const float v = lin[tid][k]; s += v; ss += v*v; }
    const float m = s * (1.0f/64.0f);
    const float var = ss * (1.0f/64.0f) - m*m;
    rstat[tid][0] = m;
    rstat[tid][1] = rsqrtf(var + LN_EPS);
  }
  __syncthreads();
  #pragma unroll
  for (int i = 0; i < 2; ++i) {
    const int r = r0 + i, row = base + r;
    if (row < nrows) {
      const float m = rstat[r][0], inv = rstat[r][1];
      const float u = ud[row];
      const float4 old = *(const float4*)&radial[(size_t)row*64 + j0];
      float4 o;
      o.x = C_RES*old.x + C_NEW*u*((lin[r][j0]   - m)*inv*eln_g[j0]   + eln_b[j0]);
      o.y = C_RES*old.y + C_NEW*u*((lin[r][j0+1] - m)*inv*eln_g[j0+1] + eln_b[j0+1]);
      o.z = C_RES*old.z + C_NEW*u*((lin[r][j0+2] - m)*inv*eln_g[j0+2] + eln_b[j0+2]);
      o.w = C_RES*old.w + C_NEW*u*((lin[r][j0+3] - m)*inv*eln_g[j0+3] + eln_b[j0+3]);
      *(float4*)&radial[(size_t)row*64 + j0] = o;
    }
  }
}

// ---------------- launch -----------------------------------------------------

extern "C" void kernel_launch(void* const* d_in, const int* in_sizes, int n_in,
                              void* d_out, int out_size, void* d_ws, size_t ws_size,
                              hipStream_t stream)
{
  const int*   atom_types = (const int*)  d_in[0];
  const float* env_vec    = (const float*)d_in[1];
  const float* env_len    = (const float*)d_in[2];
  const float* edge_len   = (const float*)d_in[3];
  const int*   env_idx    = (const int*)  d_in[4];
  const int*   edge_idx   = (const int*)  d_in[5];
  const float* bessel_w   = (const float*)d_in[6];
  const float* srW1 = (const float*)d_in[7];  const float* srb1 = (const float*)d_in[8];
  const float* srW2 = (const float*)d_in[9];  const float* srb2 = (const float*)d_in[10];
  const float* srW3 = (const float*)d_in[11]; const float* srb3 = (const float*)d_in[12];
  const float* rdW1 = (const float*)d_in[13]; const float* rdb1 = (const float*)d_in[14];
  const float* rdW2 = (const float*)d_in[15]; const float* rdb2 = (const float*)d_in[16];
  const float* rdW3 = (const float*)d_in[17]; const float* rdb3 = (const float*)d_in[18];
  const float* ne_emb_W = (const float*)d_in[19]; const float* ne_emb_b = (const float*)d_in[20];
  const float* ne_nln_g = (const float*)d_in[21]; const float* ne_nln_b = (const float*)d_in[22];
  const float* ne_eln_g = (const float*)d_in[23]; const float* ne_eln_b = (const float*)d_in[24];
  const float* ly_emb_W = (const float*)d_in[25]; const float* ly_emb_b = (const float*)d_in[26];
  const float* ly_hid_W1 = (const float*)d_in[27]; const float* ly_hid_b1 = (const float*)d_in[28];
  const float* ly_hid_W2 = (const float*)d_in[29]; const float* ly_hid_b2 = (const float*)d_in[30];
  const float* ly_hid_W3 = (const float*)d_in[31]; const float* ly_hid_b3 = (const float*)d_in[32];
  const float* ly_rdl_W1 = (const float*)d_in[33]; const float* ly_rdl_b1 = (const float*)d_in[34];
  const float* ly_rdl_W2 = (const float*)d_in[35]; const float* ly_rdl_b2 = (const float*)d_in[36];
  const float* ly_rdl_W3 = (const float*)d_in[37]; const float* ly_rdl_b3 = (const float*)d_in[38];
  const float* ly_nln_g = (const float*)d_in[39]; const float* ly_nln_b = (const float*)d_in[40];
  const float* ly_eln_g = (const float*)d_in[41]; const float* ly_eln_b = (const float*)d_in[42];

  const int N  = in_sizes[0];
  const int E  = in_sizes[2];
  const int E2 = in_sizes[3];

  float* out = (float*)d_out;
  float* env_radial  = out;
  float* edge_radial = env_radial + (size_t)E * 64;
  float* node_emb    = edge_radial + (size_t)E2 * 64;
  float* env_hidden  = node_emb + (size_t)N * 128;
  float* edge_hidden = env_hidden + (size_t)E * 128;

  float* ws = (float*)d_ws;
  float* ud_env  = ws;  ws += E;
  float* ud_edge = ws;  ws += E2;
  float* aggS    = ws;  ws += (size_t)N * 48;
  float* cnt     = ws;  ws += N;
  float* agg2    = ws;  ws += (size_t)N * 128;

  const int gE  = (E  + 31) / 32;
  const int gE2 = (E2 + 31) / 32;

  // zero aggS + cnt (contiguous)
  zero_kernel<<<1024, 256, 0, stream>>>(aggS, (size_t)N * 49);

  feat_mlp_kernel<1><<<gE, 256, 0, stream>>>(E, atom_types, env_len, env_vec, env_idx, bessel_w,
      srW1, srb1, srW2, srb2, srW3, srb3, rdW1, rdb1, rdW2, rdb2, rdW3, rdb3,
      ne_eln_g, ne_eln_b, env_radial, ud_env, aggS, cnt);
  feat_mlp_kernel<0><<<gE2, 256, 0, stream>>>(E2, atom_types, edge_len, nullptr, edge_idx, bessel_w,
      srW1, srb1, srW2, srb2, srW3, srb3, rdW1, rdb1, rdW2, rdb2, rdW3, rdb3,
      ne_eln_g, ne_eln_b, edge_radial, ud_edge, nullptr, nullptr);

  node_emb_kernel<<<N, 128, 0, stream>>>(N, aggS, cnt, ne_nln_g, ne_nln_b, node_emb);

  emb_gemm_kernel<0><<<gE, 256, 0, stream>>>(E, env_radial, ne_emb_W, ne_emb_b, env_idx, node_emb, env_hidden);
  emb_gemm_kernel<0><<<gE2, 256, 0, stream>>>(E2, edge_radial, ne_emb_W, ne_emb_b, edge_idx, node_emb, edge_hidden);

  for (int l = 0; l < 2; ++l) {
    zero_kernel<<<1024, 256, 0, stream>>>(agg2, (size_t)N * 128);
    emb_gemm_kernel<1><<<gE, 256, 0, stream>>>(E, env_radial, ly_emb_W + (size_t)l*64*128,
        ly_emb_b + (size_t)l*128, env_idx, nullptr, agg2);
    node_update_kernel<<<N, 128, 0, stream>>>(N, agg2, cnt,
        ly_nln_g + (size_t)l*128, ly_nln_b + (size_t)l*128, node_emb);

    hid_mlp_kernel<<<gE, 256, 0, stream>>>(E, env_idx, node_emb,
        ly_hid_W1 + (size_t)l*256*128, ly_hid_b1 + (size_t)l*128,
        ly_hid_W2 + (size_t)l*128*128, ly_hid_b2 + (size_t)l*128,
        ly_hid_W3 + (size_t)l*128*128, ly_hid_b3 + (size_t)l*128, env_hidden);
    hid_mlp_kernel<<<gE2, 256, 0, stream>>>(E2, edge_idx, node_emb,
        ly_hid_W1 + (size_t)l*256*128, ly_hid_b1 + (size_t)l*128,
        ly_hid_W2 + (size_t)l*128*128, ly_hid_b2 + (size_t)l*128,
        ly_hid_W3 + (size_t)l*128*128, ly_hid_b3 + (size_t)l*128, edge_hidden);

    rdl_kernel<<<gE, 256, 0, stream>>>(E, env_hidden, ud_env,
        ly_rdl_W1 + (size_t)l*192*64, ly_rdl_b1 + (size_t)l*64,
        ly_rdl_W2 + (size_t)l*64*64,  ly_rdl_b2 + (size_t)l*64,
        ly_rdl_W3 + (size_t)l*64*64,  ly_rdl_b3 + (size_t)l*64,
        ly_eln_g + (size_t)l*64, ly_eln_b + (size_t)l*64, env_radial);
    rdl_kernel<<<gE2, 256, 0, stream>>>(E2, edge_hidden, ud_edge,
        ly_rdl_W1 + (size_t)l*192*64, ly_rdl_b1 + (size_t)l*64,
        ly_rdl_W2 + (size_t)l*64*64,  ly_rdl_b2 + (size_t)l*64,
        ly_rdl_W3 + (size_t)l*64*64,  ly_rdl_b3 + (size_t)l*64,
        ly_eln_g + (size_t)l*64, ly_eln_b + (size_t)l*64, edge_radial);
  }
}

// Round 2
// 4656.078 us; speedup vs baseline: 1.6234x; 1.6234x over previous
//
#include <hip/hip_runtime.h>
#include <math.h>

#define C_RES 0.89442719f
#define C_NEW 0.4472f
#define LN_EPS 1e-5f
#define BESSEL_PREF 0.6324555320336759f  // sqrt(2/5)
#define RC_INV 0.2f

typedef __attribute__((ext_vector_type(8))) short short8;
typedef __attribute__((ext_vector_type(8))) unsigned short u16x8;
typedef __attribute__((ext_vector_type(16))) float f32x16;

__device__ __forceinline__ float fast_tanh(float x) {
  float ax = fabsf(x);
  float e = __expf(2.0f * ax);
  float t = 1.0f - 2.0f / (e + 1.0f);
  return copysignf(t, x);
}

__device__ __forceinline__ unsigned short f2b(float f) {
  unsigned int u = __float_as_uint(f);
  unsigned int r = (u + 0x7FFFu + ((u >> 16) & 1u)) >> 16;
  return (unsigned short)r;
}

__device__ __forceinline__ float poly_cutoff(float x) {
  float xr = x * RC_INV;
  if (xr >= 1.0f) return 0.0f;
  float x2 = xr * xr;
  float x3 = x2 * xr;
  float x6 = x3 * x3;
  return 1.0f - 28.0f * x6 + 48.0f * x6 * xr - 21.0f * x6 * x2;
}

// A-frag slot swizzle: spreads the 512B/1024B-stride aliasing of the
// C/D->A scatter writes across banks; reads stay a permutation (conflict-free).
__device__ __forceinline__ int swz(int s, int kc) {
  return s ^ ((s >> 5) << 1) ^ ((kc & 1) << 2);
}

__global__ void zero_kernel(float* __restrict__ p, size_t n) {
  size_t i = (size_t)blockIdx.x * blockDim.x + threadIdx.x;
  size_t stride = (size_t)gridDim.x * blockDim.x;
  for (; i < n; i += stride) p[i] = 0.0f;
}

// ---------------- pack hidden-MLP weights into bf16 MFMA B-fragment order ----
// Per layer (65536 ushorts): W1 [256x128] at 0, W2 [128x128] at 32768, W3 at 49152.
// Block layout: blk = kc*4 + ct; within blk: lane = (col&31) + 32*((k>>3)&1), j = k&7.
__global__ void pack_hid_weights(const float* __restrict__ W1,
                                 const float* __restrict__ W2,
                                 const float* __restrict__ W3,
                                 unsigned short* __restrict__ out)
{
  int t = blockIdx.x * 256 + threadIdx.x;  // 0..131071
  if (t >= 131072) return;
  int l = t >> 16;
  int oidx = t & 65535;
  const float* src;
  int midx;
  if (oidx < 32768)      { src = W1 + l * 32768; midx = oidx; }
  else if (oidx < 49152) { src = W2 + l * 16384; midx = oidx - 32768; }
  else                   { src = W3 + l * 16384; midx = oidx - 49152; }
  int j = midx & 7;
  int lane = (midx >> 3) & 63;
  int blk = midx >> 9;
  int ct = blk & 3, kc = blk >> 2;
  int col = ct * 32 + (lane & 31);
  int k = kc * 16 + (lane >> 5) * 8 + j;
  out[l * 65536 + oidx] = f2b(src[k * 128 + col]);
}

// ---------------- stage-A: features + sr/rd MLPs + LN + msg scatter ----------
// 32 rows per block, 256 threads.

#define STAGE_W(SRC, NF) do {                                                   \
    __syncthreads();                                                            \
    for (int i_ = tid; i_ < (NF); i_ += 256) wbuf[i_] = (SRC)[i_];              \
    __syncthreads();                                                            \
  } while (0)

#define MM_2x4(SRCARR, KDIM, WSTR, BIASP, DOTANH, DSTARR) do {                  \
    const int r0_ = (tid >> 4) * 2, j0_ = (tid & 15) * 4;                       \
    float a00 = (BIASP)[j0_],   a01 = (BIASP)[j0_+1];                           \
    float a02 = (BIASP)[j0_+2], a03 = (BIASP)[j0_+3];                           \
    float a10 = a00, a11 = a01, a12 = a02, a13 = a03;                           \
    for (int k_ = 0; k_ < (KDIM); ++k_) {                                       \
      const float s0_ = SRCARR[r0_][k_], s1_ = SRCARR[r0_+1][k_];               \
      const float4 w_ = *(const float4*)&wbuf[k_*(WSTR) + j0_];                 \
      a00 += s0_*w_.x; a01 += s0_*w_.y; a02 += s0_*w_.z; a03 += s0_*w_.w;       \
      a10 += s1_*w_.x; a11 += s1_*w_.y; a12 += s1_*w_.z; a13 += s1_*w_.w;       \
    }                                                                           \
    if (DOTANH) {                                                               \
      a00 = fast_tanh(a00); a01 = fast_tanh(a01);                               \
      a02 = fast_tanh(a02); a03 = fast_tanh(a03);                               \
      a10 = fast_tanh(a10); a11 = fast_tanh(a11);                               \
      a12 = fast_tanh(a12); a13 = fast_tanh(a13);                               \
    }                                                                           \
    DSTARR[r0_][j0_]   = a00; DSTARR[r0_][j0_+1]   = a01;                       \
    DSTARR[r0_][j0_+2] = a02; DSTARR[r0_][j0_+3]   = a03;                       \
    DSTARR[r0_+1][j0_]   = a10; DSTARR[r0_+1][j0_+1] = a11;                     \
    DSTARR[r0_+1][j0_+2] = a12; DSTARR[r0_+1][j0_+3] = a13;                     \
  } while (0)

template<int HAS_SR>
__launch_bounds__(256)
__global__ void feat_mlp_kernel(
    int nrows,
    const int* __restrict__ types, const float* __restrict__ lens,
    const float* __restrict__ vecs, const int* __restrict__ idx,
    const float* __restrict__ bessel_w,
    const float* __restrict__ srW1, const float* __restrict__ srb1,
    const float* __restrict__ srW2, const float* __restrict__ srb2,
    const float* __restrict__ srW3, const float* __restrict__ srb3,
    const float* __restrict__ rdW1, const float* __restrict__ rdb1,
    const float* __restrict__ rdW2, const float* __restrict__ rdb2,
    const float* __restrict__ rdW3, const float* __restrict__ rdb3,
    const float* __restrict__ eln_g, const float* __restrict__ eln_b,
    float* __restrict__ radial_out, float* __restrict__ ud_out,
    float* __restrict__ aggS, float* __restrict__ cnt)
{
  __shared__ float feat[32][25];
  __shared__ float bufA[32][65];
  __shared__ float bufB[32][65];
  __shared__ __align__(16) float wbuf[4096];
  __shared__ float sval[32][17];
  __shared__ float evud[32][3];
  __shared__ float udl[32];
  __shared__ int   i1l[32];
  __shared__ float rstat[32][2];

  const int tid = threadIdx.x;
  const int base = blockIdx.x * 32;

  if (tid < 32) {
    const int r = tid;
    const int row = base + r;
    const bool valid = row < nrows;
    float len = 1.0f, ud = 0.0f;
    int i0 = 0, i1 = 0;
    if (valid) {
      i0 = idx[row];
      i1 = idx[nrows + row];
      len = lens[row];
      ud = poly_cutoff(len);
    }
    const int t0 = valid ? types[i0] : -1;
    const int t1 = valid ? types[i1] : -1;
    #pragma unroll
    for (int a = 0; a < 4; ++a) {
      feat[r][a]     = (t0 == a) ? 1.0f : 0.0f;
      feat[r][4 + a] = (t1 == a) ? 1.0f : 0.0f;
    }
    const float invl = 1.0f / len;
    #pragma unroll
    for (int k = 0; k < 16; ++k) {
      feat[r][8 + k] = valid ? ud * BESSEL_PREF * sinf(bessel_w[k] * len * RC_INV) * invl : 0.0f;
    }
    udl[r] = ud;
    i1l[r] = i1;
    if (valid) {
      ud_out[row] = ud;
      if (HAS_SR) {
        evud[r][0] = ud * vecs[(size_t)row*3 + 0];
        evud[r][1] = ud * vecs[(size_t)row*3 + 1];
        evud[r][2] = ud * vecs[(size_t)row*3 + 2];
        atomicAdd(&cnt[i1], 1.0f);
      }
    }
  }

  if (HAS_SR) {
    STAGE_W(srW1, 24*64);
    MM_2x4(feat, 24, 64, srb1, true, bufA);
    STAGE_W(srW2, 64*64);
    MM_2x4(bufA, 64, 64, srb2, true, bufB);
    STAGE_W(srW3, 64*16);
    {
      const int r = tid & 31;
      const int j = (tid >> 5) * 2;
      float a0 = srb3[j], a1 = srb3[j + 1];
      for (int k = 0; k < 64; ++k) {
        const float v = bufB[r][k];
        a0 += v * wbuf[k*16 + j];
        a1 += v * wbuf[k*16 + j + 1];
      }
      const float u = udl[r];
      sval[r][j]   = a0 * u;
      sval[r][j+1] = a1 * u;
    }
  }

  STAGE_W(rdW1, 24*64);
  MM_2x4(feat, 24, 64, rdb1, true, bufA);
  STAGE_W(rdW2, 64*64);
  MM_2x4(bufA, 64, 64, rdb2, true, bufB);
  STAGE_W(rdW3, 64*64);
  MM_2x4(bufB, 64, 64, rdb3, false, bufA);
  __syncthreads();
  if (tid < 32) {
    float s = 0.0f, ss = 0.0f;
    for (int k = 0; k < 64; ++k) { const float v = bufA[tid][k]; s += v; ss += v*v; }
    const float m = s * (1.0f/64.0f);
    const float var = ss * (1.0f/64.0f) - m*m;
    rstat[tid][0] = m;
    rstat[tid][1] = rsqrtf(var + LN_EPS);
  }
  __syncthreads();
  {
    const int r0 = (tid >> 4) * 2, j0 = (tid & 15) * 4;
    #pragma unroll
    for (int i = 0; i < 2; ++i) {
      const int r = r0 + i, row = base + r;
      if (row < nrows) {
        const float m = rstat[r][0], inv = rstat[r][1], u = udl[r];
        float4 v;
        v.x = ((bufA[r][j0]   - m)*inv*eln_g[j0]   + eln_b[j0])   * u;
        v.y = ((bufA[r][j0+1] - m)*inv*eln_g[j0+1] + eln_b[j0+1]) * u;
        v.z = ((bufA[r][j0+2] - m)*inv*eln_g[j0+2] + eln_b[j0+2]) * u;
        v.w = ((bufA[r][j0+3] - m)*inv*eln_g[j0+3] + eln_b[j0+3]) * u;
        *(float4*)&radial_out[(size_t)row*64 + j0] = v;
      }
    }
  }
  if (HAS_SR) {
    const int r = tid >> 3, q = tid & 7;
    const int row = base + r;
    if (row < nrows) {
      const size_t bo = (size_t)i1l[r] * 48;
      #pragma unroll
      for (int m6 = 0; m6 < 6; ++m6) {
        const int id = q*6 + m6;
        const int d = id / 3, c = id - d*3;
        atomicAdd(&aggS[bo + id], sval[r][d] * evud[r][c]);
      }
    }
  }
}

// ---------------- node embedding (gram + LN) ---------------------------------

__device__ __forceinline__ void block128_stats(float x, float& m, float& inv, float* red) {
  float s = x, ss = x*x;
  #pragma unroll
  for (int o = 32; o; o >>= 1) { s += __shfl_down(s, o); ss += __shfl_down(ss, o); }
  const int t = threadIdx.x;
  if ((t & 63) == 0) { red[(t >> 6)*2] = s; red[(t >> 6)*2 + 1] = ss; }
  __syncthreads();
  const float S = red[0] + red[2], SS = red[1] + red[3];
  m = S * (1.0f/128.0f);
  const float var = SS * (1.0f/128.0f) - m*m;
  inv = rsqrtf(var + LN_EPS);
}

__launch_bounds__(128)
__global__ void node_emb_kernel(int N, const float* __restrict__ aggS,
                                const float* __restrict__ cnt,
                                const float* __restrict__ g, const float* __restrict__ b,
                                float* __restrict__ node_emb)
{
  const int n = blockIdx.x, t = threadIdx.x;
  __shared__ float S[48];
  __shared__ float red[4];
  if (t < 48) S[t] = aggS[(size_t)n*48 + t];
  __syncthreads();
  const float ic = 1.0f / fmaxf(cnt[n], 1.0f);
  const int d = t >> 3, e = t & 7;
  const float x = (S[d*3+0]*S[e*3+0] + S[d*3+1]*S[e*3+1] + S[d*3+2]*S[e*3+2]) * ic * ic;
  float m, inv;
  block128_stats(x, m, inv, red);
  node_emb[(size_t)n*128 + t] = (x - m)*inv*g[t] + b[t];
}

__launch_bounds__(128)
__global__ void node_update_kernel(int N, const float* __restrict__ aggsum,
                                   const float* __restrict__ cnt,
                                   const float* __restrict__ g, const float* __restrict__ b,
                                   float* __restrict__ node_emb)
{
  const int n = blockIdx.x, t = threadIdx.x;
  __shared__ float red[4];
  const float old = node_emb[(size_t)n*128 + t];
  const float x = old * (aggsum[(size_t)n*128 + t] / fmaxf(cnt[n], 1.0f));
  float m, inv;
  block128_stats(x, m, inv, red);
  node_emb[(size_t)n*128 + t] = C_RES*old + C_NEW*((x - m)*inv*g[t] + b[t]);
}

// ---------------- embedding GEMM (K=64 -> N=128), two epilogues --------------

template<int MODE>
__launch_bounds__(256)
__global__ void emb_gemm_kernel(
    int nrows,
    const float* __restrict__ radial,
    const float* __restrict__ W, const float* __restrict__ bias,
    const int* __restrict__ idx,
    const float* __restrict__ node_emb,
    float* __restrict__ out)
{
  __shared__ float lin[32][65];
  __shared__ __align__(16) float lw[64*128];
  const int tid = threadIdx.x;
  const int base = blockIdx.x * 32;

  for (int i = tid; i < 64*128; i += 256) lw[i] = W[i];
  {
    const int rr0 = tid >> 6, k = tid & 63;
    for (int rr = rr0; rr < 32; rr += 4) {
      const int row = base + rr;
      lin[rr][k] = (row < nrows) ? radial[(size_t)row*64 + k] : 0.0f;
    }
  }
  __syncthreads();

  const int r0 = (tid >> 5) * 4, j0 = (tid & 31) * 4;
  float acc[4][4];
  #pragma unroll
  for (int j = 0; j < 4; ++j) {
    const float bj = bias[j0 + j];
    acc[0][j] = bj; acc[1][j] = bj; acc[2][j] = bj; acc[3][j] = bj;
  }
  for (int k = 0; k < 64; ++k) {
    const float4 w = *(const float4*)&lw[k*128 + j0];
    const float s0 = lin[r0][k],   s1 = lin[r0+1][k];
    const float s2 = lin[r0+2][k], s3 = lin[r0+3][k];
    acc[0][0] += s0*w.x; acc[0][1] += s0*w.y; acc[0][2] += s0*w.z; acc[0][3] += s0*w.w;
    acc[1][0] += s1*w.x; acc[1][1] += s1*w.y; acc[1][2] += s1*w.z; acc[1][3] += s1*w.w;
    acc[2][0] += s2*w.x; acc[2][1] += s2*w.y; acc[2][2] += s2*w.z; acc[2][3] += s2*w.w;
    acc[3][0] += s3*w.x; acc[3][1] += s3*w.y; acc[3][2] += s3*w.z; acc[3][3] += s3*w.w;
  }
  #pragma unroll
  for (int i = 0; i < 4; ++i) {
    const int row = base + r0 + i;
    if (row >= nrows) continue;
    if (MODE == 0) {
      const int i0 = idx[row], i1 = idx[nrows + row];
      const float4 n0 = *(const float4*)&node_emb[(size_t)i0*128 + j0];
      const float4 n1 = *(const float4*)&node_emb[(size_t)i1*128 + j0];
      float4 o;
      o.x = acc[i][0] * 0.5f * (n0.x + n1.x);
      o.y = acc[i][1] * 0.5f * (n0.y + n1.y);
      o.z = acc[i][2] * 0.5f * (n0.z + n1.z);
      o.w = acc[i][3] * 0.5f * (n0.w + n1.w);
      *(float4*)&out[(size_t)row*128 + j0] = o;
    } else {
      const int i1 = idx[nrows + row];
      float* p = &out[(size_t)i1*128 + j0];
      atomicAdd(p + 0, acc[i][0]);
      atomicAdd(p + 1, acc[i][1]);
      atomicAdd(p + 2, acc[i][2]);
      atomicAdd(p + 3, acc[i][3]);
    }
  }
}

// ---------------- hidden MLP via bf16 MFMA -----------------------------------
// 128 rows/block, 128 threads (2 waves). Wave w owns row-tiles {2w,2w+1},
// all 4 col-tiles. 32x32x16 bf16 MFMA, fp32 accum, bias in acc init.
// A-fragments live in LDS in fragment order (swizzled slots); packed bf16
// weights group-staged (8KB/phase, linear->conflict-free).

__launch_bounds__(128)
__global__ void hid_mlp_mfma(
    int nrows, const int* __restrict__ idx0,
    const float* __restrict__ node_emb,
    const unsigned short* __restrict__ wpack,   // 65536 ushorts for this layer
    const float* __restrict__ b1, const float* __restrict__ b2,
    const float* __restrict__ b3,
    float* __restrict__ hidden)
{
  __shared__ __align__(16) unsigned short h_afrag[16384];  // 32KB: [rt4][kc8]*512
  __shared__ __align__(16) unsigned short xg[4096];        // 8KB:  [rt4][kcl2]*512
  __shared__ __align__(16) unsigned short wg[4096];        // 8KB:  [kcl2][ct4]*512

  const int tid  = threadIdx.x;
  const int lane = tid & 63;
  const int wave = tid >> 6;
  const int base = blockIdx.x * 128;

  const int r = tid;                       // staging row 0..127
  int rowg = base + r;
  if (rowg >= nrows) rowg = nrows - 1;
  const int i0 = idx0[rowg];
  const float* xsrc0 = node_emb + (size_t)i0 * 128;
  const float* xsrc1 = hidden + (size_t)rowg * 128;

  f32x16 acc[2][4];

  // ---------- layer 1: K=256, 8 phases x (2 kc) ----------
  #pragma unroll
  for (int ct = 0; ct < 4; ++ct) {
    const float bv = b1[ct*32 + (lane & 31)];
    #pragma unroll
    for (int q = 0; q < 16; ++q) { acc[0][ct][q] = bv; acc[1][ct][q] = bv; }
  }
  for (int p = 0; p < 8; ++p) {
    __syncthreads();
    #pragma unroll
    for (int o = 0; o < 4; ++o) {
      const int k = p*32 + o*8;
      const float* s = (k < 128) ? (xsrc0 + k) : (xsrc1 + (k - 128));
      const float4 v0 = *(const float4*)s;
      const float4 v1 = *(const float4*)(s + 4);
      u16x8 w;
      w[0]=f2b(v0.x); w[1]=f2b(v0.y); w[2]=f2b(v0.z); w[3]=f2b(v0.w);
      w[4]=f2b(v1.x); w[5]=f2b(v1.y); w[6]=f2b(v1.z); w[7]=f2b(v1.w);
      const int kc = p*2 + (o >> 1);
      const int s_ = (r & 31) + 32*(o & 1);
      *(u16x8*)&xg[ ((r>>5)*2 + (o>>1))*512 + swz(s_, kc)*8 ] = w;
    }
    #pragma unroll
    for (int i = 0; i < 4; ++i) {
      const int c = tid + i*128;
      *(u16x8*)&wg[c*8] = *(const u16x8*)&wpack[p*4096 + c*8];
    }
    __syncthreads();
    #pragma unroll
    for (int kcl = 0; kcl < 2; ++kcl) {
      const int kc = p*2 + kcl;
      const short8 a0 = *(const short8*)&xg[ ((wave*2+0)*2 + kcl)*512 + swz(lane, kc)*8 ];
      const short8 a1 = *(const short8*)&xg[ ((wave*2+1)*2 + kcl)*512 + swz(lane, kc)*8 ];
      #pragma unroll
      for (int ct = 0; ct < 4; ++ct) {
        const short8 b = *(const short8*)&wg[ (kcl*4 + ct)*512 + lane*8 ];
        acc[0][ct] = __builtin_amdgcn_mfma_f32_32x32x16_bf16(a0, b, acc[0][ct], 0, 0, 0);
        acc[1][ct] = __builtin_amdgcn_mfma_f32_32x32x16_bf16(a1, b, acc[1][ct], 0, 0, 0);
      }
    }
  }

  // ---------- transition 1: tanh -> h_afrag ----------
  __syncthreads();
  #pragma unroll
  for (int m = 0; m < 2; ++m) {
    const int rt = wave*2 + m;
    #pragma unroll
    for (int ct = 0; ct < 4; ++ct) {
      const int kc  = ct*2 + ((lane >> 4) & 1);
      const int oct = (lane >> 3) & 1;
      const int j   = lane & 7;
      const int xk  = (oct << 1) ^ ((kc & 1) << 2);
      const int hi  = 4*(lane >> 5);
      const int bi  = (rt*8 + kc)*512 + oct*256 + j;
      #pragma unroll
      for (int q = 0; q < 16; ++q) {
        const int m32 = (q & 3) + 8*(q >> 2) + hi;
        h_afrag[bi + (m32 ^ xk)*8] = f2b(fast_tanh(acc[m][ct][q]));
      }
    }
  }
  #pragma unroll
  for (int ct = 0; ct < 4; ++ct) {
    const float bv = b2[ct*32 + (lane & 31)];
    #pragma unroll
    for (int q = 0; q < 16; ++q) { acc[0][ct][q] = bv; acc[1][ct][q] = bv; }
  }
  __syncthreads();

  // ---------- layer 2: K=128, 4 phases x (2 kc) ----------
  for (int p = 0; p < 4; ++p) {
    __syncthreads();
    #pragma unroll
    for (int i = 0; i < 4; ++i) {
      const int c = tid + i*128;
      *(u16x8*)&wg[c*8] = *(const u16x8*)&wpack[32768 + p*4096 + c*8];
    }
    __syncthreads();
    #pragma unroll
    for (int kcl = 0; kcl < 2; ++kcl) {
      const int kc = p*2 + kcl;
      const short8 a0 = *(const short8*)&h_afrag[ ((wave*2+0)*8 + kc)*512 + swz(lane, kc)*8 ];
      const short8 a1 = *(const short8*)&h_afrag[ ((wave*2+1)*8 + kc)*512 + swz(lane, kc)*8 ];
      #pragma unroll
      for (int ct = 0; ct < 4; ++ct) {
        const short8 b = *(const short8*)&wg[ (kcl*4 + ct)*512 + lane*8 ];
        acc[0][ct] = __builtin_amdgcn_mfma_f32_32x32x16_bf16(a0, b, acc[0][ct], 0, 0, 0);
        acc[1][ct] = __builtin_amdgcn_mfma_f32_32x32x16_bf16(a1, b, acc[1][ct], 0, 0, 0);
      }
    }
  }

  // ---------- transition 2: tanh -> h_afrag (overwrite) ----------
  __syncthreads();
  #pragma unroll
  for (int m = 0; m < 2; ++m) {
    const int rt = wave*2 + m;
    #pragma unroll
    for (int ct = 0; ct < 4; ++ct) {
      const int kc  = ct*2 + ((lane >> 4) & 1);
      const int oct = (lane >> 3) & 1;
      const int j   = lane & 7;
      const int xk  = (oct << 1) ^ ((kc & 1) << 2);
      const int hi  = 4*(lane >> 5);
      const int bi  = (rt*8 + kc)*512 + oct*256 + j;
      #pragma unroll
      for (int q = 0; q < 16; ++q) {
        const int m32 = (q & 3) + 8*(q >> 2) + hi;
        h_afrag[bi + (m32 ^ xk)*8] = f2b(fast_tanh(acc[m][ct][q]));
      }
    }
  }
  #pragma unroll
  for (int ct = 0; ct < 4; ++ct) {
    const float bv = b3[ct*32 + (lane & 31)];
    #pragma unroll
    for (int q = 0; q < 16; ++q) { acc[0][ct][q] = bv; acc[1][ct][q] = bv; }
  }
  __syncthreads();

  // ---------- layer 3: K=128 ----------
  for (int p = 0; p < 4; ++p) {
    __syncthreads();
    #pragma unroll
    for (int i = 0; i < 4; ++i) {
      const int c = tid + i*128;
      *(u16x8*)&wg[c*8] = *(const u16x8*)&wpack[49152 + p*4096 + c*8];
    }
    __syncthreads();
    #pragma unroll
    for (int kcl = 0; kcl < 2; ++kcl) {
      const int kc = p*2 + kcl;
      const short8 a0 = *(const short8*)&h_afrag[ ((wave*2+0)*8 + kc)*512 + swz(lane, kc)*8 ];
      const short8 a1 = *(const short8*)&h_afrag[ ((wave*2+1)*8 + kc)*512 + swz(lane, kc)*8 ];
      #pragma unroll
      for (int ct = 0; ct < 4; ++ct) {
        const short8 b = *(const short8*)&wg[ (kcl*4 + ct)*512 + lane*8 ];
        acc[0][ct] = __builtin_amdgcn_mfma_f32_32x32x16_bf16(a0, b, acc[0][ct], 0, 0, 0);
        acc[1][ct] = __builtin_amdgcn_mfma_f32_32x32x16_bf16(a1, b, acc[1][ct], 0, 0, 0);
      }
    }
  }

  // ---------- epilogue: store f32 ----------
  #pragma unroll
  for (int m = 0; m < 2; ++m) {
    #pragma unroll
    for (int ct = 0; ct < 4; ++ct) {
      const int col = ct*32 + (lane & 31);
      #pragma unroll
      for (int q = 0; q < 16; ++q) {
        const int row = base + (wave*2+m)*32 + (q & 3) + 8*(q >> 2) + 4*(lane >> 5);
        if (row < nrows) hidden[(size_t)row*128 + col] = acc[m][ct][q];
      }
    }
  }
}

// ---------------- radial ResNet + LN + residual-scale epilogue ---------------

#define RDL_FMA(SRCARR, KGLOB, KLOC, ACC) do {                                  \
    const float4 w_ = *(const float4*)&lw[(KLOC)*64 + j0];                      \
    const float s0_ = SRCARR[r0][KGLOB], s1_ = SRCARR[r0+1][KGLOB];             \
    ACC[0][0] += s0_*w_.x; ACC[0][1] += s0_*w_.y; ACC[0][2] += s0_*w_.z; ACC[0][3] += s0_*w_.w; \
    ACC[1][0] += s1_*w_.x; ACC[1][1] += s1_*w_.y; ACC[1][2] += s1_*w_.z; ACC[1][3] += s1_*w_.w; \
  } while (0)

__launch_bounds__(256)
__global__ void rdl_kernel(
    int nrows,
    const float* __restrict__ hidden, const float* __restrict__ ud,
    const float* __restrict__ W1, const float* __restrict__ b1,
    const float* __restrict__ W2, const float* __restrict__ b2,
    const float* __restrict__ W3, const float* __restrict__ b3,
    const float* __restrict__ eln_g, const float* __restrict__ eln_b,
    float* __restrict__ radial)
{
  __shared__ float lin[32][193];
  __shared__ float lh[32][65];
  __shared__ __align__(16) float lw[32*64];
  __shared__ float rstat[32][2];
  const int tid = threadIdx.x;
  const int base = blockIdx.x * 32;

  for (int rr = 0; rr < 32; ++rr) {
    const int row = base + rr;
    if (tid < 192) {
      float v = 0.0f;
      if (row < nrows) v = (tid < 64) ? radial[(size_t)row*64 + tid]
                                      : hidden[(size_t)row*128 + (tid - 64)];
      lin[rr][tid] = v;
    }
  }

  const int r0 = (tid >> 4) * 2, j0 = (tid & 15) * 4;
  float acc[2][4];
  float h[2][4];

  #pragma unroll
  for (int j = 0; j < 4; ++j) { const float bj = b1[j0+j]; acc[0][j] = bj; acc[1][j] = bj; }
  for (int kc = 0; kc < 6; ++kc) {
    __syncthreads();
    for (int i = tid; i < 2048; i += 256) lw[i] = W1[kc*2048 + i];
    __syncthreads();
    #pragma unroll
    for (int kk = 0; kk < 32; ++kk) {
      const int k = kc*32 + kk;
      RDL_FMA(lin, k, kk, acc);
    }
  }
  #pragma unroll
  for (int i = 0; i < 2; ++i) {
    lh[r0+i][j0+0] = fast_tanh(acc[i][0]);
    lh[r0+i][j0+1] = fast_tanh(acc[i][1]);
    lh[r0+i][j0+2] = fast_tanh(acc[i][2]);
    lh[r0+i][j0+3] = fast_tanh(acc[i][3]);
  }

  #pragma unroll
  for (int j = 0; j < 4; ++j) { const float bj = b2[j0+j]; h[0][j] = bj; h[1][j] = bj; }
  for (int kc = 0; kc < 2; ++kc) {
    __syncthreads();
    for (int i = tid; i < 2048; i += 256) lw[i] = W2[kc*2048 + i];
    __syncthreads();
    #pragma unroll
    for (int kk = 0; kk < 32; ++kk) {
      const int k = kc*32 + kk;
      RDL_FMA(lh, k, kk, h);
    }
  }
  __syncthreads();
  #pragma unroll
  for (int i = 0; i < 2; ++i) {
    lh[r0+i][j0+0] = fast_tanh(h[i][0]);
    lh[r0+i][j0+1] = fast_tanh(h[i][1]);
    lh[r0+i][j0+2] = fast_tanh(h[i][2]);
    lh[r0+i][j0+3] = fast_tanh(h[i][3]);
  }

  #pragma unroll
  for (int j = 0; j < 4; ++j) { const float bj = b3[j0+j]; acc[0][j] = bj; acc[1][j] = bj; }
  for (int kc = 0; kc < 2; ++kc) {
    __syncthreads();
    for (int i = tid; i < 2048; i += 256) lw[i] = W3[kc*2048 + i];
    __syncthreads();
    #pragma unroll
    for (int kk = 0; kk < 32; ++kk) {
      const int k = kc*32 + kk;
      RDL_FMA(lh, k, kk, acc);
    }
  }
  #pragma unroll
  for (int i = 0; i < 2; ++i) {
    lin[r0+i][j0+0] = acc[i][0] + h[i][0];
    lin[r0+i][j0+1] = acc[i][1] + h[i][1];
    lin[r0+i][j0+2] = acc[i][2] + h[i][2];
    lin[r0+i][j0+3] = acc[i][3] + h[i][3];
  }
  __syncthreads();
  if (tid < 32) {
    float s = 0.0f, ss = 0.0f;
    for (int k = 0; k < 64; ++k) { const float v = lin[tid][k]; s += v; ss += v*v; }
    const float m = s * (1.0f/64.0f);
    const float var = ss * (1.0f/64.0f) - m*m;
    rstat[tid][0] = m;
    rstat[tid][1] = rsqrtf(var + LN_EPS);
  }
  __syncthreads();
  #pragma unroll
  for (int i = 0; i < 2; ++i) {
    const int r = r0 + i, row = base + r;
    if (row < nrows) {
      const float m = rstat[r][0], inv = rstat[r][1];
      const float u = ud[row];
      const float4 old = *(const float4*)&radial[(size_t)row*64 + j0];
      float4 o;
      o.x = C_RES*old.x + C_NEW*u*((lin[r][j0]   - m)*inv*eln_g[j0]   + eln_b[j0]);
      o.y = C_RES*old.y + C_NEW*u*((lin[r][j0+1] - m)*inv*eln_g[j0+1] + eln_b[j0+1]);
      o.z = C_RES*old.z + C_NEW*u*((lin[r][j0+2] - m)*inv*eln_g[j0+2] + eln_b[j0+2]);
      o.w = C_RES*old.w + C_NEW*u*((lin[r][j0+3] - m)*inv*eln_g[j0+3] + eln_b[j0+3]);
      *(float4*)&radial[(size_t)row*64 + j0] = o;
    }
  }
}

// ---------------- launch -----------------------------------------------------

extern "C" void kernel_launch(void* const* d_in, const int* in_sizes, int n_in,
                              void* d_out, int out_size, void* d_ws, size_t ws_size,
                              hipStream_t stream)
{
  const int*   atom_types = (const int*)  d_in[0];
  const float* env_vec    = (const float*)d_in[1];
  const float* env_len    = (const float*)d_in[2];
  const float* edge_len   = (const float*)d_in[3];
  const int*   env_idx    = (const int*)  d_in[4];
  const int*   edge_idx   = (const int*)  d_in[5];
  const float* bessel_w   = (const float*)d_in[6];
  const float* srW1 = (const float*)d_in[7];  const float* srb1 = (const float*)d_in[8];
  const float* srW2 = (const float*)d_in[9];  const float* srb2 = (const float*)d_in[10];
  const float* srW3 = (const float*)d_in[11]; const float* srb3 = (const float*)d_in[12];
  const float* rdW1 = (const float*)d_in[13]; const float* rdb1 = (const float*)d_in[14];
  const float* rdW2 = (const float*)d_in[15]; const float* rdb2 = (const float*)d_in[16];
  const float* rdW3 = (const float*)d_in[17]; const float* rdb3 = (const float*)d_in[18];
  const float* ne_emb_W = (const float*)d_in[19]; const float* ne_emb_b = (const float*)d_in[20];
  const float* ne_nln_g = (const float*)d_in[21]; const float* ne_nln_b = (const float*)d_in[22];
  const float* ne_eln_g = (const float*)d_in[23]; const float* ne_eln_b = (const float*)d_in[24];
  const float* ly_emb_W = (const float*)d_in[25]; const float* ly_emb_b = (const float*)d_in[26];
  const float* ly_hid_W1 = (const float*)d_in[27]; const float* ly_hid_b1 = (const float*)d_in[28];
  const float* ly_hid_W2 = (const float*)d_in[29]; const float* ly_hid_b2 = (const float*)d_in[30];
  const float* ly_hid_W3 = (const float*)d_in[31]; const float* ly_hid_b3 = (const float*)d_in[32];
  const float* ly_rdl_W1 = (const float*)d_in[33]; const float* ly_rdl_b1 = (const float*)d_in[34];
  const float* ly_rdl_W2 = (const float*)d_in[35]; const float* ly_rdl_b2 = (const float*)d_in[36];
  const float* ly_rdl_W3 = (const float*)d_in[37]; const float* ly_rdl_b3 = (const float*)d_in[38];
  const float* ly_nln_g = (const float*)d_in[39]; const float* ly_nln_b = (const float*)d_in[40];
  const float* ly_eln_g = (const float*)d_in[41]; const float* ly_eln_b = (const float*)d_in[42];

  const int N  = in_sizes[0];
  const int E  = in_sizes[2];
  const int E2 = in_sizes[3];

  float* out = (float*)d_out;
  float* env_radial  = out;
  float* edge_radial = env_radial + (size_t)E * 64;
  float* node_emb    = edge_radial + (size_t)E2 * 64;
  float* env_hidden  = node_emb + (size_t)N * 128;
  float* edge_hidden = env_hidden + (size_t)E * 128;

  float* ws = (float*)d_ws;
  float* ud_env  = ws;  ws += E;
  float* ud_edge = ws;  ws += E2;
  float* aggS    = ws;  ws += (size_t)N * 48;
  float* cnt     = ws;  ws += N;
  float* agg2    = ws;  ws += (size_t)N * 128;
  unsigned short* wpack = (unsigned short*)ws;  ws += 65536;  // 2 layers x 65536 ushorts

  const int gE  = (E  + 31) / 32;
  const int gE2 = (E2 + 31) / 32;
  const int gEh  = (E  + 127) / 128;
  const int gE2h = (E2 + 127) / 128;

  // zero aggS + cnt (contiguous)
  zero_kernel<<<1024, 256, 0, stream>>>(aggS, (size_t)N * 49);
  pack_hid_weights<<<512, 256, 0, stream>>>(ly_hid_W1, ly_hid_W2, ly_hid_W3, wpack);

  feat_mlp_kernel<1><<<gE, 256, 0, stream>>>(E, atom_types, env_len, env_vec, env_idx, bessel_w,
      srW1, srb1, srW2, srb2, srW3, srb3, rdW1, rdb1, rdW2, rdb2, rdW3, rdb3,
      ne_eln_g, ne_eln_b, env_radial, ud_env, aggS, cnt);
  feat_mlp_kernel<0><<<gE2, 256, 0, stream>>>(E2, atom_types, edge_len, nullptr, edge_idx, bessel_w,
      srW1, srb1, srW2, srb2, srW3, srb3, rdW1, rdb1, rdW2, rdb2, rdW3, rdb3,
      ne_eln_g, ne_eln_b, edge_radial, ud_edge, nullptr, nullptr);

  node_emb_kernel<<<N, 128, 0, stream>>>(N, aggS, cnt, ne_nln_g, ne_nln_b, node_emb);

  emb_gemm_kernel<0><<<gE, 256, 0, stream>>>(E, env_radial, ne_emb_W, ne_emb_b, env_idx, node_emb, env_hidden);
  emb_gemm_kernel<0><<<gE2, 256, 0, stream>>>(E2, edge_radial, ne_emb_W, ne_emb_b, edge_idx, node_emb, edge_hidden);

  for (int l = 0; l < 2; ++l) {
    zero_kernel<<<1024, 256, 0, stream>>>(agg2, (size_t)N * 128);
    emb_gemm_kernel<1><<<gE, 256, 0, stream>>>(E, env_radial, ly_emb_W + (size_t)l*64*128,
        ly_emb_b + (size_t)l*128, env_idx, nullptr, agg2);
    node_update_kernel<<<N, 128, 0, stream>>>(N, agg2, cnt,
        ly_nln_g + (size_t)l*128, ly_nln_b + (size_t)l*128, node_emb);

    hid_mlp_mfma<<<gEh, 128, 0, stream>>>(E, env_idx, node_emb,
        wpack + (size_t)l*65536,
        ly_hid_b1 + (size_t)l*128, ly_hid_b2 + (size_t)l*128, ly_hid_b3 + (size_t)l*128,
        env_hidden);
    hid_mlp_mfma<<<gE2h, 128, 0, stream>>>(E2, edge_idx, node_emb,
        wpack + (size_t)l*65536,
        ly_hid_b1 + (size_t)l*128, ly_hid_b2 + (size_t)l*128, ly_hid_b3 + (size_t)l*128,
        edge_hidden);

    rdl_kernel<<<gE, 256, 0, stream>>>(E, env_hidden, ud_env,
        ly_rdl_W1 + (size_t)l*192*64, ly_rdl_b1 + (size_t)l*64,
        ly_rdl_W2 + (size_t)l*64*64,  ly_rdl_b2 + (size_t)l*64,
        ly_rdl_W3 + (size_t)l*64*64,  ly_rdl_b3 + (size_t)l*64,
        ly_eln_g + (size_t)l*64, ly_eln_b + (size_t)l*64, env_radial);
    rdl_kernel<<<gE2, 256, 0, stream>>>(E2, edge_hidden, ud_edge,
        ly_rdl_W1 + (size_t)l*192*64, ly_rdl_b1 + (size_t)l*64,
        ly_rdl_W2 + (size_t)l*64*64,  ly_rdl_b2 + (size_t)l*64,
        ly_rdl_W3 + (size_t)l*64*64,  ly_rdl_b3 + (size_t)l*64,
        ly_eln_g + (size_t)l*64, ly_eln_b + (size_t)l*64, edge_radial);
  }
}

// Round 3
// 3016.956 us; speedup vs baseline: 2.5054x; 1.5433x over previous
//
#include <hip/hip_runtime.h>
#include <math.h>

#define C_RES 0.89442719f
#define C_NEW 0.4472f
#define LN_EPS 1e-5f
#define BESSEL_PREF 0.6324555320336759f  // sqrt(2/5)
#define RC_INV 0.2f

typedef __attribute__((ext_vector_type(8))) short short8;
typedef __attribute__((ext_vector_type(8))) unsigned short u16x8;
typedef __attribute__((ext_vector_type(16))) float f32x16;

__device__ __forceinline__ float fast_tanh(float x) {
  float ax = fabsf(x);
  float e = __expf(2.0f * ax);
  float t = 1.0f - 2.0f / (e + 1.0f);
  return copysignf(t, x);
}

__device__ __forceinline__ unsigned short f2b(float f) {
  unsigned int u = __float_as_uint(f);
  unsigned int r = (u + 0x7FFFu + ((u >> 16) & 1u)) >> 16;
  return (unsigned short)r;
}

__device__ __forceinline__ float poly_cutoff(float x) {
  float xr = x * RC_INV;
  if (xr >= 1.0f) return 0.0f;
  float x2 = xr * xr;
  float x3 = x2 * xr;
  float x6 = x3 * x3;
  return 1.0f - 28.0f * x6 + 48.0f * x6 * xr - 21.0f * x6 * x2;
}

// A-frag slot swizzle: spreads the strided aliasing of the C/D->A scatter
// writes across banks; reads stay a permutation (conflict-free).
__device__ __forceinline__ int swz(int s, int kc) {
  return s ^ ((s >> 5) << 1) ^ ((kc & 1) << 2);
}

__global__ void zero_kernel(float* __restrict__ p, size_t n) {
  size_t i = (size_t)blockIdx.x * blockDim.x + threadIdx.x;
  size_t stride = (size_t)gridDim.x * blockDim.x;
  for (; i < n; i += stride) p[i] = 0.0f;
}

// ---------------- pack hidden-MLP weights into bf16 MFMA B-fragment order ----
// Per layer (65536 ushorts): W1 [256x128] at 0, W2 [128x128] at 32768, W3 at 49152.
// Block layout: blk = kc*4 + ct; within blk: lane = (col&31) + 32*((k>>3)&1), j = k&7.
__global__ void pack_hid_weights(const float* __restrict__ W1,
                                 const float* __restrict__ W2,
                                 const float* __restrict__ W3,
                                 unsigned short* __restrict__ out)
{
  int t = blockIdx.x * 256 + threadIdx.x;  // 0..131071
  if (t >= 131072) return;
  int l = t >> 16;
  int oidx = t & 65535;
  const float* src;
  int midx;
  if (oidx < 32768)      { src = W1 + l * 32768; midx = oidx; }
  else if (oidx < 49152) { src = W2 + l * 16384; midx = oidx - 32768; }
  else                   { src = W3 + l * 16384; midx = oidx - 49152; }
  int j = midx & 7;
  int lane = (midx >> 3) & 63;
  int blk = midx >> 9;
  int ct = blk & 3, kc = blk >> 2;
  int col = ct * 32 + (lane & 31);
  int k = kc * 16 + (lane >> 5) * 8 + j;
  out[l * 65536 + oidx] = f2b(src[k * 128 + col]);
}

// ---------------- pack radial-ResNet weights, N=64 (ct in 0..1) --------------
// Per layer (20480 ushorts): W1 [192x64] at 0 (24 blks), W2 [64x64] at 12288
// (8 blks), W3 [64x64] at 16384 (8 blks). blk = kc*2 + ct.
__global__ void pack_rdl_weights(const float* __restrict__ W1,
                                 const float* __restrict__ W2,
                                 const float* __restrict__ W3,
                                 unsigned short* __restrict__ out)
{
  int t = blockIdx.x * 256 + threadIdx.x;  // 0..40959
  if (t >= 40960) return;
  int l = t / 20480;
  int o = t - l * 20480;
  const float* src;
  int midx;
  if (o < 12288)      { src = W1 + l * 12288; midx = o; }
  else if (o < 16384) { src = W2 + l * 4096;  midx = o - 12288; }
  else                { src = W3 + l * 4096;  midx = o - 16384; }
  int j = midx & 7;
  int lane = (midx >> 3) & 63;
  int blk = midx >> 9;
  int ct = blk & 1, kc = blk >> 1;
  int col = ct * 32 + (lane & 31);
  int k = kc * 16 + (lane >> 5) * 8 + j;
  out[l * 20480 + o] = f2b(src[k * 64 + col]);
}

// ---------------- stage-A: features + sr/rd MLPs + LN + msg scatter ----------
// 32 rows per block, 256 threads.

#define STAGE_W(SRC, NF) do {                                                   \
    __syncthreads();                                                            \
    for (int i_ = tid; i_ < (NF); i_ += 256) wbuf[i_] = (SRC)[i_];              \
    __syncthreads();                                                            \
  } while (0)

#define MM_2x4(SRCARR, KDIM, WSTR, BIASP, DOTANH, DSTARR) do {                  \
    const int r0_ = (tid >> 4) * 2, j0_ = (tid & 15) * 4;                       \
    float a00 = (BIASP)[j0_],   a01 = (BIASP)[j0_+1];                           \
    float a02 = (BIASP)[j0_+2], a03 = (BIASP)[j0_+3];                           \
    float a10 = a00, a11 = a01, a12 = a02, a13 = a03;                           \
    for (int k_ = 0; k_ < (KDIM); ++k_) {                                       \
      const float s0_ = SRCARR[r0_][k_], s1_ = SRCARR[r0_+1][k_];               \
      const float4 w_ = *(const float4*)&wbuf[k_*(WSTR) + j0_];                 \
      a00 += s0_*w_.x; a01 += s0_*w_.y; a02 += s0_*w_.z; a03 += s0_*w_.w;       \
      a10 += s1_*w_.x; a11 += s1_*w_.y; a12 += s1_*w_.z; a13 += s1_*w_.w;       \
    }                                                                           \
    if (DOTANH) {                                                               \
      a00 = fast_tanh(a00); a01 = fast_tanh(a01);                               \
      a02 = fast_tanh(a02); a03 = fast_tanh(a03);                               \
      a10 = fast_tanh(a10); a11 = fast_tanh(a11);                               \
      a12 = fast_tanh(a12); a13 = fast_tanh(a13);                               \
    }                                                                           \
    DSTARR[r0_][j0_]   = a00; DSTARR[r0_][j0_+1]   = a01;                       \
    DSTARR[r0_][j0_+2] = a02; DSTARR[r0_][j0_+3]   = a03;                       \
    DSTARR[r0_+1][j0_]   = a10; DSTARR[r0_+1][j0_+1] = a11;                     \
    DSTARR[r0_+1][j0_+2] = a12; DSTARR[r0_+1][j0_+3] = a13;                     \
  } while (0)

template<int HAS_SR>
__launch_bounds__(256)
__global__ void feat_mlp_kernel(
    int nrows,
    const int* __restrict__ types, const float* __restrict__ lens,
    const float* __restrict__ vecs, const int* __restrict__ idx,
    const float* __restrict__ bessel_w,
    const float* __restrict__ srW1, const float* __restrict__ srb1,
    const float* __restrict__ srW2, const float* __restrict__ srb2,
    const float* __restrict__ srW3, const float* __restrict__ srb3,
    const float* __restrict__ rdW1, const float* __restrict__ rdb1,
    const float* __restrict__ rdW2, const float* __restrict__ rdb2,
    const float* __restrict__ rdW3, const float* __restrict__ rdb3,
    const float* __restrict__ eln_g, const float* __restrict__ eln_b,
    float* __restrict__ radial_out, float* __restrict__ ud_out,
    float* __restrict__ aggS, float* __restrict__ cnt)
{
  __shared__ float feat[32][25];
  __shared__ float bufA[32][65];
  __shared__ float bufB[32][65];
  __shared__ __align__(16) float wbuf[4096];
  __shared__ float sval[32][17];
  __shared__ float evud[32][3];
  __shared__ float udl[32];
  __shared__ int   i1l[32];
  __shared__ float rstat[32][2];

  const int tid = threadIdx.x;
  const int base = blockIdx.x * 32;

  if (tid < 32) {
    const int r = tid;
    const int row = base + r;
    const bool valid = row < nrows;
    float len = 1.0f, ud = 0.0f;
    int i0 = 0, i1 = 0;
    if (valid) {
      i0 = idx[row];
      i1 = idx[nrows + row];
      len = lens[row];
      ud = poly_cutoff(len);
    }
    const int t0 = valid ? types[i0] : -1;
    const int t1 = valid ? types[i1] : -1;
    #pragma unroll
    for (int a = 0; a < 4; ++a) {
      feat[r][a]     = (t0 == a) ? 1.0f : 0.0f;
      feat[r][4 + a] = (t1 == a) ? 1.0f : 0.0f;
    }
    const float invl = 1.0f / len;
    #pragma unroll
    for (int k = 0; k < 16; ++k) {
      feat[r][8 + k] = valid ? ud * BESSEL_PREF * sinf(bessel_w[k] * len * RC_INV) * invl : 0.0f;
    }
    udl[r] = ud;
    i1l[r] = i1;
    if (valid) {
      ud_out[row] = ud;
      if (HAS_SR) {
        evud[r][0] = ud * vecs[(size_t)row*3 + 0];
        evud[r][1] = ud * vecs[(size_t)row*3 + 1];
        evud[r][2] = ud * vecs[(size_t)row*3 + 2];
        atomicAdd(&cnt[i1], 1.0f);
      }
    }
  }

  if (HAS_SR) {
    STAGE_W(srW1, 24*64);
    MM_2x4(feat, 24, 64, srb1, true, bufA);
    STAGE_W(srW2, 64*64);
    MM_2x4(bufA, 64, 64, srb2, true, bufB);
    STAGE_W(srW3, 64*16);
    {
      const int r = tid & 31;
      const int j = (tid >> 5) * 2;
      float a0 = srb3[j], a1 = srb3[j + 1];
      for (int k = 0; k < 64; ++k) {
        const float v = bufB[r][k];
        a0 += v * wbuf[k*16 + j];
        a1 += v * wbuf[k*16 + j + 1];
      }
      const float u = udl[r];
      sval[r][j]   = a0 * u;
      sval[r][j+1] = a1 * u;
    }
  }

  STAGE_W(rdW1, 24*64);
  MM_2x4(feat, 24, 64, rdb1, true, bufA);
  STAGE_W(rdW2, 64*64);
  MM_2x4(bufA, 64, 64, rdb2, true, bufB);
  STAGE_W(rdW3, 64*64);
  MM_2x4(bufB, 64, 64, rdb3, false, bufA);
  __syncthreads();
  if (tid < 32) {
    float s = 0.0f, ss = 0.0f;
    for (int k = 0; k < 64; ++k) { const float v = bufA[tid][k]; s += v; ss += v*v; }
    const float m = s * (1.0f/64.0f);
    const float var = ss * (1.0f/64.0f) - m*m;
    rstat[tid][0] = m;
    rstat[tid][1] = rsqrtf(var + LN_EPS);
  }
  __syncthreads();
  {
    const int r0 = (tid >> 4) * 2, j0 = (tid & 15) * 4;
    #pragma unroll
    for (int i = 0; i < 2; ++i) {
      const int r = r0 + i, row = base + r;
      if (row < nrows) {
        const float m = rstat[r][0], inv = rstat[r][1], u = udl[r];
        float4 v;
        v.x = ((bufA[r][j0]   - m)*inv*eln_g[j0]   + eln_b[j0])   * u;
        v.y = ((bufA[r][j0+1] - m)*inv*eln_g[j0+1] + eln_b[j0+1]) * u;
        v.z = ((bufA[r][j0+2] - m)*inv*eln_g[j0+2] + eln_b[j0+2]) * u;
        v.w = ((bufA[r][j0+3] - m)*inv*eln_g[j0+3] + eln_b[j0+3]) * u;
        *(float4*)&radial_out[(size_t)row*64 + j0] = v;
      }
    }
  }
  if (HAS_SR) {
    const int r = tid >> 3, q = tid & 7;
    const int row = base + r;
    if (row < nrows) {
      const size_t bo = (size_t)i1l[r] * 48;
      #pragma unroll
      for (int m6 = 0; m6 < 6; ++m6) {
        const int id = q*6 + m6;
        const int d = id / 3, c = id - d*3;
        atomicAdd(&aggS[bo + id], sval[r][d] * evud[r][c]);
      }
    }
  }
}

// ---------------- node embedding (gram + LN) ---------------------------------

__device__ __forceinline__ void block128_stats(float x, float& m, float& inv, float* red) {
  float s = x, ss = x*x;
  #pragma unroll
  for (int o = 32; o; o >>= 1) { s += __shfl_down(s, o); ss += __shfl_down(ss, o); }
  const int t = threadIdx.x;
  if ((t & 63) == 0) { red[(t >> 6)*2] = s; red[(t >> 6)*2 + 1] = ss; }
  __syncthreads();
  const float S = red[0] + red[2], SS = red[1] + red[3];
  m = S * (1.0f/128.0f);
  const float var = SS * (1.0f/128.0f) - m*m;
  inv = rsqrtf(var + LN_EPS);
}

__launch_bounds__(128)
__global__ void node_emb_kernel(int N, const float* __restrict__ aggS,
                                const float* __restrict__ cnt,
                                const float* __restrict__ g, const float* __restrict__ b,
                                float* __restrict__ node_emb)
{
  const int n = blockIdx.x, t = threadIdx.x;
  __shared__ float S[48];
  __shared__ float red[4];
  if (t < 48) S[t] = aggS[(size_t)n*48 + t];
  __syncthreads();
  const float ic = 1.0f / fmaxf(cnt[n], 1.0f);
  const int d = t >> 3, e = t & 7;
  const float x = (S[d*3+0]*S[e*3+0] + S[d*3+1]*S[e*3+1] + S[d*3+2]*S[e*3+2]) * ic * ic;
  float m, inv;
  block128_stats(x, m, inv, red);
  node_emb[(size_t)n*128 + t] = (x - m)*inv*g[t] + b[t];
}

__launch_bounds__(128)
__global__ void node_update_kernel(int N, const float* __restrict__ aggsum,
                                   const float* __restrict__ cnt,
                                   const float* __restrict__ g, const float* __restrict__ b,
                                   float* __restrict__ node_emb)
{
  const int n = blockIdx.x, t = threadIdx.x;
  __shared__ float red[4];
  const float old = node_emb[(size_t)n*128 + t];
  const float x = old * (aggsum[(size_t)n*128 + t] / fmaxf(cnt[n], 1.0f));
  float m, inv;
  block128_stats(x, m, inv, red);
  node_emb[(size_t)n*128 + t] = C_RES*old + C_NEW*((x - m)*inv*g[t] + b[t]);
}

// ---------------- embedding GEMM (K=64 -> N=128), two epilogues --------------

template<int MODE>
__launch_bounds__(256)
__global__ void emb_gemm_kernel(
    int nrows,
    const float* __restrict__ radial,
    const float* __restrict__ W, const float* __restrict__ bias,
    const int* __restrict__ idx,
    const float* __restrict__ node_emb,
    float* __restrict__ out)
{
  __shared__ float lin[32][65];
  __shared__ __align__(16) float lw[64*128];
  const int tid = threadIdx.x;
  const int base = blockIdx.x * 32;

  for (int i = tid; i < 64*128; i += 256) lw[i] = W[i];
  {
    const int rr0 = tid >> 6, k = tid & 63;
    for (int rr = rr0; rr < 32; rr += 4) {
      const int row = base + rr;
      lin[rr][k] = (row < nrows) ? radial[(size_t)row*64 + k] : 0.0f;
    }
  }
  __syncthreads();

  const int r0 = (tid >> 5) * 4, j0 = (tid & 31) * 4;
  float acc[4][4];
  #pragma unroll
  for (int j = 0; j < 4; ++j) {
    const float bj = bias[j0 + j];
    acc[0][j] = bj; acc[1][j] = bj; acc[2][j] = bj; acc[3][j] = bj;
  }
  for (int k = 0; k < 64; ++k) {
    const float4 w = *(const float4*)&lw[k*128 + j0];
    const float s0 = lin[r0][k],   s1 = lin[r0+1][k];
    const float s2 = lin[r0+2][k], s3 = lin[r0+3][k];
    acc[0][0] += s0*w.x; acc[0][1] += s0*w.y; acc[0][2] += s0*w.z; acc[0][3] += s0*w.w;
    acc[1][0] += s1*w.x; acc[1][1] += s1*w.y; acc[1][2] += s1*w.z; acc[1][3] += s1*w.w;
    acc[2][0] += s2*w.x; acc[2][1] += s2*w.y; acc[2][2] += s2*w.z; acc[2][3] += s2*w.w;
    acc[3][0] += s3*w.x; acc[3][1] += s3*w.y; acc[3][2] += s3*w.z; acc[3][3] += s3*w.w;
  }
  #pragma unroll
  for (int i = 0; i < 4; ++i) {
    const int row = base + r0 + i;
    if (row >= nrows) continue;
    if (MODE == 0) {
      const int i0 = idx[row], i1 = idx[nrows + row];
      const float4 n0 = *(const float4*)&node_emb[(size_t)i0*128 + j0];
      const float4 n1 = *(const float4*)&node_emb[(size_t)i1*128 + j0];
      float4 o;
      o.x = acc[i][0] * 0.5f * (n0.x + n1.x);
      o.y = acc[i][1] * 0.5f * (n0.y + n1.y);
      o.z = acc[i][2] * 0.5f * (n0.z + n1.z);
      o.w = acc[i][3] * 0.5f * (n0.w + n1.w);
      *(float4*)&out[(size_t)row*128 + j0] = o;
    } else {
      const int i1 = idx[nrows + row];
      float* p = &out[(size_t)i1*128 + j0];
      atomicAdd(p + 0, acc[i][0]);
      atomicAdd(p + 1, acc[i][1]);
      atomicAdd(p + 2, acc[i][2]);
      atomicAdd(p + 3, acc[i][3]);
    }
  }
}

// ---------------- hidden MLP via bf16 MFMA -----------------------------------

__launch_bounds__(128)
__global__ void hid_mlp_mfma(
    int nrows, const int* __restrict__ idx0,
    const float* __restrict__ node_emb,
    const unsigned short* __restrict__ wpack,   // 65536 ushorts for this layer
    const float* __restrict__ b1, const float* __restrict__ b2,
    const float* __restrict__ b3,
    float* __restrict__ hidden)
{
  __shared__ __align__(16) unsigned short h_afrag[16384];  // 32KB: [rt4][kc8]*512
  __shared__ __align__(16) unsigned short xg[4096];        // 8KB:  [rt4][kcl2]*512
  __shared__ __align__(16) unsigned short wg[4096];        // 8KB:  [kcl2][ct4]*512

  const int tid  = threadIdx.x;
  const int lane = tid & 63;
  const int wave = tid >> 6;
  const int base = blockIdx.x * 128;

  const int r = tid;                       // staging row 0..127
  int rowg = base + r;
  if (rowg >= nrows) rowg = nrows - 1;
  const int i0 = idx0[rowg];
  const float* xsrc0 = node_emb + (size_t)i0 * 128;
  const float* xsrc1 = hidden + (size_t)rowg * 128;

  f32x16 acc[2][4];

  // ---------- layer 1: K=256, 8 phases x (2 kc) ----------
  #pragma unroll
  for (int ct = 0; ct < 4; ++ct) {
    const float bv = b1[ct*32 + (lane & 31)];
    #pragma unroll
    for (int q = 0; q < 16; ++q) { acc[0][ct][q] = bv; acc[1][ct][q] = bv; }
  }
  for (int p = 0; p < 8; ++p) {
    __syncthreads();
    #pragma unroll
    for (int o = 0; o < 4; ++o) {
      const int k = p*32 + o*8;
      const float* s = (k < 128) ? (xsrc0 + k) : (xsrc1 + (k - 128));
      const float4 v0 = *(const float4*)s;
      const float4 v1 = *(const float4*)(s + 4);
      u16x8 w;
      w[0]=f2b(v0.x); w[1]=f2b(v0.y); w[2]=f2b(v0.z); w[3]=f2b(v0.w);
      w[4]=f2b(v1.x); w[5]=f2b(v1.y); w[6]=f2b(v1.z); w[7]=f2b(v1.w);
      const int kc = p*2 + (o >> 1);
      const int s_ = (r & 31) + 32*(o & 1);
      *(u16x8*)&xg[ ((r>>5)*2 + (o>>1))*512 + swz(s_, kc)*8 ] = w;
    }
    #pragma unroll
    for (int i = 0; i < 4; ++i) {
      const int c = tid + i*128;
      *(u16x8*)&wg[c*8] = *(const u16x8*)&wpack[p*4096 + c*8];
    }
    __syncthreads();
    #pragma unroll
    for (int kcl = 0; kcl < 2; ++kcl) {
      const int kc = p*2 + kcl;
      const short8 a0 = *(const short8*)&xg[ ((wave*2+0)*2 + kcl)*512 + swz(lane, kc)*8 ];
      const short8 a1 = *(const short8*)&xg[ ((wave*2+1)*2 + kcl)*512 + swz(lane, kc)*8 ];
      #pragma unroll
      for (int ct = 0; ct < 4; ++ct) {
        const short8 b = *(const short8*)&wg[ (kcl*4 + ct)*512 + lane*8 ];
        acc[0][ct] = __builtin_amdgcn_mfma_f32_32x32x16_bf16(a0, b, acc[0][ct], 0, 0, 0);
        acc[1][ct] = __builtin_amdgcn_mfma_f32_32x32x16_bf16(a1, b, acc[1][ct], 0, 0, 0);
      }
    }
  }

  // ---------- transition 1: tanh -> h_afrag ----------
  __syncthreads();
  #pragma unroll
  for (int m = 0; m < 2; ++m) {
    const int rt = wave*2 + m;
    #pragma unroll
    for (int ct = 0; ct < 4; ++ct) {
      const int kc  = ct*2 + ((lane >> 4) & 1);
      const int oct = (lane >> 3) & 1;
      const int j   = lane & 7;
      const int xk  = (oct << 1) ^ ((kc & 1) << 2);
      const int hi  = 4*(lane >> 5);
      const int bi  = (rt*8 + kc)*512 + oct*256 + j;
      #pragma unroll
      for (int q = 0; q < 16; ++q) {
        const int m32 = (q & 3) + 8*(q >> 2) + hi;
        h_afrag[bi + (m32 ^ xk)*8] = f2b(fast_tanh(acc[m][ct][q]));
      }
    }
  }
  #pragma unroll
  for (int ct = 0; ct < 4; ++ct) {
    const float bv = b2[ct*32 + (lane & 31)];
    #pragma unroll
    for (int q = 0; q < 16; ++q) { acc[0][ct][q] = bv; acc[1][ct][q] = bv; }
  }
  __syncthreads();

  // ---------- layer 2: K=128, 4 phases x (2 kc) ----------
  for (int p = 0; p < 4; ++p) {
    __syncthreads();
    #pragma unroll
    for (int i = 0; i < 4; ++i) {
      const int c = tid + i*128;
      *(u16x8*)&wg[c*8] = *(const u16x8*)&wpack[32768 + p*4096 + c*8];
    }
    __syncthreads();
    #pragma unroll
    for (int kcl = 0; kcl < 2; ++kcl) {
      const int kc = p*2 + kcl;
      const short8 a0 = *(const short8*)&h_afrag[ ((wave*2+0)*8 + kc)*512 + swz(lane, kc)*8 ];
      const short8 a1 = *(const short8*)&h_afrag[ ((wave*2+1)*8 + kc)*512 + swz(lane, kc)*8 ];
      #pragma unroll
      for (int ct = 0; ct < 4; ++ct) {
        const short8 b = *(const short8*)&wg[ (kcl*4 + ct)*512 + lane*8 ];
        acc[0][ct] = __builtin_amdgcn_mfma_f32_32x32x16_bf16(a0, b, acc[0][ct], 0, 0, 0);
        acc[1][ct] = __builtin_amdgcn_mfma_f32_32x32x16_bf16(a1, b, acc[1][ct], 0, 0, 0);
      }
    }
  }

  // ---------- transition 2: tanh -> h_afrag (overwrite) ----------
  __syncthreads();
  #pragma unroll
  for (int m = 0; m < 2; ++m) {
    const int rt = wave*2 + m;
    #pragma unroll
    for (int ct = 0; ct < 4; ++ct) {
      const int kc  = ct*2 + ((lane >> 4) & 1);
      const int oct = (lane >> 3) & 1;
      const int j   = lane & 7;
      const int xk  = (oct << 1) ^ ((kc & 1) << 2);
      const int hi  = 4*(lane >> 5);
      const int bi  = (rt*8 + kc)*512 + oct*256 + j;
      #pragma unroll
      for (int q = 0; q < 16; ++q) {
        const int m32 = (q & 3) + 8*(q >> 2) + hi;
        h_afrag[bi + (m32 ^ xk)*8] = f2b(fast_tanh(acc[m][ct][q]));
      }
    }
  }
  #pragma unroll
  for (int ct = 0; ct < 4; ++ct) {
    const float bv = b3[ct*32 + (lane & 31)];
    #pragma unroll
    for (int q = 0; q < 16; ++q) { acc[0][ct][q] = bv; acc[1][ct][q] = bv; }
  }
  __syncthreads();

  // ---------- layer 3: K=128 ----------
  for (int p = 0; p < 4; ++p) {
    __syncthreads();
    #pragma unroll
    for (int i = 0; i < 4; ++i) {
      const int c = tid + i*128;
      *(u16x8*)&wg[c*8] = *(const u16x8*)&wpack[49152 + p*4096 + c*8];
    }
    __syncthreads();
    #pragma unroll
    for (int kcl = 0; kcl < 2; ++kcl) {
      const int kc = p*2 + kcl;
      const short8 a0 = *(const short8*)&h_afrag[ ((wave*2+0)*8 + kc)*512 + swz(lane, kc)*8 ];
      const short8 a1 = *(const short8*)&h_afrag[ ((wave*2+1)*8 + kc)*512 + swz(lane, kc)*8 ];
      #pragma unroll
      for (int ct = 0; ct < 4; ++ct) {
        const short8 b = *(const short8*)&wg[ (kcl*4 + ct)*512 + lane*8 ];
        acc[0][ct] = __builtin_amdgcn_mfma_f32_32x32x16_bf16(a0, b, acc[0][ct], 0, 0, 0);
        acc[1][ct] = __builtin_amdgcn_mfma_f32_32x32x16_bf16(a1, b, acc[1][ct], 0, 0, 0);
      }
    }
  }

  // ---------- epilogue: store f32 ----------
  #pragma unroll
  for (int m = 0; m < 2; ++m) {
    #pragma unroll
    for (int ct = 0; ct < 4; ++ct) {
      const int col = ct*32 + (lane & 31);
      #pragma unroll
      for (int q = 0; q < 16; ++q) {
        const int row = base + (wave*2+m)*32 + (q & 3) + 8*(q >> 2) + 4*(lane >> 5);
        if (row < nrows) hidden[(size_t)row*128 + col] = acc[m][ct][q];
      }
    }
  }
}

// ---------------- radial ResNet via bf16 MFMA --------------------------------
// 96 rows/block, 192 threads (3 waves). Wave w owns row-tile w, col-tiles 0,1.
// All weights (40KB) + all A-frags (36KB) staged once -> single barrier.
// Inter-layer transitions are wave-local (own row-tile only). LN via
// __shfl_xor butterfly (all 32 lanes of a half share a row per reg q).

__launch_bounds__(192)
__global__ void rdl_mfma(
    int nrows,
    const float* __restrict__ hidden, const float* __restrict__ ud,
    const unsigned short* __restrict__ wpack,   // 20480 ushorts this layer
    const float* __restrict__ b1, const float* __restrict__ b2,
    const float* __restrict__ b3,
    const float* __restrict__ eln_g, const float* __restrict__ eln_b,
    float* __restrict__ radial)
{
  // afrag block (kc, rt) at (kc*3+rt)*512. kc 0..3: radial (kept for epilogue);
  // kc 4..7: hidden -> overwritten by layer-2 input frags; kc 8..11: hidden ->
  // overwritten by layer-3 input frags.
  __shared__ __align__(16) unsigned short afrag[36*512];  // 36KB
  __shared__ __align__(16) unsigned short wlds[40*512];   // 40KB
  __shared__ float udl[96];

  const int tid  = threadIdx.x;    // 0..191
  const int lane = tid & 63;
  const int wave = tid >> 6;       // rt
  const int base = blockIdx.x * 96;
  const int cl   = lane & 31;

  // ---- stage all packed weights (40 blocks) ----
  for (int i = tid; i < 2560; i += 192) {
    *(u16x8*)&wlds[i*8] = *(const u16x8*)&wpack[i*8];
  }
  // ---- stage input A-frags: [radial(64) | hidden(128)] ----
  {
    const int r  = tid >> 1;       // 0..95
    const int kh = tid & 1;
    int rowg = base + r;
    if (rowg >= nrows) rowg = nrows - 1;
    const float* rsrc = radial + (size_t)rowg * 64;
    const float* hsrc = hidden + (size_t)rowg * 128;
    if (kh == 0) udl[r] = ud[rowg];
    #pragma unroll
    for (int g = 0; g < 12; ++g) {
      const int k = kh*96 + g*8;
      const float* s = (k < 64) ? (rsrc + k) : (hsrc + (k - 64));
      const float4 v0 = *(const float4*)s;
      const float4 v1 = *(const float4*)(s + 4);
      u16x8 w;
      w[0]=f2b(v0.x); w[1]=f2b(v0.y); w[2]=f2b(v0.z); w[3]=f2b(v0.w);
      w[4]=f2b(v1.x); w[5]=f2b(v1.y); w[6]=f2b(v1.z); w[7]=f2b(v1.w);
      const int kc = k >> 4;
      const int s_ = (r & 31) + 32*((k >> 3) & 1);
      *(u16x8*)&afrag[(kc*3 + (r>>5))*512 + swz(s_, kc)*8] = w;
    }
  }
  __syncthreads();   // the only block-wide barrier

  // ---- layer 1: K=192, out 64 (tanh) ----
  f32x16 acc0, acc1;
  {
    const float bv0 = b1[cl], bv1 = b1[32 + cl];
    #pragma unroll
    for (int q = 0; q < 16; ++q) { acc0[q] = bv0; acc1[q] = bv1; }
  }
  #pragma unroll
  for (int kc = 0; kc < 12; ++kc) {
    const short8 a  = *(const short8*)&afrag[(kc*3 + wave)*512 + swz(lane, kc)*8];
    const short8 w0 = *(const short8*)&wlds[(kc*2 + 0)*512 + lane*8];
    const short8 w1 = *(const short8*)&wlds[(kc*2 + 1)*512 + lane*8];
    acc0 = __builtin_amdgcn_mfma_f32_32x32x16_bf16(a, w0, acc0, 0, 0, 0);
    acc1 = __builtin_amdgcn_mfma_f32_32x32x16_bf16(a, w1, acc1, 0, 0, 0);
  }

  // ---- transition 1 (wave-local): tanh -> A-frags at blocks (4+kc2, wave) ----
  #pragma unroll
  for (int ct = 0; ct < 2; ++ct) {
    const int colh = ct*32 + cl;
    const int kc2  = colh >> 4;
    const int b3_  = (colh >> 3) & 1;
    const int jj   = colh & 7;
    const int blk  = ((4 + kc2)*3 + wave)*512;
    #pragma unroll
    for (int q = 0; q < 16; ++q) {
      const int row32 = (q & 3) + 8*(q >> 2) + 4*(lane >> 5);
      const int s_ = (row32 & 31) + 32*b3_;
      const float v = ct ? acc1[q] : acc0[q];
      afrag[blk + swz(s_, kc2)*8 + jj] = f2b(fast_tanh(v));
    }
  }

  // ---- layer 2: K=64, out 64 (no tanh) -> h kept in regs ----
  f32x16 h0, h1;
  {
    const float bv0 = b2[cl], bv1 = b2[32 + cl];
    #pragma unroll
    for (int q = 0; q < 16; ++q) { h0[q] = bv0; h1[q] = bv1; }
  }
  #pragma unroll
  for (int kc = 0; kc < 4; ++kc) {
    const short8 a  = *(const short8*)&afrag[((4 + kc)*3 + wave)*512 + swz(lane, kc)*8];
    const short8 w0 = *(const short8*)&wlds[(24 + kc*2 + 0)*512 + lane*8];
    const short8 w1 = *(const short8*)&wlds[(24 + kc*2 + 1)*512 + lane*8];
    h0 = __builtin_amdgcn_mfma_f32_32x32x16_bf16(a, w0, h0, 0, 0, 0);
    h1 = __builtin_amdgcn_mfma_f32_32x32x16_bf16(a, w1, h1, 0, 0, 0);
  }

  // ---- transition 2 (wave-local): tanh(h) -> A-frags at blocks (8+kc2, wave) --
  #pragma unroll
  for (int ct = 0; ct < 2; ++ct) {
    const int colh = ct*32 + cl;
    const int kc2  = colh >> 4;
    const int b3_  = (colh >> 3) & 1;
    const int jj   = colh & 7;
    const int blk  = ((8 + kc2)*3 + wave)*512;
    #pragma unroll
    for (int q = 0; q < 16; ++q) {
      const int row32 = (q & 3) + 8*(q >> 2) + 4*(lane >> 5);
      const int s_ = (row32 & 31) + 32*b3_;
      const float v = ct ? h1[q] : h0[q];
      afrag[blk + swz(s_, kc2)*8 + jj] = f2b(fast_tanh(v));
    }
  }

  // ---- layer 3: K=64, out = tanh(h)@W3 + b3 (+ h later) ----
  {
    const float bv0 = b3[cl], bv1 = b3[32 + cl];
    #pragma unroll
    for (int q = 0; q < 16; ++q) { acc0[q] = bv0; acc1[q] = bv1; }
  }
  #pragma unroll
  for (int kc = 0; kc < 4; ++kc) {
    const short8 a  = *(const short8*)&afrag[((8 + kc)*3 + wave)*512 + swz(lane, kc)*8];
    const short8 w0 = *(const short8*)&wlds[(32 + kc*2 + 0)*512 + lane*8];
    const short8 w1 = *(const short8*)&wlds[(32 + kc*2 + 1)*512 + lane*8];
    acc0 = __builtin_amdgcn_mfma_f32_32x32x16_bf16(a, w0, acc0, 0, 0, 0);
    acc1 = __builtin_amdgcn_mfma_f32_32x32x16_bf16(a, w1, acc1, 0, 0, 0);
  }

  // ---- epilogue: +h, LN (shfl butterfly), residual-scale, store ----
  const float eg0 = eln_g[cl],      eb0 = eln_b[cl];
  const float eg1 = eln_g[32 + cl], eb1 = eln_b[32 + cl];
  const int kcA = cl >> 4;                 // old-radial frag indices
  const int kcB = (32 + cl) >> 4;
  const int jA  = cl & 7;
  const int jB  = cl & 7;
  const int bA  = (kcA*3 + wave)*512;
  const int bB  = (kcB*3 + wave)*512;
  const int b3A = (cl >> 3) & 1;
  const int b3B = ((32 + cl) >> 3) & 1;

  #pragma unroll
  for (int q = 0; q < 16; ++q) {
    const float v0 = acc0[q] + h0[q];
    const float v1 = acc1[q] + h1[q];
    float s = v0 + v1, ss = v0*v0 + v1*v1;
    #pragma unroll
    for (int o = 1; o <= 16; o <<= 1) {
      s  += __shfl_xor(s, o);
      ss += __shfl_xor(ss, o);
    }
    const float m   = s * (1.0f/64.0f);
    const float inv = rsqrtf(ss * (1.0f/64.0f) - m*m + LN_EPS);
    const int row32 = (q & 3) + 8*(q >> 2) + 4*(lane >> 5);
    const int rloc  = wave*32 + row32;
    const int row   = base + rloc;
    if (row < nrows) {
      const float u = udl[rloc];
      const int sA = (row32 & 31) + 32*b3A;
      const int sB = (row32 & 31) + 32*b3B;
      const float oldA = __uint_as_float((unsigned)afrag[bA + swz(sA, kcA)*8 + jA] << 16);
      const float oldB = __uint_as_float((unsigned)afrag[bB + swz(sB, kcB)*8 + jB] << 16);
      radial[(size_t)row*64 + cl]      = C_RES*oldA + C_NEW*u*((v0 - m)*inv*eg0 + eb0);
      radial[(size_t)row*64 + 32 + cl] = C_RES*oldB + C_NEW*u*((v1 - m)*inv*eg1 + eb1);
    }
  }
}

// ---------------- launch -----------------------------------------------------

extern "C" void kernel_launch(void* const* d_in, const int* in_sizes, int n_in,
                              void* d_out, int out_size, void* d_ws, size_t ws_size,
                              hipStream_t stream)
{
  const int*   atom_types = (const int*)  d_in[0];
  const float* env_vec    = (const float*)d_in[1];
  const float* env_len    = (const float*)d_in[2];
  const float* edge_len   = (const float*)d_in[3];
  const int*   env_idx    = (const int*)  d_in[4];
  const int*   edge_idx   = (const int*)  d_in[5];
  const float* bessel_w   = (const float*)d_in[6];
  const float* srW1 = (const float*)d_in[7];  const float* srb1 = (const float*)d_in[8];
  const float* srW2 = (const float*)d_in[9];  const float* srb2 = (const float*)d_in[10];
  const float* srW3 = (const float*)d_in[11]; const float* srb3 = (const float*)d_in[12];
  const float* rdW1 = (const float*)d_in[13]; const float* rdb1 = (const float*)d_in[14];
  const float* rdW2 = (const float*)d_in[15]; const float* rdb2 = (const float*)d_in[16];
  const float* rdW3 = (const float*)d_in[17]; const float* rdb3 = (const float*)d_in[18];
  const float* ne_emb_W = (const float*)d_in[19]; const float* ne_emb_b = (const float*)d_in[20];
  const float* ne_nln_g = (const float*)d_in[21]; const float* ne_nln_b = (const float*)d_in[22];
  const float* ne_eln_g = (const float*)d_in[23]; const float* ne_eln_b = (const float*)d_in[24];
  const float* ly_emb_W = (const float*)d_in[25]; const float* ly_emb_b = (const float*)d_in[26];
  const float* ly_hid_W1 = (const float*)d_in[27]; const float* ly_hid_b1 = (const float*)d_in[28];
  const float* ly_hid_W2 = (const float*)d_in[29]; const float* ly_hid_b2 = (const float*)d_in[30];
  const float* ly_hid_W3 = (const float*)d_in[31]; const float* ly_hid_b3 = (const float*)d_in[32];
  const float* ly_rdl_W1 = (const float*)d_in[33]; const float* ly_rdl_b1 = (const float*)d_in[34];
  const float* ly_rdl_W2 = (const float*)d_in[35]; const float* ly_rdl_b2 = (const float*)d_in[36];
  const float* ly_rdl_W3 = (const float*)d_in[37]; const float* ly_rdl_b3 = (const float*)d_in[38];
  const float* ly_nln_g = (const float*)d_in[39]; const float* ly_nln_b = (const float*)d_in[40];
  const float* ly_eln_g = (const float*)d_in[41]; const float* ly_eln_b = (const float*)d_in[42];

  const int N  = in_sizes[0];
  const int E  = in_sizes[2];
  const int E2 = in_sizes[3];

  float* out = (float*)d_out;
  float* env_radial  = out;
  float* edge_radial = env_radial + (size_t)E * 64;
  float* node_emb    = edge_radial + (size_t)E2 * 64;
  float* env_hidden  = node_emb + (size_t)N * 128;
  float* edge_hidden = env_hidden + (size_t)E * 128;

  float* ws = (float*)d_ws;
  float* ud_env  = ws;  ws += E;
  float* ud_edge = ws;  ws += E2;
  float* aggS    = ws;  ws += (size_t)N * 48;
  float* cnt     = ws;  ws += N;
  float* agg2    = ws;  ws += (size_t)N * 128;
  unsigned short* wpack = (unsigned short*)ws;  ws += 65536;   // hid: 2 x 65536 u16
  unsigned short* wpack2 = (unsigned short*)ws; ws += 20480;   // rdl: 2 x 20480 u16

  const int gE  = (E  + 31) / 32;
  const int gE2 = (E2 + 31) / 32;
  const int gEh  = (E  + 127) / 128;
  const int gE2h = (E2 + 127) / 128;
  const int gEr  = (E  + 95) / 96;
  const int gE2r = (E2 + 95) / 96;

  // zero aggS + cnt (contiguous)
  zero_kernel<<<1024, 256, 0, stream>>>(aggS, (size_t)N * 49);
  pack_hid_weights<<<512, 256, 0, stream>>>(ly_hid_W1, ly_hid_W2, ly_hid_W3, wpack);
  pack_rdl_weights<<<160, 256, 0, stream>>>(ly_rdl_W1, ly_rdl_W2, ly_rdl_W3, wpack2);

  feat_mlp_kernel<1><<<gE, 256, 0, stream>>>(E, atom_types, env_len, env_vec, env_idx, bessel_w,
      srW1, srb1, srW2, srb2, srW3, srb3, rdW1, rdb1, rdW2, rdb2, rdW3, rdb3,
      ne_eln_g, ne_eln_b, env_radial, ud_env, aggS, cnt);
  feat_mlp_kernel<0><<<gE2, 256, 0, stream>>>(E2, atom_types, edge_len, nullptr, edge_idx, bessel_w,
      srW1, srb1, srW2, srb2, srW3, srb3, rdW1, rdb1, rdW2, rdb2, rdW3, rdb3,
      ne_eln_g, ne_eln_b, edge_radial, ud_edge, nullptr, nullptr);

  node_emb_kernel<<<N, 128, 0, stream>>>(N, aggS, cnt, ne_nln_g, ne_nln_b, node_emb);

  emb_gemm_kernel<0><<<gE, 256, 0, stream>>>(E, env_radial, ne_emb_W, ne_emb_b, env_idx, node_emb, env_hidden);
  emb_gemm_kernel<0><<<gE2, 256, 0, stream>>>(E2, edge_radial, ne_emb_W, ne_emb_b, edge_idx, node_emb, edge_hidden);

  for (int l = 0; l < 2; ++l) {
    zero_kernel<<<1024, 256, 0, stream>>>(agg2, (size_t)N * 128);
    emb_gemm_kernel<1><<<gE, 256, 0, stream>>>(E, env_radial, ly_emb_W + (size_t)l*64*128,
        ly_emb_b + (size_t)l*128, env_idx, nullptr, agg2);
    node_update_kernel<<<N, 128, 0, stream>>>(N, agg2, cnt,
        ly_nln_g + (size_t)l*128, ly_nln_b + (size_t)l*128, node_emb);

    hid_mlp_mfma<<<gEh, 128, 0, stream>>>(E, env_idx, node_emb,
        wpack + (size_t)l*65536,
        ly_hid_b1 + (size_t)l*128, ly_hid_b2 + (size_t)l*128, ly_hid_b3 + (size_t)l*128,
        env_hidden);
    hid_mlp_mfma<<<gE2h, 128, 0, stream>>>(E2, edge_idx, node_emb,
        wpack + (size_t)l*65536,
        ly_hid_b1 + (size_t)l*128, ly_hid_b2 + (size_t)l*128, ly_hid_b3 + (size_t)l*128,
        edge_hidden);

    rdl_mfma<<<gEr, 192, 0, stream>>>(E, env_hidden, ud_env,
        wpack2 + (size_t)l*20480,
        ly_rdl_b1 + (size_t)l*64, ly_rdl_b2 + (size_t)l*64, ly_rdl_b3 + (size_t)l*64,
        ly_eln_g + (size_t)l*64, ly_eln_b + (size_t)l*64, env_radial);
    rdl_mfma<<<gE2r, 192, 0, stream>>>(E2, edge_hidden, ud_edge,
        wpack2 + (size_t)l*20480,
        ly_rdl_b1 + (size_t)l*64, ly_rdl_b2 + (size_t)l*64, ly_rdl_b3 + (size_t)l*64,
        ly_eln_g + (size_t)l*64, ly_eln_b + (size_t)l*64, edge_radial);
  }
}

// Round 4
// 2072.679 us; speedup vs baseline: 3.6469x; 1.4556x over previous
//
#include <hip/hip_runtime.h>
#include <math.h>

#define C_RES 0.89442719f
#define C_NEW 0.4472f
#define LN_EPS 1e-5f
#define BESSEL_PREF 0.6324555320336759f  // sqrt(2/5)
#define RC_INV 0.2f

typedef __attribute__((ext_vector_type(8))) short short8;
typedef __attribute__((ext_vector_type(8))) unsigned short u16x8;
typedef __attribute__((ext_vector_type(16))) float f32x16;

__device__ __forceinline__ float fast_tanh(float x) {
  float ax = fabsf(x);
  float e = __expf(2.0f * ax);
  float t = 1.0f - 2.0f / (e + 1.0f);
  return copysignf(t, x);
}

__device__ __forceinline__ unsigned short f2b(float f) {
  unsigned int u = __float_as_uint(f);
  unsigned int r = (u + 0x7FFFu + ((u >> 16) & 1u)) >> 16;
  return (unsigned short)r;
}

__device__ __forceinline__ float poly_cutoff(float x) {
  float xr = x * RC_INV;
  if (xr >= 1.0f) return 0.0f;
  float x2 = xr * xr;
  float x3 = x2 * xr;
  float x6 = x3 * x3;
  return 1.0f - 28.0f * x6 + 48.0f * x6 * xr - 21.0f * x6 * x2;
}

// A-frag slot swizzle: spreads the strided aliasing of the C/D->A scatter
// writes across banks; reads stay a permutation (conflict-free).
__device__ __forceinline__ int swz(int s, int kc) {
  return s ^ ((s >> 5) << 1) ^ ((kc & 1) << 2);
}

__global__ void zero_kernel(float* __restrict__ p, size_t n) {
  size_t i = (size_t)blockIdx.x * blockDim.x + threadIdx.x;
  size_t stride = (size_t)gridDim.x * blockDim.x;
  for (; i < n; i += stride) p[i] = 0.0f;
}

__global__ void zero_int_kernel(int* __restrict__ p, int n) {
  int i = blockIdx.x * blockDim.x + threadIdx.x;
  int stride = gridDim.x * blockDim.x;
  for (; i < n; i += stride) p[i] = 0;
}

// ---------------- CSR build: hist -> scan -> scatter --------------------------

__global__ void hist_kernel(int E, const int* __restrict__ idx, int* __restrict__ ecnt) {
  int t = blockIdx.x * 256 + threadIdx.x;
  if (t < E) atomicAdd(&ecnt[idx[E + t]], 1);
}

__launch_bounds__(1024)
__global__ void scan_kernel(const int* __restrict__ ecnt, int* __restrict__ eoff,
                            int* __restrict__ ecur, int n) {
  __shared__ int buf[1024];
  __shared__ int carry;
  const int tid = threadIdx.x;
  if (tid == 0) carry = 0;
  __syncthreads();
  for (int b0 = 0; b0 < n; b0 += 1024) {
    const int i = b0 + tid;
    const int v = (i < n) ? ecnt[i] : 0;
    buf[tid] = v;
    __syncthreads();
    #pragma unroll
    for (int o = 1; o < 1024; o <<= 1) {
      const int t = (tid >= o) ? buf[tid - o] : 0;
      __syncthreads();
      buf[tid] += t;
      __syncthreads();
    }
    const int c0 = carry;
    const int excl = c0 + buf[tid] - v;
    if (i < n) { eoff[i] = excl; ecur[i] = excl; }
    __syncthreads();
    if (tid == 1023) carry = c0 + buf[1023];
    __syncthreads();
  }
  if (tid == 0) eoff[n] = carry;
}

__global__ void scatter_kernel(int E, const int* __restrict__ idx,
                               int* __restrict__ ecur, int* __restrict__ perm) {
  int t = blockIdx.x * 256 + threadIdx.x;
  if (t < E) {
    const int pos = atomicAdd(&ecur[idx[E + t]], 1);
    perm[pos] = t;
  }
}

// ---------------- pack hidden-MLP weights into bf16 MFMA B-fragment order ----
__global__ void pack_hid_weights(const float* __restrict__ W1,
                                 const float* __restrict__ W2,
                                 const float* __restrict__ W3,
                                 unsigned short* __restrict__ out)
{
  int t = blockIdx.x * 256 + threadIdx.x;  // 0..131071
  if (t >= 131072) return;
  int l = t >> 16;
  int oidx = t & 65535;
  const float* src;
  int midx;
  if (oidx < 32768)      { src = W1 + l * 32768; midx = oidx; }
  else if (oidx < 49152) { src = W2 + l * 16384; midx = oidx - 32768; }
  else                   { src = W3 + l * 16384; midx = oidx - 49152; }
  int j = midx & 7;
  int lane = (midx >> 3) & 63;
  int blk = midx >> 9;
  int ct = blk & 3, kc = blk >> 2;
  int col = ct * 32 + (lane & 31);
  int k = kc * 16 + (lane >> 5) * 8 + j;
  out[l * 65536 + oidx] = f2b(src[k * 128 + col]);
}

// ---------------- pack radial-ResNet weights, N=64 (ct in 0..1) --------------
__global__ void pack_rdl_weights(const float* __restrict__ W1,
                                 const float* __restrict__ W2,
                                 const float* __restrict__ W3,
                                 unsigned short* __restrict__ out)
{
  int t = blockIdx.x * 256 + threadIdx.x;  // 0..40959
  if (t >= 40960) return;
  int l = t / 20480;
  int o = t - l * 20480;
  const float* src;
  int midx;
  if (o < 12288)      { src = W1 + l * 12288; midx = o; }
  else if (o < 16384) { src = W2 + l * 4096;  midx = o - 12288; }
  else                { src = W3 + l * 4096;  midx = o - 16384; }
  int j = midx & 7;
  int lane = (midx >> 3) & 63;
  int blk = midx >> 9;
  int ct = blk & 1, kc = blk >> 1;
  int col = ct * 32 + (lane & 31);
  int k = kc * 16 + (lane >> 5) * 8 + j;
  out[l * 20480 + o] = f2b(src[k * 64 + col]);
}

// ---------------- stage-A: features + sr/rd MLPs + LN + msg scatter ----------

#define STAGE_W(SRC, NF) do {                                                   \
    __syncthreads();                                                            \
    for (int i_ = tid; i_ < (NF); i_ += 256) wbuf[i_] = (SRC)[i_];              \
    __syncthreads();                                                            \
  } while (0)

#define MM_2x4(SRCARR, KDIM, WSTR, BIASP, DOTANH, DSTARR) do {                  \
    const int r0_ = (tid >> 4) * 2, j0_ = (tid & 15) * 4;                       \
    float a00 = (BIASP)[j0_],   a01 = (BIASP)[j0_+1];                           \
    float a02 = (BIASP)[j0_+2], a03 = (BIASP)[j0_+3];                           \
    float a10 = a00, a11 = a01, a12 = a02, a13 = a03;                           \
    for (int k_ = 0; k_ < (KDIM); ++k_) {                                       \
      const float s0_ = SRCARR[r0_][k_], s1_ = SRCARR[r0_+1][k_];               \
      const float4 w_ = *(const float4*)&wbuf[k_*(WSTR) + j0_];                 \
      a00 += s0_*w_.x; a01 += s0_*w_.y; a02 += s0_*w_.z; a03 += s0_*w_.w;       \
      a10 += s1_*w_.x; a11 += s1_*w_.y; a12 += s1_*w_.z; a13 += s1_*w_.w;       \
    }                                                                           \
    if (DOTANH) {                                                               \
      a00 = fast_tanh(a00); a01 = fast_tanh(a01);                               \
      a02 = fast_tanh(a02); a03 = fast_tanh(a03);                               \
      a10 = fast_tanh(a10); a11 = fast_tanh(a11);                               \
      a12 = fast_tanh(a12); a13 = fast_tanh(a13);                               \
    }                                                                           \
    DSTARR[r0_][j0_]   = a00; DSTARR[r0_][j0_+1]   = a01;                       \
    DSTARR[r0_][j0_+2] = a02; DSTARR[r0_][j0_+3]   = a03;                       \
    DSTARR[r0_+1][j0_]   = a10; DSTARR[r0_+1][j0_+1] = a11;                     \
    DSTARR[r0_+1][j0_+2] = a12; DSTARR[r0_+1][j0_+3] = a13;                     \
  } while (0)

template<int HAS_SR>
__launch_bounds__(256)
__global__ void feat_mlp_kernel(
    int nrows,
    const int* __restrict__ types, const float* __restrict__ lens,
    const float* __restrict__ vecs, const int* __restrict__ idx,
    const float* __restrict__ bessel_w,
    const float* __restrict__ srW1, const float* __restrict__ srb1,
    const float* __restrict__ srW2, const float* __restrict__ srb2,
    const float* __restrict__ srW3, const float* __restrict__ srb3,
    const float* __restrict__ rdW1, const float* __restrict__ rdb1,
    const float* __restrict__ rdW2, const float* __restrict__ rdb2,
    const float* __restrict__ rdW3, const float* __restrict__ rdb3,
    const float* __restrict__ eln_g, const float* __restrict__ eln_b,
    float* __restrict__ radial_out, float* __restrict__ ud_out,
    float* __restrict__ aggS)
{
  __shared__ float feat[32][25];
  __shared__ float bufA[32][65];
  __shared__ float bufB[32][65];
  __shared__ __align__(16) float wbuf[4096];
  __shared__ float sval[32][17];
  __shared__ float evud[32][3];
  __shared__ float udl[32];
  __shared__ int   i1l[32];
  __shared__ float rstat[32][2];

  const int tid = threadIdx.x;
  const int base = blockIdx.x * 32;

  if (tid < 32) {
    const int r = tid;
    const int row = base + r;
    const bool valid = row < nrows;
    float len = 1.0f, ud = 0.0f;
    int i0 = 0, i1 = 0;
    if (valid) {
      i0 = idx[row];
      i1 = idx[nrows + row];
      len = lens[row];
      ud = poly_cutoff(len);
    }
    const int t0 = valid ? types[i0] : -1;
    const int t1 = valid ? types[i1] : -1;
    #pragma unroll
    for (int a = 0; a < 4; ++a) {
      feat[r][a]     = (t0 == a) ? 1.0f : 0.0f;
      feat[r][4 + a] = (t1 == a) ? 1.0f : 0.0f;
    }
    const float invl = 1.0f / len;
    #pragma unroll
    for (int k = 0; k < 16; ++k) {
      feat[r][8 + k] = valid ? ud * BESSEL_PREF * sinf(bessel_w[k] * len * RC_INV) * invl : 0.0f;
    }
    udl[r] = ud;
    i1l[r] = i1;
    if (valid) {
      ud_out[row] = ud;
      if (HAS_SR) {
        evud[r][0] = ud * vecs[(size_t)row*3 + 0];
        evud[r][1] = ud * vecs[(size_t)row*3 + 1];
        evud[r][2] = ud * vecs[(size_t)row*3 + 2];
      }
    }
  }

  if (HAS_SR) {
    STAGE_W(srW1, 24*64);
    MM_2x4(feat, 24, 64, srb1, true, bufA);
    STAGE_W(srW2, 64*64);
    MM_2x4(bufA, 64, 64, srb2, true, bufB);
    STAGE_W(srW3, 64*16);
    {
      const int r = tid & 31;
      const int j = (tid >> 5) * 2;
      float a0 = srb3[j], a1 = srb3[j + 1];
      for (int k = 0; k < 64; ++k) {
        const float v = bufB[r][k];
        a0 += v * wbuf[k*16 + j];
        a1 += v * wbuf[k*16 + j + 1];
      }
      const float u = udl[r];
      sval[r][j]   = a0 * u;
      sval[r][j+1] = a1 * u;
    }
  }

  STAGE_W(rdW1, 24*64);
  MM_2x4(feat, 24, 64, rdb1, true, bufA);
  STAGE_W(rdW2, 64*64);
  MM_2x4(bufA, 64, 64, rdb2, true, bufB);
  STAGE_W(rdW3, 64*64);
  MM_2x4(bufB, 64, 64, rdb3, false, bufA);
  __syncthreads();
  if (tid < 32) {
    float s = 0.0f, ss = 0.0f;
    for (int k = 0; k < 64; ++k) { const float v = bufA[tid][k]; s += v; ss += v*v; }
    const float m = s * (1.0f/64.0f);
    const float var = ss * (1.0f/64.0f) - m*m;
    rstat[tid][0] = m;
    rstat[tid][1] = rsqrtf(var + LN_EPS);
  }
  __syncthreads();
  {
    const int r0 = (tid >> 4) * 2, j0 = (tid & 15) * 4;
    #pragma unroll
    for (int i = 0; i < 2; ++i) {
      const int r = r0 + i, row = base + r;
      if (row < nrows) {
        const float m = rstat[r][0], inv = rstat[r][1], u = udl[r];
        float4 v;
        v.x = ((bufA[r][j0]   - m)*inv*eln_g[j0]   + eln_b[j0])   * u;
        v.y = ((bufA[r][j0+1] - m)*inv*eln_g[j0+1] + eln_b[j0+1]) * u;
        v.z = ((bufA[r][j0+2] - m)*inv*eln_g[j0+2] + eln_b[j0+2]) * u;
        v.w = ((bufA[r][j0+3] - m)*inv*eln_g[j0+3] + eln_b[j0+3]) * u;
        *(float4*)&radial_out[(size_t)row*64 + j0] = v;
      }
    }
  }
  if (HAS_SR) {
    const int r = tid >> 3, q = tid & 7;
    const int row = base + r;
    if (row < nrows) {
      const size_t bo = (size_t)i1l[r] * 48;
      #pragma unroll
      for (int m6 = 0; m6 < 6; ++m6) {
        const int id = q*6 + m6;
        const int d = id / 3, c = id - d*3;
        atomicAdd(&aggS[bo + id], sval[r][d] * evud[r][c]);
      }
    }
  }
}

// ---------------- node embedding (gram + LN) ---------------------------------

__device__ __forceinline__ void block128_stats(float x, float& m, float& inv, float* red) {
  float s = x, ss = x*x;
  #pragma unroll
  for (int o = 32; o; o >>= 1) { s += __shfl_down(s, o); ss += __shfl_down(ss, o); }
  const int t = threadIdx.x;
  if ((t & 63) == 0) { red[(t >> 6)*2] = s; red[(t >> 6)*2 + 1] = ss; }
  __syncthreads();
  const float S = red[0] + red[2], SS = red[1] + red[3];
  m = S * (1.0f/128.0f);
  const float var = SS * (1.0f/128.0f) - m*m;
  inv = rsqrtf(var + LN_EPS);
}

__launch_bounds__(128)
__global__ void node_emb_kernel(int N, const float* __restrict__ aggS,
                                const int* __restrict__ ecnt,
                                const float* __restrict__ g, const float* __restrict__ b,
                                float* __restrict__ node_emb)
{
  const int n = blockIdx.x, t = threadIdx.x;
  __shared__ float S[48];
  __shared__ float red[4];
  if (t < 48) S[t] = aggS[(size_t)n*48 + t];
  __syncthreads();
  const float ic = 1.0f / fmaxf((float)ecnt[n], 1.0f);
  const int d = t >> 3, e = t & 7;
  const float x = (S[d*3+0]*S[e*3+0] + S[d*3+1]*S[e*3+1] + S[d*3+2]*S[e*3+2]) * ic * ic;
  float m, inv;
  block128_stats(x, m, inv, red);
  node_emb[(size_t)n*128 + t] = (x - m)*inv*g[t] + b[t];
}

// ---------------- per-layer aggregation: CSR gather (no atomics) -------------
// one wave per node; lane = radial column.

__launch_bounds__(256)
__global__ void agg_gather_kernel(int N, const int* __restrict__ eoff,
                                  const int* __restrict__ perm,
                                  const float* __restrict__ radial,
                                  float* __restrict__ mean_r)
{
  const int w = (blockIdx.x * 256 + threadIdx.x) >> 6;
  const int lane = threadIdx.x & 63;
  if (w >= N) return;
  const int s = eoff[w], e = eoff[w + 1];
  float acc = 0.0f;
  for (int j = s; j < e; ++j) {
    const int ed = perm[j];
    acc += radial[(size_t)ed * 64 + lane];
  }
  const float inv = 1.0f / fmaxf((float)(e - s), 1.0f);
  mean_r[(size_t)w * 64 + lane] = acc * inv;
}

// ---------------- node update: (mean_r @ W + b) * old, LN, residual ----------

__launch_bounds__(256)
__global__ void node_update_gemm(
    int N, const float* __restrict__ mean_r, const int* __restrict__ ecnt,
    const float* __restrict__ W, const float* __restrict__ bias,
    const float* __restrict__ g, const float* __restrict__ b,
    float* __restrict__ node_emb)
{
  __shared__ __align__(16) float lw[64*128];
  __shared__ float lm[32][65];
  const int tid = threadIdx.x;
  const int base = blockIdx.x * 32;

  for (int i = tid; i < 8192; i += 256) lw[i] = W[i];
  {
    const int rr0 = tid >> 6, k = tid & 63;
    for (int rr = rr0; rr < 32; rr += 4) {
      const int n = base + rr;
      lm[rr][k] = (n < N) ? mean_r[(size_t)n*64 + k] : 0.0f;
    }
  }
  __syncthreads();

  const int r0 = (tid >> 5) * 4, j0 = (tid & 31) * 4;
  float acc[4][4];
  #pragma unroll
  for (int j = 0; j < 4; ++j) {
    const float bj = bias[j0 + j];
    acc[0][j] = bj; acc[1][j] = bj; acc[2][j] = bj; acc[3][j] = bj;
  }
  for (int k = 0; k < 64; ++k) {
    const float4 w = *(const float4*)&lw[k*128 + j0];
    const float s0 = lm[r0][k],   s1 = lm[r0+1][k];
    const float s2 = lm[r0+2][k], s3 = lm[r0+3][k];
    acc[0][0] += s0*w.x; acc[0][1] += s0*w.y; acc[0][2] += s0*w.z; acc[0][3] += s0*w.w;
    acc[1][0] += s1*w.x; acc[1][1] += s1*w.y; acc[1][2] += s1*w.z; acc[1][3] += s1*w.w;
    acc[2][0] += s2*w.x; acc[2][1] += s2*w.y; acc[2][2] += s2*w.z; acc[2][3] += s2*w.w;
    acc[3][0] += s3*w.x; acc[3][1] += s3*w.y; acc[3][2] += s3*w.z; acc[3][3] += s3*w.w;
  }

  const float g0 = g[j0], g1 = g[j0+1], g2 = g[j0+2], g3 = g[j0+3];
  const float bb0 = b[j0], bb1 = b[j0+1], bb2 = b[j0+2], bb3 = b[j0+3];
  #pragma unroll
  for (int i = 0; i < 4; ++i) {
    const int n = base + r0 + i;
    if (n >= N) continue;
    const float mask = (ecnt[n] > 0) ? 1.0f : 0.0f;
    const float4 old = *(const float4*)&node_emb[(size_t)n*128 + j0];
    const float x0 = old.x * acc[i][0] * mask;
    const float x1 = old.y * acc[i][1] * mask;
    const float x2 = old.z * acc[i][2] * mask;
    const float x3 = old.w * acc[i][3] * mask;
    float s = x0 + x1 + x2 + x3;
    float ss = x0*x0 + x1*x1 + x2*x2 + x3*x3;
    #pragma unroll
    for (int o = 1; o <= 16; o <<= 1) {
      s  += __shfl_xor(s, o);
      ss += __shfl_xor(ss, o);
    }
    const float m = s * (1.0f/128.0f);
    const float inv = rsqrtf(ss * (1.0f/128.0f) - m*m + LN_EPS);
    float4 o4;
    o4.x = C_RES*old.x + C_NEW*((x0 - m)*inv*g0 + bb0);
    o4.y = C_RES*old.y + C_NEW*((x1 - m)*inv*g1 + bb1);
    o4.z = C_RES*old.z + C_NEW*((x2 - m)*inv*g2 + bb2);
    o4.w = C_RES*old.w + C_NEW*((x3 - m)*inv*g3 + bb3);
    *(float4*)&node_emb[(size_t)n*128 + j0] = o4;
  }
}

// ---------------- embedding GEMM (K=64 -> N=128), hidden-init epilogue -------

__launch_bounds__(256)
__global__ void emb_gemm_kernel(
    int nrows,
    const float* __restrict__ radial,
    const float* __restrict__ W, const float* __restrict__ bias,
    const int* __restrict__ idx,
    const float* __restrict__ node_emb,
    float* __restrict__ out)
{
  __shared__ float lin[32][65];
  __shared__ __align__(16) float lw[64*128];
  const int tid = threadIdx.x;
  const int base = blockIdx.x * 32;

  for (int i = tid; i < 64*128; i += 256) lw[i] = W[i];
  {
    const int rr0 = tid >> 6, k = tid & 63;
    for (int rr = rr0; rr < 32; rr += 4) {
      const int row = base + rr;
      lin[rr][k] = (row < nrows) ? radial[(size_t)row*64 + k] : 0.0f;
    }
  }
  __syncthreads();

  const int r0 = (tid >> 5) * 4, j0 = (tid & 31) * 4;
  float acc[4][4];
  #pragma unroll
  for (int j = 0; j < 4; ++j) {
    const float bj = bias[j0 + j];
    acc[0][j] = bj; acc[1][j] = bj; acc[2][j] = bj; acc[3][j] = bj;
  }
  for (int k = 0; k < 64; ++k) {
    const float4 w = *(const float4*)&lw[k*128 + j0];
    const float s0 = lin[r0][k],   s1 = lin[r0+1][k];
    const float s2 = lin[r0+2][k], s3 = lin[r0+3][k];
    acc[0][0] += s0*w.x; acc[0][1] += s0*w.y; acc[0][2] += s0*w.z; acc[0][3] += s0*w.w;
    acc[1][0] += s1*w.x; acc[1][1] += s1*w.y; acc[1][2] += s1*w.z; acc[1][3] += s1*w.w;
    acc[2][0] += s2*w.x; acc[2][1] += s2*w.y; acc[2][2] += s2*w.z; acc[2][3] += s2*w.w;
    acc[3][0] += s3*w.x; acc[3][1] += s3*w.y; acc[3][2] += s3*w.z; acc[3][3] += s3*w.w;
  }
  #pragma unroll
  for (int i = 0; i < 4; ++i) {
    const int row = base + r0 + i;
    if (row >= nrows) continue;
    const int i0 = idx[row], i1 = idx[nrows + row];
    const float4 n0 = *(const float4*)&node_emb[(size_t)i0*128 + j0];
    const float4 n1 = *(const float4*)&node_emb[(size_t)i1*128 + j0];
    float4 o;
    o.x = acc[i][0] * 0.5f * (n0.x + n1.x);
    o.y = acc[i][1] * 0.5f * (n0.y + n1.y);
    o.z = acc[i][2] * 0.5f * (n0.z + n1.z);
    o.w = acc[i][3] * 0.5f * (n0.w + n1.w);
    *(float4*)&out[(size_t)row*128 + j0] = o;
  }
}

// ---------------- hidden MLP via bf16 MFMA -----------------------------------

__launch_bounds__(128)
__global__ void hid_mlp_mfma(
    int nrows, const int* __restrict__ idx0,
    const float* __restrict__ node_emb,
    const unsigned short* __restrict__ wpack,   // 65536 ushorts for this layer
    const float* __restrict__ b1, const float* __restrict__ b2,
    const float* __restrict__ b3,
    float* __restrict__ hidden)
{
  __shared__ __align__(16) unsigned short h_afrag[16384];  // 32KB: [rt4][kc8]*512
  __shared__ __align__(16) unsigned short xg[4096];        // 8KB:  [rt4][kcl2]*512
  __shared__ __align__(16) unsigned short wg[4096];        // 8KB:  [kcl2][ct4]*512

  const int tid  = threadIdx.x;
  const int lane = tid & 63;
  const int wave = tid >> 6;
  const int base = blockIdx.x * 128;

  const int r = tid;                       // staging row 0..127
  int rowg = base + r;
  if (rowg >= nrows) rowg = nrows - 1;
  const int i0 = idx0[rowg];
  const float* xsrc0 = node_emb + (size_t)i0 * 128;
  const float* xsrc1 = hidden + (size_t)rowg * 128;

  f32x16 acc[2][4];

  // ---------- layer 1: K=256, 8 phases x (2 kc) ----------
  #pragma unroll
  for (int ct = 0; ct < 4; ++ct) {
    const float bv = b1[ct*32 + (lane & 31)];
    #pragma unroll
    for (int q = 0; q < 16; ++q) { acc[0][ct][q] = bv; acc[1][ct][q] = bv; }
  }
  for (int p = 0; p < 8; ++p) {
    __syncthreads();
    #pragma unroll
    for (int o = 0; o < 4; ++o) {
      const int k = p*32 + o*8;
      const float* s = (k < 128) ? (xsrc0 + k) : (xsrc1 + (k - 128));
      const float4 v0 = *(const float4*)s;
      const float4 v1 = *(const float4*)(s + 4);
      u16x8 w;
      w[0]=f2b(v0.x); w[1]=f2b(v0.y); w[2]=f2b(v0.z); w[3]=f2b(v0.w);
      w[4]=f2b(v1.x); w[5]=f2b(v1.y); w[6]=f2b(v1.z); w[7]=f2b(v1.w);
      const int kc = p*2 + (o >> 1);
      const int s_ = (r & 31) + 32*(o & 1);
      *(u16x8*)&xg[ ((r>>5)*2 + (o>>1))*512 + swz(s_, kc)*8 ] = w;
    }
    #pragma unroll
    for (int i = 0; i < 4; ++i) {
      const int c = tid + i*128;
      *(u16x8*)&wg[c*8] = *(const u16x8*)&wpack[p*4096 + c*8];
    }
    __syncthreads();
    #pragma unroll
    for (int kcl = 0; kcl < 2; ++kcl) {
      const int kc = p*2 + kcl;
      const short8 a0 = *(const short8*)&xg[ ((wave*2+0)*2 + kcl)*512 + swz(lane, kc)*8 ];
      const short8 a1 = *(const short8*)&xg[ ((wave*2+1)*2 + kcl)*512 + swz(lane, kc)*8 ];
      #pragma unroll
      for (int ct = 0; ct < 4; ++ct) {
        const short8 b = *(const short8*)&wg[ (kcl*4 + ct)*512 + lane*8 ];
        acc[0][ct] = __builtin_amdgcn_mfma_f32_32x32x16_bf16(a0, b, acc[0][ct], 0, 0, 0);
        acc[1][ct] = __builtin_amdgcn_mfma_f32_32x32x16_bf16(a1, b, acc[1][ct], 0, 0, 0);
      }
    }
  }

  // ---------- transition 1: tanh -> h_afrag ----------
  __syncthreads();
  #pragma unroll
  for (int m = 0; m < 2; ++m) {
    const int rt = wave*2 + m;
    #pragma unroll
    for (int ct = 0; ct < 4; ++ct) {
      const int kc  = ct*2 + ((lane >> 4) & 1);
      const int oct = (lane >> 3) & 1;
      const int j   = lane & 7;
      const int xk  = (oct << 1) ^ ((kc & 1) << 2);
      const int hi  = 4*(lane >> 5);
      const int bi  = (rt*8 + kc)*512 + oct*256 + j;
      #pragma unroll
      for (int q = 0; q < 16; ++q) {
        const int m32 = (q & 3) + 8*(q >> 2) + hi;
        h_afrag[bi + (m32 ^ xk)*8] = f2b(fast_tanh(acc[m][ct][q]));
      }
    }
  }
  #pragma unroll
  for (int ct = 0; ct < 4; ++ct) {
    const float bv = b2[ct*32 + (lane & 31)];
    #pragma unroll
    for (int q = 0; q < 16; ++q) { acc[0][ct][q] = bv; acc[1][ct][q] = bv; }
  }
  __syncthreads();

  // ---------- layer 2: K=128, 4 phases x (2 kc) ----------
  for (int p = 0; p < 4; ++p) {
    __syncthreads();
    #pragma unroll
    for (int i = 0; i < 4; ++i) {
      const int c = tid + i*128;
      *(u16x8*)&wg[c*8] = *(const u16x8*)&wpack[32768 + p*4096 + c*8];
    }
    __syncthreads();
    #pragma unroll
    for (int kcl = 0; kcl < 2; ++kcl) {
      const int kc = p*2 + kcl;
      const short8 a0 = *(const short8*)&h_afrag[ ((wave*2+0)*8 + kc)*512 + swz(lane, kc)*8 ];
      const short8 a1 = *(const short8*)&h_afrag[ ((wave*2+1)*8 + kc)*512 + swz(lane, kc)*8 ];
      #pragma unroll
      for (int ct = 0; ct < 4; ++ct) {
        const short8 b = *(const short8*)&wg[ (kcl*4 + ct)*512 + lane*8 ];
        acc[0][ct] = __builtin_amdgcn_mfma_f32_32x32x16_bf16(a0, b, acc[0][ct], 0, 0, 0);
        acc[1][ct] = __builtin_amdgcn_mfma_f32_32x32x16_bf16(a1, b, acc[1][ct], 0, 0, 0);
      }
    }
  }

  // ---------- transition 2: tanh -> h_afrag (overwrite) ----------
  __syncthreads();
  #pragma unroll
  for (int m = 0; m < 2; ++m) {
    const int rt = wave*2 + m;
    #pragma unroll
    for (int ct = 0; ct < 4; ++ct) {
      const int kc  = ct*2 + ((lane >> 4) & 1);
      const int oct = (lane >> 3) & 1;
      const int j   = lane & 7;
      const int xk  = (oct << 1) ^ ((kc & 1) << 2);
      const int hi  = 4*(lane >> 5);
      const int bi  = (rt*8 + kc)*512 + oct*256 + j;
      #pragma unroll
      for (int q = 0; q < 16; ++q) {
        const int m32 = (q & 3) + 8*(q >> 2) + hi;
        h_afrag[bi + (m32 ^ xk)*8] = f2b(fast_tanh(acc[m][ct][q]));
      }
    }
  }
  #pragma unroll
  for (int ct = 0; ct < 4; ++ct) {
    const float bv = b3[ct*32 + (lane & 31)];
    #pragma unroll
    for (int q = 0; q < 16; ++q) { acc[0][ct][q] = bv; acc[1][ct][q] = bv; }
  }
  __syncthreads();

  // ---------- layer 3: K=128 ----------
  for (int p = 0; p < 4; ++p) {
    __syncthreads();
    #pragma unroll
    for (int i = 0; i < 4; ++i) {
      const int c = tid + i*128;
      *(u16x8*)&wg[c*8] = *(const u16x8*)&wpack[49152 + p*4096 + c*8];
    }
    __syncthreads();
    #pragma unroll
    for (int kcl = 0; kcl < 2; ++kcl) {
      const int kc = p*2 + kcl;
      const short8 a0 = *(const short8*)&h_afrag[ ((wave*2+0)*8 + kc)*512 + swz(lane, kc)*8 ];
      const short8 a1 = *(const short8*)&h_afrag[ ((wave*2+1)*8 + kc)*512 + swz(lane, kc)*8 ];
      #pragma unroll
      for (int ct = 0; ct < 4; ++ct) {
        const short8 b = *(const short8*)&wg[ (kcl*4 + ct)*512 + lane*8 ];
        acc[0][ct] = __builtin_amdgcn_mfma_f32_32x32x16_bf16(a0, b, acc[0][ct], 0, 0, 0);
        acc[1][ct] = __builtin_amdgcn_mfma_f32_32x32x16_bf16(a1, b, acc[1][ct], 0, 0, 0);
      }
    }
  }

  // ---------- epilogue: store f32 ----------
  #pragma unroll
  for (int m = 0; m < 2; ++m) {
    #pragma unroll
    for (int ct = 0; ct < 4; ++ct) {
      const int col = ct*32 + (lane & 31);
      #pragma unroll
      for (int q = 0; q < 16; ++q) {
        const int row = base + (wave*2+m)*32 + (q & 3) + 8*(q >> 2) + 4*(lane >> 5);
        if (row < nrows) hidden[(size_t)row*128 + col] = acc[m][ct][q];
      }
    }
  }
}

// ---------------- radial ResNet via bf16 MFMA --------------------------------

__launch_bounds__(192)
__global__ void rdl_mfma(
    int nrows,
    const float* __restrict__ hidden, const float* __restrict__ ud,
    const unsigned short* __restrict__ wpack,   // 20480 ushorts this layer
    const float* __restrict__ b1, const float* __restrict__ b2,
    const float* __restrict__ b3,
    const float* __restrict__ eln_g, const float* __restrict__ eln_b,
    float* __restrict__ radial)
{
  __shared__ __align__(16) unsigned short afrag[36*512];  // 36KB
  __shared__ __align__(16) unsigned short wlds[40*512];   // 40KB
  __shared__ float udl[96];

  const int tid  = threadIdx.x;    // 0..191
  const int lane = tid & 63;
  const int wave = tid >> 6;       // rt
  const int base = blockIdx.x * 96;
  const int cl   = lane & 31;

  for (int i = tid; i < 2560; i += 192) {
    *(u16x8*)&wlds[i*8] = *(const u16x8*)&wpack[i*8];
  }
  {
    const int r  = tid >> 1;       // 0..95
    const int kh = tid & 1;
    int rowg = base + r;
    if (rowg >= nrows) rowg = nrows - 1;
    const float* rsrc = radial + (size_t)rowg * 64;
    const float* hsrc = hidden + (size_t)rowg * 128;
    if (kh == 0) udl[r] = ud[rowg];
    #pragma unroll
    for (int g = 0; g < 12; ++g) {
      const int k = kh*96 + g*8;
      const float* s = (k < 64) ? (rsrc + k) : (hsrc + (k - 64));
      const float4 v0 = *(const float4*)s;
      const float4 v1 = *(const float4*)(s + 4);
      u16x8 w;
      w[0]=f2b(v0.x); w[1]=f2b(v0.y); w[2]=f2b(v0.z); w[3]=f2b(v0.w);
      w[4]=f2b(v1.x); w[5]=f2b(v1.y); w[6]=f2b(v1.z); w[7]=f2b(v1.w);
      const int kc = k >> 4;
      const int s_ = (r & 31) + 32*((k >> 3) & 1);
      *(u16x8*)&afrag[(kc*3 + (r>>5))*512 + swz(s_, kc)*8] = w;
    }
  }
  __syncthreads();   // the only block-wide barrier

  f32x16 acc0, acc1;
  {
    const float bv0 = b1[cl], bv1 = b1[32 + cl];
    #pragma unroll
    for (int q = 0; q < 16; ++q) { acc0[q] = bv0; acc1[q] = bv1; }
  }
  #pragma unroll
  for (int kc = 0; kc < 12; ++kc) {
    const short8 a  = *(const short8*)&afrag[(kc*3 + wave)*512 + swz(lane, kc)*8];
    const short8 w0 = *(const short8*)&wlds[(kc*2 + 0)*512 + lane*8];
    const short8 w1 = *(const short8*)&wlds[(kc*2 + 1)*512 + lane*8];
    acc0 = __builtin_amdgcn_mfma_f32_32x32x16_bf16(a, w0, acc0, 0, 0, 0);
    acc1 = __builtin_amdgcn_mfma_f32_32x32x16_bf16(a, w1, acc1, 0, 0, 0);
  }

  #pragma unroll
  for (int ct = 0; ct < 2; ++ct) {
    const int colh = ct*32 + cl;
    const int kc2  = colh >> 4;
    const int b3_  = (colh >> 3) & 1;
    const int jj   = colh & 7;
    const int blk  = ((4 + kc2)*3 + wave)*512;
    #pragma unroll
    for (int q = 0; q < 16; ++q) {
      const int row32 = (q & 3) + 8*(q >> 2) + 4*(lane >> 5);
      const int s_ = (row32 & 31) + 32*b3_;
      const float v = ct ? acc1[q] : acc0[q];
      afrag[blk + swz(s_, kc2)*8 + jj] = f2b(fast_tanh(v));
    }
  }

  f32x16 h0, h1;
  {
    const float bv0 = b2[cl], bv1 = b2[32 + cl];
    #pragma unroll
    for (int q = 0; q < 16; ++q) { h0[q] = bv0; h1[q] = bv1; }
  }
  #pragma unroll
  for (int kc = 0; kc < 4; ++kc) {
    const short8 a  = *(const short8*)&afrag[((4 + kc)*3 + wave)*512 + swz(lane, kc)*8];
    const short8 w0 = *(const short8*)&wlds[(24 + kc*2 + 0)*512 + lane*8];
    const short8 w1 = *(const short8*)&wlds[(24 + kc*2 + 1)*512 + lane*8];
    h0 = __builtin_amdgcn_mfma_f32_32x32x16_bf16(a, w0, h0, 0, 0, 0);
    h1 = __builtin_amdgcn_mfma_f32_32x32x16_bf16(a, w1, h1, 0, 0, 0);
  }

  #pragma unroll
  for (int ct = 0; ct < 2; ++ct) {
    const int colh = ct*32 + cl;
    const int kc2  = colh >> 4;
    const int b3_  = (colh >> 3) & 1;
    const int jj   = colh & 7;
    const int blk  = ((8 + kc2)*3 + wave)*512;
    #pragma unroll
    for (int q = 0; q < 16; ++q) {
      const int row32 = (q & 3) + 8*(q >> 2) + 4*(lane >> 5);
      const int s_ = (row32 & 31) + 32*b3_;
      const float v = ct ? h1[q] : h0[q];
      afrag[blk + swz(s_, kc2)*8 + jj] = f2b(fast_tanh(v));
    }
  }

  {
    const float bv0 = b3[cl], bv1 = b3[32 + cl];
    #pragma unroll
    for (int q = 0; q < 16; ++q) { acc0[q] = bv0; acc1[q] = bv1; }
  }
  #pragma unroll
  for (int kc = 0; kc < 4; ++kc) {
    const short8 a  = *(const short8*)&afrag[((8 + kc)*3 + wave)*512 + swz(lane, kc)*8];
    const short8 w0 = *(const short8*)&wlds[(32 + kc*2 + 0)*512 + lane*8];
    const short8 w1 = *(const short8*)&wlds[(32 + kc*2 + 1)*512 + lane*8];
    acc0 = __builtin_amdgcn_mfma_f32_32x32x16_bf16(a, w0, acc0, 0, 0, 0);
    acc1 = __builtin_amdgcn_mfma_f32_32x32x16_bf16(a, w1, acc1, 0, 0, 0);
  }

  const float eg0 = eln_g[cl],      eb0 = eln_b[cl];
  const float eg1 = eln_g[32 + cl], eb1 = eln_b[32 + cl];
  const int kcA = cl >> 4;
  const int kcB = (32 + cl) >> 4;
  const int jA  = cl & 7;
  const int jB  = cl & 7;
  const int bA  = (kcA*3 + wave)*512;
  const int bB  = (kcB*3 + wave)*512;
  const int b3A = (cl >> 3) & 1;
  const int b3B = ((32 + cl) >> 3) & 1;

  #pragma unroll
  for (int q = 0; q < 16; ++q) {
    const float v0 = acc0[q] + h0[q];
    const float v1 = acc1[q] + h1[q];
    float s = v0 + v1, ss = v0*v0 + v1*v1;
    #pragma unroll
    for (int o = 1; o <= 16; o <<= 1) {
      s  += __shfl_xor(s, o);
      ss += __shfl_xor(ss, o);
    }
    const float m   = s * (1.0f/64.0f);
    const float inv = rsqrtf(ss * (1.0f/64.0f) - m*m + LN_EPS);
    const int row32 = (q & 3) + 8*(q >> 2) + 4*(lane >> 5);
    const int rloc  = wave*32 + row32;
    const int row   = base + rloc;
    if (row < nrows) {
      const float u = udl[rloc];
      const int sA = (row32 & 31) + 32*b3A;
      const int sB = (row32 & 31) + 32*b3B;
      const float oldA = __uint_as_float((unsigned)afrag[bA + swz(sA, kcA)*8 + jA] << 16);
      const float oldB = __uint_as_float((unsigned)afrag[bB + swz(sB, kcB)*8 + jB] << 16);
      radial[(size_t)row*64 + cl]      = C_RES*oldA + C_NEW*u*((v0 - m)*inv*eg0 + eb0);
      radial[(size_t)row*64 + 32 + cl] = C_RES*oldB + C_NEW*u*((v1 - m)*inv*eg1 + eb1);
    }
  }
}

// ---------------- launch -----------------------------------------------------

extern "C" void kernel_launch(void* const* d_in, const int* in_sizes, int n_in,
                              void* d_out, int out_size, void* d_ws, size_t ws_size,
                              hipStream_t stream)
{
  const int*   atom_types = (const int*)  d_in[0];
  const float* env_vec    = (const float*)d_in[1];
  const float* env_len    = (const float*)d_in[2];
  const float* edge_len   = (const float*)d_in[3];
  const int*   env_idx    = (const int*)  d_in[4];
  const int*   edge_idx   = (const int*)  d_in[5];
  const float* bessel_w   = (const float*)d_in[6];
  const float* srW1 = (const float*)d_in[7];  const float* srb1 = (const float*)d_in[8];
  const float* srW2 = (const float*)d_in[9];  const float* srb2 = (const float*)d_in[10];
  const float* srW3 = (const float*)d_in[11]; const float* srb3 = (const float*)d_in[12];
  const float* rdW1 = (const float*)d_in[13]; const float* rdb1 = (const float*)d_in[14];
  const float* rdW2 = (const float*)d_in[15]; const float* rdb2 = (const float*)d_in[16];
  const float* rdW3 = (const float*)d_in[17]; const float* rdb3 = (const float*)d_in[18];
  const float* ne_emb_W = (const float*)d_in[19]; const float* ne_emb_b = (const float*)d_in[20];
  const float* ne_nln_g = (const float*)d_in[21]; const float* ne_nln_b = (const float*)d_in[22];
  const float* ne_eln_g = (const float*)d_in[23]; const float* ne_eln_b = (const float*)d_in[24];
  const float* ly_emb_W = (const float*)d_in[25]; const float* ly_emb_b = (const float*)d_in[26];
  const float* ly_hid_W1 = (const float*)d_in[27]; const float* ly_hid_b1 = (const float*)d_in[28];
  const float* ly_hid_W2 = (const float*)d_in[29]; const float* ly_hid_b2 = (const float*)d_in[30];
  const float* ly_hid_W3 = (const float*)d_in[31]; const float* ly_hid_b3 = (const float*)d_in[32];
  const float* ly_rdl_W1 = (const float*)d_in[33]; const float* ly_rdl_b1 = (const float*)d_in[34];
  const float* ly_rdl_W2 = (const float*)d_in[35]; const float* ly_rdl_b2 = (const float*)d_in[36];
  const float* ly_rdl_W3 = (const float*)d_in[37]; const float* ly_rdl_b3 = (const float*)d_in[38];
  const float* ly_nln_g = (const float*)d_in[39]; const float* ly_nln_b = (const float*)d_in[40];
  const float* ly_eln_g = (const float*)d_in[41]; const float* ly_eln_b = (const float*)d_in[42];

  const int N  = in_sizes[0];
  const int E  = in_sizes[2];
  const int E2 = in_sizes[3];

  float* out = (float*)d_out;
  float* env_radial  = out;
  float* edge_radial = env_radial + (size_t)E * 64;
  float* node_emb    = edge_radial + (size_t)E2 * 64;
  float* env_hidden  = node_emb + (size_t)N * 128;
  float* edge_hidden = env_hidden + (size_t)E * 128;

  float* ws = (float*)d_ws;
  float* ud_env  = ws;  ws += E;
  float* ud_edge = ws;  ws += E2;
  float* aggS    = ws;  ws += (size_t)N * 48;
  float* mean_r  = ws;  ws += (size_t)N * 64;
  unsigned short* wpack = (unsigned short*)ws;  ws += 65536;   // hid: 2 x 65536 u16
  unsigned short* wpack2 = (unsigned short*)ws; ws += 20480;   // rdl: 2 x 20480 u16
  int* ecnt = (int*)ws; ws += N;
  int* eoff = (int*)ws; ws += N + 1;
  int* ecur = (int*)ws; ws += N + 1;
  int* perm = (int*)ws; ws += E;

  const int gE  = (E  + 31) / 32;
  const int gE2 = (E2 + 31) / 32;
  const int gEh  = (E  + 127) / 128;
  const int gE2h = (E2 + 127) / 128;
  const int gEr  = (E  + 95) / 96;
  const int gE2r = (E2 + 95) / 96;
  const int gN32 = (N + 31) / 32;
  const int gN4w = (N * 64 + 255) / 256;

  // CSR build over env graph (i1 = env_idx[1])
  zero_int_kernel<<<256, 256, 0, stream>>>(ecnt, N);
  hist_kernel<<<(E + 255) / 256, 256, 0, stream>>>(E, env_idx, ecnt);
  scan_kernel<<<1, 1024, 0, stream>>>(ecnt, eoff, ecur, N);
  scatter_kernel<<<(E + 255) / 256, 256, 0, stream>>>(E, env_idx, ecur, perm);

  zero_kernel<<<1024, 256, 0, stream>>>(aggS, (size_t)N * 48);
  pack_hid_weights<<<512, 256, 0, stream>>>(ly_hid_W1, ly_hid_W2, ly_hid_W3, wpack);
  pack_rdl_weights<<<160, 256, 0, stream>>>(ly_rdl_W1, ly_rdl_W2, ly_rdl_W3, wpack2);

  feat_mlp_kernel<1><<<gE, 256, 0, stream>>>(E, atom_types, env_len, env_vec, env_idx, bessel_w,
      srW1, srb1, srW2, srb2, srW3, srb3, rdW1, rdb1, rdW2, rdb2, rdW3, rdb3,
      ne_eln_g, ne_eln_b, env_radial, ud_env, aggS);
  feat_mlp_kernel<0><<<gE2, 256, 0, stream>>>(E2, atom_types, edge_len, nullptr, edge_idx, bessel_w,
      srW1, srb1, srW2, srb2, srW3, srb3, rdW1, rdb1, rdW2, rdb2, rdW3, rdb3,
      ne_eln_g, ne_eln_b, edge_radial, ud_edge, nullptr);

  node_emb_kernel<<<N, 128, 0, stream>>>(N, aggS, ecnt, ne_nln_g, ne_nln_b, node_emb);

  emb_gemm_kernel<<<gE, 256, 0, stream>>>(E, env_radial, ne_emb_W, ne_emb_b, env_idx, node_emb, env_hidden);
  emb_gemm_kernel<<<gE2, 256, 0, stream>>>(E2, edge_radial, ne_emb_W, ne_emb_b, edge_idx, node_emb, edge_hidden);

  for (int l = 0; l < 2; ++l) {
    agg_gather_kernel<<<gN4w, 256, 0, stream>>>(N, eoff, perm, env_radial, mean_r);
    node_update_gemm<<<gN32, 256, 0, stream>>>(N, mean_r, ecnt,
        ly_emb_W + (size_t)l*64*128, ly_emb_b + (size_t)l*128,
        ly_nln_g + (size_t)l*128, ly_nln_b + (size_t)l*128, node_emb);

    hid_mlp_mfma<<<gEh, 128, 0, stream>>>(E, env_idx, node_emb,
        wpack + (size_t)l*65536,
        ly_hid_b1 + (size_t)l*128, ly_hid_b2 + (size_t)l*128, ly_hid_b3 + (size_t)l*128,
        env_hidden);
    hid_mlp_mfma<<<gE2h, 128, 0, stream>>>(E2, edge_idx, node_emb,
        wpack + (size_t)l*65536,
        ly_hid_b1 + (size_t)l*128, ly_hid_b2 + (size_t)l*128, ly_hid_b3 + (size_t)l*128,
        edge_hidden);

    rdl_mfma<<<gEr, 192, 0, stream>>>(E, env_hidden, ud_env,
        wpack2 + (size_t)l*20480,
        ly_rdl_b1 + (size_t)l*64, ly_rdl_b2 + (size_t)l*64, ly_rdl_b3 + (size_t)l*64,
        ly_eln_g + (size_t)l*64, ly_eln_b + (size_t)l*64, env_radial);
    rdl_mfma<<<gE2r, 192, 0, stream>>>(E2, edge_hidden, ud_edge,
        wpack2 + (size_t)l*20480,
        ly_rdl_b1 + (size_t)l*64, ly_rdl_b2 + (size_t)l*64, ly_rdl_b3 + (size_t)l*64,
        ly_eln_g + (size_t)l*64, ly_eln_b + (size_t)l*64, edge_radial);
  }
}

// Round 5
// 1797.657 us; speedup vs baseline: 4.2048x; 1.1530x over previous
//
#include <hip/hip_runtime.h>
#include <math.h>

#define C_RES 0.89442719f
#define C_NEW 0.4472f
#define LN_EPS 1e-5f
#define BESSEL_PREF 0.6324555320336759f  // sqrt(2/5)
#define RC_INV 0.2f

typedef __attribute__((ext_vector_type(8))) short short8;
typedef __attribute__((ext_vector_type(8))) unsigned short u16x8;
typedef __attribute__((ext_vector_type(16))) float f32x16;

__device__ __forceinline__ float fast_tanh(float x) {
  float ax = fabsf(x);
  float e = __expf(2.0f * ax);
  float t = 1.0f - 2.0f / (e + 1.0f);
  return copysignf(t, x);
}

__device__ __forceinline__ unsigned short f2b(float f) {
  unsigned int u = __float_as_uint(f);
  unsigned int r = (u + 0x7FFFu + ((u >> 16) & 1u)) >> 16;
  return (unsigned short)r;
}

__device__ __forceinline__ float poly_cutoff(float x) {
  float xr = x * RC_INV;
  if (xr >= 1.0f) return 0.0f;
  float x2 = xr * xr;
  float x3 = x2 * xr;
  float x6 = x3 * x3;
  return 1.0f - 28.0f * x6 + 48.0f * x6 * xr - 21.0f * x6 * x2;
}

// A-frag slot swizzle: spreads the strided aliasing of the C/D->A scatter
// writes across banks; reads stay a permutation (conflict-free).
__device__ __forceinline__ int swz(int s, int kc) {
  return s ^ ((s >> 5) << 1) ^ ((kc & 1) << 2);
}

__global__ void zero_int_kernel(int* __restrict__ p, int n) {
  int i = blockIdx.x * blockDim.x + threadIdx.x;
  int stride = gridDim.x * blockDim.x;
  for (; i < n; i += stride) p[i] = 0;
}

// ---------------- CSR build: hist -> scan -> scatter --------------------------

__global__ void hist_kernel(int E, const int* __restrict__ idx, int* __restrict__ ecnt) {
  int t = blockIdx.x * 256 + threadIdx.x;
  if (t < E) atomicAdd(&ecnt[idx[E + t]], 1);
}

__launch_bounds__(1024)
__global__ void scan_kernel(const int* __restrict__ ecnt, int* __restrict__ eoff,
                            int* __restrict__ ecur, int n) {
  __shared__ int buf[1024];
  __shared__ int carry;
  const int tid = threadIdx.x;
  if (tid == 0) carry = 0;
  __syncthreads();
  for (int b0 = 0; b0 < n; b0 += 1024) {
    const int i = b0 + tid;
    const int v = (i < n) ? ecnt[i] : 0;
    buf[tid] = v;
    __syncthreads();
    #pragma unroll
    for (int o = 1; o < 1024; o <<= 1) {
      const int t = (tid >= o) ? buf[tid - o] : 0;
      __syncthreads();
      buf[tid] += t;
      __syncthreads();
    }
    const int c0 = carry;
    const int excl = c0 + buf[tid] - v;
    if (i < n) { eoff[i] = excl; ecur[i] = excl; }
    __syncthreads();
    if (tid == 1023) carry = c0 + buf[1023];
    __syncthreads();
  }
  if (tid == 0) eoff[n] = carry;
}

__global__ void scatter_kernel(int E, const int* __restrict__ idx,
                               int* __restrict__ ecur, int* __restrict__ perm) {
  int t = blockIdx.x * 256 + threadIdx.x;
  if (t < E) {
    const int pos = atomicAdd(&ecur[idx[E + t]], 1);
    perm[pos] = t;
  }
}

// ---------------- pack hidden-MLP weights into bf16 MFMA B-fragment order ----
__global__ void pack_hid_weights(const float* __restrict__ W1,
                                 const float* __restrict__ W2,
                                 const float* __restrict__ W3,
                                 unsigned short* __restrict__ out)
{
  int t = blockIdx.x * 256 + threadIdx.x;  // 0..131071
  if (t >= 131072) return;
  int l = t >> 16;
  int oidx = t & 65535;
  const float* src;
  int midx;
  if (oidx < 32768)      { src = W1 + l * 32768; midx = oidx; }
  else if (oidx < 49152) { src = W2 + l * 16384; midx = oidx - 32768; }
  else                   { src = W3 + l * 16384; midx = oidx - 49152; }
  int j = midx & 7;
  int lane = (midx >> 3) & 63;
  int blk = midx >> 9;
  int ct = blk & 3, kc = blk >> 2;
  int col = ct * 32 + (lane & 31);
  int k = kc * 16 + (lane >> 5) * 8 + j;
  out[l * 65536 + oidx] = f2b(src[k * 128 + col]);
}

// ---------------- pack radial-ResNet weights, N=64 (ct in 0..1) --------------
__global__ void pack_rdl_weights(const float* __restrict__ W1,
                                 const float* __restrict__ W2,
                                 const float* __restrict__ W3,
                                 unsigned short* __restrict__ out)
{
  int t = blockIdx.x * 256 + threadIdx.x;  // 0..40959
  if (t >= 40960) return;
  int l = t / 20480;
  int o = t - l * 20480;
  const float* src;
  int midx;
  if (o < 12288)      { src = W1 + l * 12288; midx = o; }
  else if (o < 16384) { src = W2 + l * 4096;  midx = o - 12288; }
  else                { src = W3 + l * 4096;  midx = o - 16384; }
  int j = midx & 7;
  int lane = (midx >> 3) & 63;
  int blk = midx >> 9;
  int ct = blk & 1, kc = blk >> 1;
  int col = ct * 32 + (lane & 31);
  int k = kc * 16 + (lane >> 5) * 8 + j;
  out[l * 20480 + o] = f2b(src[k * 64 + col]);
}

// ---------------- pack feature-MLP weights (rd + sr), 36 blocks --------------
// blk 0..3 rdW1[24x64] (K pad 32), 4..11 rdW2[64x64], 12..19 rdW3[64x64],
// 20..23 srW1[24x64], 24..31 srW2[64x64], 32..35 srW3[64x16] (N pad 32).
__global__ void pack_feat_weights(const float* __restrict__ rdW1,
                                  const float* __restrict__ rdW2,
                                  const float* __restrict__ rdW3,
                                  const float* __restrict__ srW1,
                                  const float* __restrict__ srW2,
                                  const float* __restrict__ srW3,
                                  unsigned short* __restrict__ out)
{
  int t = blockIdx.x * 256 + threadIdx.x;  // 0..18431
  if (t >= 18432) return;
  const int blk = t >> 9, midx = t & 511;
  const int j = midx & 7, lane = (midx >> 3) & 63;
  const float* src; int kc, ct, K, NC;
  if (blk < 4)       { int b = blk;      src = rdW1; kc = b>>1; ct = b&1; K = 24; NC = 64; }
  else if (blk < 12) { int b = blk - 4;  src = rdW2; kc = b>>1; ct = b&1; K = 64; NC = 64; }
  else if (blk < 20) { int b = blk - 12; src = rdW3; kc = b>>1; ct = b&1; K = 64; NC = 64; }
  else if (blk < 24) { int b = blk - 20; src = srW1; kc = b>>1; ct = b&1; K = 24; NC = 64; }
  else if (blk < 32) { int b = blk - 24; src = srW2; kc = b>>1; ct = b&1; K = 64; NC = 64; }
  else               { int b = blk - 32; src = srW3; kc = b;    ct = 0;   K = 64; NC = 16; }
  const int col = ct * 32 + (lane & 31);
  const int k = kc * 16 + (lane >> 5) * 8 + j;
  const float v = (k < K && col < NC) ? src[k * NC + col] : 0.0f;
  out[t] = f2b(v);
}

// ---------------- stage-A via bf16 MFMA --------------------------------------
// 96 rows/block, 192 threads (3 waves), one barrier. Feature built scalar,
// rd-MLP (radial out, LN*ud) + sr-MLP (sval -> msgbuf) both on matrix cores.

#define FEAT_TRANS(BASEBLK, V0, V1) do {                                        \
    _Pragma("unroll")                                                           \
    for (int ct_ = 0; ct_ < 2; ++ct_) {                                         \
      const int colh_ = ct_*32 + cl;                                            \
      const int kc2_  = colh_ >> 4;                                             \
      const int b3_   = (colh_ >> 3) & 1;                                       \
      const int jj_   = colh_ & 7;                                              \
      const int blk_  = ((BASEBLK) + kc2_*3 + wave)*512;                        \
      _Pragma("unroll")                                                         \
      for (int q_ = 0; q_ < 16; ++q_) {                                         \
        const int row32_ = (q_ & 3) + 8*(q_ >> 2) + 4*(lane >> 5);              \
        const int s2_ = (row32_ & 31) + 32*b3_;                                 \
        const float v_ = ct_ ? (V1)[q_] : (V0)[q_];                             \
        afrag[blk_ + swz(s2_, kc2_)*8 + jj_] = f2b(fast_tanh(v_));              \
      }                                                                         \
    }                                                                           \
  } while (0)

template<int HAS_SR>
__launch_bounds__(192)
__global__ void feat_mfma(
    int nrows,
    const int* __restrict__ types, const float* __restrict__ lens,
    const float* __restrict__ vecs, const int* __restrict__ idx,
    const float* __restrict__ bessel_w,
    const unsigned short* __restrict__ wpackf,
    const float* __restrict__ srb1, const float* __restrict__ srb2,
    const float* __restrict__ srb3,
    const float* __restrict__ rdb1, const float* __restrict__ rdb2,
    const float* __restrict__ rdb3,
    const float* __restrict__ eln_g, const float* __restrict__ eln_b,
    float* __restrict__ radial_out, float* __restrict__ ud_out,
    float* __restrict__ msgbuf)
{
  // afrag blocks: feat kc0..1 -> 0..5 (kc*3+rt); int1 -> 6..17; int2 -> 18..29
  __shared__ __align__(16) unsigned short afrag[30*512];  // 30KB
  __shared__ __align__(16) unsigned short wlds[36*512];   // 36KB
  __shared__ float udl[96];

  const int tid  = threadIdx.x;    // 0..191
  const int lane = tid & 63;
  const int wave = tid >> 6;
  const int base = blockIdx.x * 96;
  const int cl   = lane & 31;

  // ---- stage packed weights ----
  for (int i = tid; i < 2304; i += 192)
    *(u16x8*)&wlds[i*8] = *(const u16x8*)&wpackf[i*8];

  // ---- feature build: 2 threads/row, k split by parity ----
  {
    const int r = tid >> 1, h = tid & 1;
    int rowc = base + r;
    const bool valid = rowc < nrows;
    if (!valid) rowc = nrows - 1;
    const int i0 = idx[rowc];
    const int i1 = idx[nrows + rowc];
    const float len = lens[rowc];
    const float ud = poly_cutoff(len);
    const int t0 = types[i0], t1 = types[i1];
    const float invl = 1.0f / len;
    const int rt = r >> 5;
    #pragma unroll
    for (int m = 0; m < 12; ++m) {
      const int k = h + m*2;
      float v;
      if (k < 4)      v = (t0 == k) ? 1.0f : 0.0f;
      else if (k < 8) v = (t1 == (k-4)) ? 1.0f : 0.0f;
      else            v = ud * BESSEL_PREF * __sinf(bessel_w[k-8] * len * RC_INV) * invl;
      const int kc = k >> 4;
      const int s_ = (r & 31) + 32*((k >> 3) & 1);
      afrag[(kc*3 + rt)*512 + swz(s_, kc)*8 + (k & 7)] = f2b(v);
    }
    #pragma unroll
    for (int m = 0; m < 4; ++m) {   // zero-pad k = 24..31
      const int k = 24 + h + m*2;
      const int s_ = (r & 31) + 32*((k >> 3) & 1);
      afrag[(1*3 + rt)*512 + swz(s_, 1)*8 + (k & 7)] = 0;
    }
    if (h == 0) {
      udl[r] = ud;
      if (valid) {
        ud_out[rowc] = ud;
        if (HAS_SR) {
          msgbuf[(size_t)rowc*20 + 16] = ud * vecs[(size_t)rowc*3 + 0];
          msgbuf[(size_t)rowc*20 + 17] = ud * vecs[(size_t)rowc*3 + 1];
          msgbuf[(size_t)rowc*20 + 18] = ud * vecs[(size_t)rowc*3 + 2];
        }
      }
    }
  }
  __syncthreads();   // the only block-wide barrier

  f32x16 acc0, acc1;

  // ======== rd path ========
  {
    const float bv0 = rdb1[cl], bv1 = rdb1[32 + cl];
    #pragma unroll
    for (int q = 0; q < 16; ++q) { acc0[q] = bv0; acc1[q] = bv1; }
  }
  #pragma unroll
  for (int kc = 0; kc < 2; ++kc) {
    const short8 a  = *(const short8*)&afrag[(kc*3 + wave)*512 + swz(lane, kc)*8];
    const short8 w0 = *(const short8*)&wlds[(kc*2 + 0)*512 + lane*8];
    const short8 w1 = *(const short8*)&wlds[(kc*2 + 1)*512 + lane*8];
    acc0 = __builtin_amdgcn_mfma_f32_32x32x16_bf16(a, w0, acc0, 0, 0, 0);
    acc1 = __builtin_amdgcn_mfma_f32_32x32x16_bf16(a, w1, acc1, 0, 0, 0);
  }
  FEAT_TRANS(6, acc0, acc1);

  {
    const float bv0 = rdb2[cl], bv1 = rdb2[32 + cl];
    #pragma unroll
    for (int q = 0; q < 16; ++q) { acc0[q] = bv0; acc1[q] = bv1; }
  }
  #pragma unroll
  for (int kc = 0; kc < 4; ++kc) {
    const short8 a  = *(const short8*)&afrag[((6 + kc*3) + wave)*512 + swz(lane, kc)*8];
    const short8 w0 = *(const short8*)&wlds[(4 + kc*2 + 0)*512 + lane*8];
    const short8 w1 = *(const short8*)&wlds[(4 + kc*2 + 1)*512 + lane*8];
    acc0 = __builtin_amdgcn_mfma_f32_32x32x16_bf16(a, w0, acc0, 0, 0, 0);
    acc1 = __builtin_amdgcn_mfma_f32_32x32x16_bf16(a, w1, acc1, 0, 0, 0);
  }
  FEAT_TRANS(18, acc0, acc1);

  {
    const float bv0 = rdb3[cl], bv1 = rdb3[32 + cl];
    #pragma unroll
    for (int q = 0; q < 16; ++q) { acc0[q] = bv0; acc1[q] = bv1; }
  }
  #pragma unroll
  for (int kc = 0; kc < 4; ++kc) {
    const short8 a  = *(const short8*)&afrag[((18 + kc*3) + wave)*512 + swz(lane, kc)*8];
    const short8 w0 = *(const short8*)&wlds[(12 + kc*2 + 0)*512 + lane*8];
    const short8 w1 = *(const short8*)&wlds[(12 + kc*2 + 1)*512 + lane*8];
    acc0 = __builtin_amdgcn_mfma_f32_32x32x16_bf16(a, w0, acc0, 0, 0, 0);
    acc1 = __builtin_amdgcn_mfma_f32_32x32x16_bf16(a, w1, acc1, 0, 0, 0);
  }
  // LN + *ud epilogue
  {
    const float eg0 = eln_g[cl],      eb0 = eln_b[cl];
    const float eg1 = eln_g[32 + cl], eb1 = eln_b[32 + cl];
    #pragma unroll
    for (int q = 0; q < 16; ++q) {
      const float v0 = acc0[q], v1 = acc1[q];
      float s = v0 + v1, ss = v0*v0 + v1*v1;
      #pragma unroll
      for (int o = 1; o <= 16; o <<= 1) {
        s  += __shfl_xor(s, o);
        ss += __shfl_xor(ss, o);
      }
      const float m   = s * (1.0f/64.0f);
      const float inv = rsqrtf(ss * (1.0f/64.0f) - m*m + LN_EPS);
      const int row32 = (q & 3) + 8*(q >> 2) + 4*(lane >> 5);
      const int rloc  = wave*32 + row32;
      const int row   = base + rloc;
      if (row < nrows) {
        const float u = udl[rloc];
        radial_out[(size_t)row*64 + cl]      = ((v0 - m)*inv*eg0 + eb0) * u;
        radial_out[(size_t)row*64 + 32 + cl] = ((v1 - m)*inv*eg1 + eb1) * u;
      }
    }
  }

  // ======== sr path ========
  if (HAS_SR) {
    {
      const float bv0 = srb1[cl], bv1 = srb1[32 + cl];
      #pragma unroll
      for (int q = 0; q < 16; ++q) { acc0[q] = bv0; acc1[q] = bv1; }
    }
    #pragma unroll
    for (int kc = 0; kc < 2; ++kc) {
      const short8 a  = *(const short8*)&afrag[(kc*3 + wave)*512 + swz(lane, kc)*8];
      const short8 w0 = *(const short8*)&wlds[(20 + kc*2 + 0)*512 + lane*8];
      const short8 w1 = *(const short8*)&wlds[(20 + kc*2 + 1)*512 + lane*8];
      acc0 = __builtin_amdgcn_mfma_f32_32x32x16_bf16(a, w0, acc0, 0, 0, 0);
      acc1 = __builtin_amdgcn_mfma_f32_32x32x16_bf16(a, w1, acc1, 0, 0, 0);
    }
    FEAT_TRANS(6, acc0, acc1);

    {
      const float bv0 = srb2[cl], bv1 = srb2[32 + cl];
      #pragma unroll
      for (int q = 0; q < 16; ++q) { acc0[q] = bv0; acc1[q] = bv1; }
    }
    #pragma unroll
    for (int kc = 0; kc < 4; ++kc) {
      const short8 a  = *(const short8*)&afrag[((6 + kc*3) + wave)*512 + swz(lane, kc)*8];
      const short8 w0 = *(const short8*)&wlds[(24 + kc*2 + 0)*512 + lane*8];
      const short8 w1 = *(const short8*)&wlds[(24 + kc*2 + 1)*512 + lane*8];
      acc0 = __builtin_amdgcn_mfma_f32_32x32x16_bf16(a, w0, acc0, 0, 0, 0);
      acc1 = __builtin_amdgcn_mfma_f32_32x32x16_bf16(a, w1, acc1, 0, 0, 0);
    }
    FEAT_TRANS(18, acc0, acc1);

    {
      const float bv0 = (cl < 16) ? srb3[cl] : 0.0f;
      #pragma unroll
      for (int q = 0; q < 16; ++q) acc0[q] = bv0;
    }
    #pragma unroll
    for (int kc = 0; kc < 4; ++kc) {
      const short8 a  = *(const short8*)&afrag[((18 + kc*3) + wave)*512 + swz(lane, kc)*8];
      const short8 w0 = *(const short8*)&wlds[(32 + kc)*512 + lane*8];
      acc0 = __builtin_amdgcn_mfma_f32_32x32x16_bf16(a, w0, acc0, 0, 0, 0);
    }
    if (cl < 16) {
      #pragma unroll
      for (int q = 0; q < 16; ++q) {
        const int row32 = (q & 3) + 8*(q >> 2) + 4*(lane >> 5);
        const int rloc  = wave*32 + row32;
        const int row   = base + rloc;
        if (row < nrows) msgbuf[(size_t)row*20 + cl] = acc0[q] * udl[rloc];
      }
    }
  }
}

// ---------------- SE(2) message gather: aggS (no atomics) --------------------
// one wave per node; lane<48 -> (d,c) of the 16x3 outer product.

__launch_bounds__(256)
__global__ void msg_gather_kernel(int N, const int* __restrict__ eoff,
                                  const int* __restrict__ perm,
                                  const float* __restrict__ msgbuf,
                                  float* __restrict__ aggS)
{
  const int w = (blockIdx.x * 256 + threadIdx.x) >> 6;
  const int lane = threadIdx.x & 63;
  if (w >= N) return;
  const int s = eoff[w], e = eoff[w + 1];
  const int d = lane / 3, c = lane - d * 3;
  float acc = 0.0f;
  for (int j = s; j < e; ++j) {
    const int ed = perm[j];
    if (lane < 48)
      acc += msgbuf[(size_t)ed*20 + d] * msgbuf[(size_t)ed*20 + 16 + c];
  }
  if (lane < 48) aggS[(size_t)w*48 + lane] = acc;
}

// ---------------- node embedding (gram + LN) ---------------------------------

__device__ __forceinline__ void block128_stats(float x, float& m, float& inv, float* red) {
  float s = x, ss = x*x;
  #pragma unroll
  for (int o = 32; o; o >>= 1) { s += __shfl_down(s, o); ss += __shfl_down(ss, o); }
  const int t = threadIdx.x;
  if ((t & 63) == 0) { red[(t >> 6)*2] = s; red[(t >> 6)*2 + 1] = ss; }
  __syncthreads();
  const float S = red[0] + red[2], SS = red[1] + red[3];
  m = S * (1.0f/128.0f);
  const float var = SS * (1.0f/128.0f) - m*m;
  inv = rsqrtf(var + LN_EPS);
}

__launch_bounds__(128)
__global__ void node_emb_kernel(int N, const float* __restrict__ aggS,
                                const int* __restrict__ ecnt,
                                const float* __restrict__ g, const float* __restrict__ b,
                                float* __restrict__ node_emb)
{
  const int n = blockIdx.x, t = threadIdx.x;
  __shared__ float S[48];
  __shared__ float red[4];
  if (t < 48) S[t] = aggS[(size_t)n*48 + t];
  __syncthreads();
  const float ic = 1.0f / fmaxf((float)ecnt[n], 1.0f);
  const int d = t >> 3, e = t & 7;
  const float x = (S[d*3+0]*S[e*3+0] + S[d*3+1]*S[e*3+1] + S[d*3+2]*S[e*3+2]) * ic * ic;
  float m, inv;
  block128_stats(x, m, inv, red);
  node_emb[(size_t)n*128 + t] = (x - m)*inv*g[t] + b[t];
}

// ---------------- per-layer aggregation: CSR gather (no atomics) -------------

__launch_bounds__(256)
__global__ void agg_gather_kernel(int N, const int* __restrict__ eoff,
                                  const int* __restrict__ perm,
                                  const float* __restrict__ radial,
                                  float* __restrict__ mean_r)
{
  const int w = (blockIdx.x * 256 + threadIdx.x) >> 6;
  const int lane = threadIdx.x & 63;
  if (w >= N) return;
  const int s = eoff[w], e = eoff[w + 1];
  float acc = 0.0f;
  for (int j = s; j < e; ++j) {
    const int ed = perm[j];
    acc += radial[(size_t)ed * 64 + lane];
  }
  const float inv = 1.0f / fmaxf((float)(e - s), 1.0f);
  mean_r[(size_t)w * 64 + lane] = acc * inv;
}

// ---------------- node update: (mean_r @ W + b) * old, LN, residual ----------

__launch_bounds__(256)
__global__ void node_update_gemm(
    int N, const float* __restrict__ mean_r, const int* __restrict__ ecnt,
    const float* __restrict__ W, const float* __restrict__ bias,
    const float* __restrict__ g, const float* __restrict__ b,
    float* __restrict__ node_emb)
{
  __shared__ __align__(16) float lw[64*128];
  __shared__ float lm[32][65];
  const int tid = threadIdx.x;
  const int base = blockIdx.x * 32;

  for (int i = tid; i < 8192; i += 256) lw[i] = W[i];
  {
    const int rr0 = tid >> 6, k = tid & 63;
    for (int rr = rr0; rr < 32; rr += 4) {
      const int n = base + rr;
      lm[rr][k] = (n < N) ? mean_r[(size_t)n*64 + k] : 0.0f;
    }
  }
  __syncthreads();

  const int r0 = (tid >> 5) * 4, j0 = (tid & 31) * 4;
  float acc[4][4];
  #pragma unroll
  for (int j = 0; j < 4; ++j) {
    const float bj = bias[j0 + j];
    acc[0][j] = bj; acc[1][j] = bj; acc[2][j] = bj; acc[3][j] = bj;
  }
  for (int k = 0; k < 64; ++k) {
    const float4 w = *(const float4*)&lw[k*128 + j0];
    const float s0 = lm[r0][k],   s1 = lm[r0+1][k];
    const float s2 = lm[r0+2][k], s3 = lm[r0+3][k];
    acc[0][0] += s0*w.x; acc[0][1] += s0*w.y; acc[0][2] += s0*w.z; acc[0][3] += s0*w.w;
    acc[1][0] += s1*w.x; acc[1][1] += s1*w.y; acc[1][2] += s1*w.z; acc[1][3] += s1*w.w;
    acc[2][0] += s2*w.x; acc[2][1] += s2*w.y; acc[2][2] += s2*w.z; acc[2][3] += s2*w.w;
    acc[3][0] += s3*w.x; acc[3][1] += s3*w.y; acc[3][2] += s3*w.z; acc[3][3] += s3*w.w;
  }

  const float g0 = g[j0], g1 = g[j0+1], g2 = g[j0+2], g3 = g[j0+3];
  const float bb0 = b[j0], bb1 = b[j0+1], bb2 = b[j0+2], bb3 = b[j0+3];
  #pragma unroll
  for (int i = 0; i < 4; ++i) {
    const int n = base + r0 + i;
    if (n >= N) continue;
    const float mask = (ecnt[n] > 0) ? 1.0f : 0.0f;
    const float4 old = *(const float4*)&node_emb[(size_t)n*128 + j0];
    const float x0 = old.x * acc[i][0] * mask;
    const float x1 = old.y * acc[i][1] * mask;
    const float x2 = old.z * acc[i][2] * mask;
    const float x3 = old.w * acc[i][3] * mask;
    float s = x0 + x1 + x2 + x3;
    float ss = x0*x0 + x1*x1 + x2*x2 + x3*x3;
    #pragma unroll
    for (int o = 1; o <= 16; o <<= 1) {
      s  += __shfl_xor(s, o);
      ss += __shfl_xor(ss, o);
    }
    const float m = s * (1.0f/128.0f);
    const float inv = rsqrtf(ss * (1.0f/128.0f) - m*m + LN_EPS);
    float4 o4;
    o4.x = C_RES*old.x + C_NEW*((x0 - m)*inv*g0 + bb0);
    o4.y = C_RES*old.y + C_NEW*((x1 - m)*inv*g1 + bb1);
    o4.z = C_RES*old.z + C_NEW*((x2 - m)*inv*g2 + bb2);
    o4.w = C_RES*old.w + C_NEW*((x3 - m)*inv*g3 + bb3);
    *(float4*)&node_emb[(size_t)n*128 + j0] = o4;
  }
}

// ---------------- embedding GEMM (K=64 -> N=128), hidden-init epilogue -------

__launch_bounds__(256)
__global__ void emb_gemm_kernel(
    int nrows,
    const float* __restrict__ radial,
    const float* __restrict__ W, const float* __restrict__ bias,
    const int* __restrict__ idx,
    const float* __restrict__ node_emb,
    float* __restrict__ out)
{
  __shared__ float lin[32][65];
  __shared__ __align__(16) float lw[64*128];
  const int tid = threadIdx.x;
  const int base = blockIdx.x * 32;

  for (int i = tid; i < 64*128; i += 256) lw[i] = W[i];
  {
    const int rr0 = tid >> 6, k = tid & 63;
    for (int rr = rr0; rr < 32; rr += 4) {
      const int row = base + rr;
      lin[rr][k] = (row < nrows) ? radial[(size_t)row*64 + k] : 0.0f;
    }
  }
  __syncthreads();

  const int r0 = (tid >> 5) * 4, j0 = (tid & 31) * 4;
  float acc[4][4];
  #pragma unroll
  for (int j = 0; j < 4; ++j) {
    const float bj = bias[j0 + j];
    acc[0][j] = bj; acc[1][j] = bj; acc[2][j] = bj; acc[3][j] = bj;
  }
  for (int k = 0; k < 64; ++k) {
    const float4 w = *(const float4*)&lw[k*128 + j0];
    const float s0 = lin[r0][k],   s1 = lin[r0+1][k];
    const float s2 = lin[r0+2][k], s3 = lin[r0+3][k];
    acc[0][0] += s0*w.x; acc[0][1] += s0*w.y; acc[0][2] += s0*w.z; acc[0][3] += s0*w.w;
    acc[1][0] += s1*w.x; acc[1][1] += s1*w.y; acc[1][2] += s1*w.z; acc[1][3] += s1*w.w;
    acc[2][0] += s2*w.x; acc[2][1] += s2*w.y; acc[2][2] += s2*w.z; acc[2][3] += s2*w.w;
    acc[3][0] += s3*w.x; acc[3][1] += s3*w.y; acc[3][2] += s3*w.z; acc[3][3] += s3*w.w;
  }
  #pragma unroll
  for (int i = 0; i < 4; ++i) {
    const int row = base + r0 + i;
    if (row >= nrows) continue;
    const int i0 = idx[row], i1 = idx[nrows + row];
    const float4 n0 = *(const float4*)&node_emb[(size_t)i0*128 + j0];
    const float4 n1 = *(const float4*)&node_emb[(size_t)i1*128 + j0];
    float4 o;
    o.x = acc[i][0] * 0.5f * (n0.x + n1.x);
    o.y = acc[i][1] * 0.5f * (n0.y + n1.y);
    o.z = acc[i][2] * 0.5f * (n0.z + n1.z);
    o.w = acc[i][3] * 0.5f * (n0.w + n1.w);
    *(float4*)&out[(size_t)row*128 + j0] = o;
  }
}

// ---------------- hidden MLP via bf16 MFMA -----------------------------------

__launch_bounds__(128)
__global__ void hid_mlp_mfma(
    int nrows, const int* __restrict__ idx0,
    const float* __restrict__ node_emb,
    const unsigned short* __restrict__ wpack,   // 65536 ushorts for this layer
    const float* __restrict__ b1, const float* __restrict__ b2,
    const float* __restrict__ b3,
    float* __restrict__ hidden)
{
  __shared__ __align__(16) unsigned short h_afrag[16384];  // 32KB: [rt4][kc8]*512
  __shared__ __align__(16) unsigned short xg[4096];        // 8KB:  [rt4][kcl2]*512
  __shared__ __align__(16) unsigned short wg[4096];        // 8KB:  [kcl2][ct4]*512

  const int tid  = threadIdx.x;
  const int lane = tid & 63;
  const int wave = tid >> 6;
  const int base = blockIdx.x * 128;

  const int r = tid;                       // staging row 0..127
  int rowg = base + r;
  if (rowg >= nrows) rowg = nrows - 1;
  const int i0 = idx0[rowg];
  const float* xsrc0 = node_emb + (size_t)i0 * 128;
  const float* xsrc1 = hidden + (size_t)rowg * 128;

  f32x16 acc[2][4];

  // ---------- layer 1: K=256, 8 phases x (2 kc) ----------
  #pragma unroll
  for (int ct = 0; ct < 4; ++ct) {
    const float bv = b1[ct*32 + (lane & 31)];
    #pragma unroll
    for (int q = 0; q < 16; ++q) { acc[0][ct][q] = bv; acc[1][ct][q] = bv; }
  }
  for (int p = 0; p < 8; ++p) {
    __syncthreads();
    #pragma unroll
    for (int o = 0; o < 4; ++o) {
      const int k = p*32 + o*8;
      const float* s = (k < 128) ? (xsrc0 + k) : (xsrc1 + (k - 128));
      const float4 v0 = *(const float4*)s;
      const float4 v1 = *(const float4*)(s + 4);
      u16x8 w;
      w[0]=f2b(v0.x); w[1]=f2b(v0.y); w[2]=f2b(v0.z); w[3]=f2b(v0.w);
      w[4]=f2b(v1.x); w[5]=f2b(v1.y); w[6]=f2b(v1.z); w[7]=f2b(v1.w);
      const int kc = p*2 + (o >> 1);
      const int s_ = (r & 31) + 32*(o & 1);
      *(u16x8*)&xg[ ((r>>5)*2 + (o>>1))*512 + swz(s_, kc)*8 ] = w;
    }
    #pragma unroll
    for (int i = 0; i < 4; ++i) {
      const int c = tid + i*128;
      *(u16x8*)&wg[c*8] = *(const u16x8*)&wpack[p*4096 + c*8];
    }
    __syncthreads();
    #pragma unroll
    for (int kcl = 0; kcl < 2; ++kcl) {
      const int kc = p*2 + kcl;
      const short8 a0 = *(const short8*)&xg[ ((wave*2+0)*2 + kcl)*512 + swz(lane, kc)*8 ];
      const short8 a1 = *(const short8*)&xg[ ((wave*2+1)*2 + kcl)*512 + swz(lane, kc)*8 ];
      #pragma unroll
      for (int ct = 0; ct < 4; ++ct) {
        const short8 b = *(const short8*)&wg[ (kcl*4 + ct)*512 + lane*8 ];
        acc[0][ct] = __builtin_amdgcn_mfma_f32_32x32x16_bf16(a0, b, acc[0][ct], 0, 0, 0);
        acc[1][ct] = __builtin_amdgcn_mfma_f32_32x32x16_bf16(a1, b, acc[1][ct], 0, 0, 0);
      }
    }
  }

  // ---------- transition 1: tanh -> h_afrag ----------
  __syncthreads();
  #pragma unroll
  for (int m = 0; m < 2; ++m) {
    const int rt = wave*2 + m;
    #pragma unroll
    for (int ct = 0; ct < 4; ++ct) {
      const int kc  = ct*2 + ((lane >> 4) & 1);
      const int oct = (lane >> 3) & 1;
      const int j   = lane & 7;
      const int xk  = (oct << 1) ^ ((kc & 1) << 2);
      const int hi  = 4*(lane >> 5);
      const int bi  = (rt*8 + kc)*512 + oct*256 + j;
      #pragma unroll
      for (int q = 0; q < 16; ++q) {
        const int m32 = (q & 3) + 8*(q >> 2) + hi;
        h_afrag[bi + (m32 ^ xk)*8] = f2b(fast_tanh(acc[m][ct][q]));
      }
    }
  }
  #pragma unroll
  for (int ct = 0; ct < 4; ++ct) {
    const float bv = b2[ct*32 + (lane & 31)];
    #pragma unroll
    for (int q = 0; q < 16; ++q) { acc[0][ct][q] = bv; acc[1][ct][q] = bv; }
  }
  __syncthreads();

  // ---------- layer 2: K=128, 4 phases x (2 kc) ----------
  for (int p = 0; p < 4; ++p) {
    __syncthreads();
    #pragma unroll
    for (int i = 0; i < 4; ++i) {
      const int c = tid + i*128;
      *(u16x8*)&wg[c*8] = *(const u16x8*)&wpack[32768 + p*4096 + c*8];
    }
    __syncthreads();
    #pragma unroll
    for (int kcl = 0; kcl < 2; ++kcl) {
      const int kc = p*2 + kcl;
      const short8 a0 = *(const short8*)&h_afrag[ ((wave*2+0)*8 + kc)*512 + swz(lane, kc)*8 ];
      const short8 a1 = *(const short8*)&h_afrag[ ((wave*2+1)*8 + kc)*512 + swz(lane, kc)*8 ];
      #pragma unroll
      for (int ct = 0; ct < 4; ++ct) {
        const short8 b = *(const short8*)&wg[ (kcl*4 + ct)*512 + lane*8 ];
        acc[0][ct] = __builtin_amdgcn_mfma_f32_32x32x16_bf16(a0, b, acc[0][ct], 0, 0, 0);
        acc[1][ct] = __builtin_amdgcn_mfma_f32_32x32x16_bf16(a1, b, acc[1][ct], 0, 0, 0);
      }
    }
  }

  // ---------- transition 2: tanh -> h_afrag (overwrite) ----------
  __syncthreads();
  #pragma unroll
  for (int m = 0; m < 2; ++m) {
    const int rt = wave*2 + m;
    #pragma unroll
    for (int ct = 0; ct < 4; ++ct) {
      const int kc  = ct*2 + ((lane >> 4) & 1);
      const int oct = (lane >> 3) & 1;
      const int j   = lane & 7;
      const int xk  = (oct << 1) ^ ((kc & 1) << 2);
      const int hi  = 4*(lane >> 5);
      const int bi  = (rt*8 + kc)*512 + oct*256 + j;
      #pragma unroll
      for (int q = 0; q < 16; ++q) {
        const int m32 = (q & 3) + 8*(q >> 2) + hi;
        h_afrag[bi + (m32 ^ xk)*8] = f2b(fast_tanh(acc[m][ct][q]));
      }
    }
  }
  #pragma unroll
  for (int ct = 0; ct < 4; ++ct) {
    const float bv = b3[ct*32 + (lane & 31)];
    #pragma unroll
    for (int q = 0; q < 16; ++q) { acc[0][ct][q] = bv; acc[1][ct][q] = bv; }
  }
  __syncthreads();

  // ---------- layer 3: K=128 ----------
  for (int p = 0; p < 4; ++p) {
    __syncthreads();
    #pragma unroll
    for (int i = 0; i < 4; ++i) {
      const int c = tid + i*128;
      *(u16x8*)&wg[c*8] = *(const u16x8*)&wpack[49152 + p*4096 + c*8];
    }
    __syncthreads();
    #pragma unroll
    for (int kcl = 0; kcl < 2; ++kcl) {
      const int kc = p*2 + kcl;
      const short8 a0 = *(const short8*)&h_afrag[ ((wave*2+0)*8 + kc)*512 + swz(lane, kc)*8 ];
      const short8 a1 = *(const short8*)&h_afrag[ ((wave*2+1)*8 + kc)*512 + swz(lane, kc)*8 ];
      #pragma unroll
      for (int ct = 0; ct < 4; ++ct) {
        const short8 b = *(const short8*)&wg[ (kcl*4 + ct)*512 + lane*8 ];
        acc[0][ct] = __builtin_amdgcn_mfma_f32_32x32x16_bf16(a0, b, acc[0][ct], 0, 0, 0);
        acc[1][ct] = __builtin_amdgcn_mfma_f32_32x32x16_bf16(a1, b, acc[1][ct], 0, 0, 0);
      }
    }
  }

  // ---------- epilogue: store f32 ----------
  #pragma unroll
  for (int m = 0; m < 2; ++m) {
    #pragma unroll
    for (int ct = 0; ct < 4; ++ct) {
      const int col = ct*32 + (lane & 31);
      #pragma unroll
      for (int q = 0; q < 16; ++q) {
        const int row = base + (wave*2+m)*32 + (q & 3) + 8*(q >> 2) + 4*(lane >> 5);
        if (row < nrows) hidden[(size_t)row*128 + col] = acc[m][ct][q];
      }
    }
  }
}

// ---------------- radial ResNet via bf16 MFMA --------------------------------

__launch_bounds__(192)
__global__ void rdl_mfma(
    int nrows,
    const float* __restrict__ hidden, const float* __restrict__ ud,
    const unsigned short* __restrict__ wpack,   // 20480 ushorts this layer
    const float* __restrict__ b1, const float* __restrict__ b2,
    const float* __restrict__ b3,
    const float* __restrict__ eln_g, const float* __restrict__ eln_b,
    float* __restrict__ radial)
{
  __shared__ __align__(16) unsigned short afrag[36*512];  // 36KB
  __shared__ __align__(16) unsigned short wlds[40*512];   // 40KB
  __shared__ float udl[96];

  const int tid  = threadIdx.x;    // 0..191
  const int lane = tid & 63;
  const int wave = tid >> 6;       // rt
  const int base = blockIdx.x * 96;
  const int cl   = lane & 31;

  for (int i = tid; i < 2560; i += 192) {
    *(u16x8*)&wlds[i*8] = *(const u16x8*)&wpack[i*8];
  }
  {
    const int r  = tid >> 1;       // 0..95
    const int kh = tid & 1;
    int rowg = base + r;
    if (rowg >= nrows) rowg = nrows - 1;
    const float* rsrc = radial + (size_t)rowg * 64;
    const float* hsrc = hidden + (size_t)rowg * 128;
    if (kh == 0) udl[r] = ud[rowg];
    #pragma unroll
    for (int g = 0; g < 12; ++g) {
      const int k = kh*96 + g*8;
      const float* s = (k < 64) ? (rsrc + k) : (hsrc + (k - 64));
      const float4 v0 = *(const float4*)s;
      const float4 v1 = *(const float4*)(s + 4);
      u16x8 w;
      w[0]=f2b(v0.x); w[1]=f2b(v0.y); w[2]=f2b(v0.z); w[3]=f2b(v0.w);
      w[4]=f2b(v1.x); w[5]=f2b(v1.y); w[6]=f2b(v1.z); w[7]=f2b(v1.w);
      const int kc = k >> 4;
      const int s_ = (r & 31) + 32*((k >> 3) & 1);
      *(u16x8*)&afrag[(kc*3 + (r>>5))*512 + swz(s_, kc)*8] = w;
    }
  }
  __syncthreads();   // the only block-wide barrier

  f32x16 acc0, acc1;
  {
    const float bv0 = b1[cl], bv1 = b1[32 + cl];
    #pragma unroll
    for (int q = 0; q < 16; ++q) { acc0[q] = bv0; acc1[q] = bv1; }
  }
  #pragma unroll
  for (int kc = 0; kc < 12; ++kc) {
    const short8 a  = *(const short8*)&afrag[(kc*3 + wave)*512 + swz(lane, kc)*8];
    const short8 w0 = *(const short8*)&wlds[(kc*2 + 0)*512 + lane*8];
    const short8 w1 = *(const short8*)&wlds[(kc*2 + 1)*512 + lane*8];
    acc0 = __builtin_amdgcn_mfma_f32_32x32x16_bf16(a, w0, acc0, 0, 0, 0);
    acc1 = __builtin_amdgcn_mfma_f32_32x32x16_bf16(a, w1, acc1, 0, 0, 0);
  }

  #pragma unroll
  for (int ct = 0; ct < 2; ++ct) {
    const int colh = ct*32 + cl;
    const int kc2  = colh >> 4;
    const int b3_  = (colh >> 3) & 1;
    const int jj   = colh & 7;
    const int blk  = ((4 + kc2)*3 + wave)*512;
    #pragma unroll
    for (int q = 0; q < 16; ++q) {
      const int row32 = (q & 3) + 8*(q >> 2) + 4*(lane >> 5);
      const int s_ = (row32 & 31) + 32*b3_;
      const float v = ct ? acc1[q] : acc0[q];
      afrag[blk + swz(s_, kc2)*8 + jj] = f2b(fast_tanh(v));
    }
  }

  f32x16 h0, h1;
  {
    const float bv0 = b2[cl], bv1 = b2[32 + cl];
    #pragma unroll
    for (int q = 0; q < 16; ++q) { h0[q] = bv0; h1[q] = bv1; }
  }
  #pragma unroll
  for (int kc = 0; kc < 4; ++kc) {
    const short8 a  = *(const short8*)&afrag[((4 + kc)*3 + wave)*512 + swz(lane, kc)*8];
    const short8 w0 = *(const short8*)&wlds[(24 + kc*2 + 0)*512 + lane*8];
    const short8 w1 = *(const short8*)&wlds[(24 + kc*2 + 1)*512 + lane*8];
    h0 = __builtin_amdgcn_mfma_f32_32x32x16_bf16(a, w0, h0, 0, 0, 0);
    h1 = __builtin_amdgcn_mfma_f32_32x32x16_bf16(a, w1, h1, 0, 0, 0);
  }

  #pragma unroll
  for (int ct = 0; ct < 2; ++ct) {
    const int colh = ct*32 + cl;
    const int kc2  = colh >> 4;
    const int b3_  = (colh >> 3) & 1;
    const int jj   = colh & 7;
    const int blk  = ((8 + kc2)*3 + wave)*512;
    #pragma unroll
    for (int q = 0; q < 16; ++q) {
      const int row32 = (q & 3) + 8*(q >> 2) + 4*(lane >> 5);
      const int s_ = (row32 & 31) + 32*b3_;
      const float v = ct ? h1[q] : h0[q];
      afrag[blk + swz(s_, kc2)*8 + jj] = f2b(fast_tanh(v));
    }
  }

  {
    const float bv0 = b3[cl], bv1 = b3[32 + cl];
    #pragma unroll
    for (int q = 0; q < 16; ++q) { acc0[q] = bv0; acc1[q] = bv1; }
  }
  #pragma unroll
  for (int kc = 0; kc < 4; ++kc) {
    const short8 a  = *(const short8*)&afrag[((8 + kc)*3 + wave)*512 + swz(lane, kc)*8];
    const short8 w0 = *(const short8*)&wlds[(32 + kc*2 + 0)*512 + lane*8];
    const short8 w1 = *(const short8*)&wlds[(32 + kc*2 + 1)*512 + lane*8];
    acc0 = __builtin_amdgcn_mfma_f32_32x32x16_bf16(a, w0, acc0, 0, 0, 0);
    acc1 = __builtin_amdgcn_mfma_f32_32x32x16_bf16(a, w1, acc1, 0, 0, 0);
  }

  const float eg0 = eln_g[cl],      eb0 = eln_b[cl];
  const float eg1 = eln_g[32 + cl], eb1 = eln_b[32 + cl];
  const int kcA = cl >> 4;
  const int kcB = (32 + cl) >> 4;
  const int jA  = cl & 7;
  const int jB  = cl & 7;
  const int bA  = (kcA*3 + wave)*512;
  const int bB  = (kcB*3 + wave)*512;
  const int b3A = (cl >> 3) & 1;
  const int b3B = ((32 + cl) >> 3) & 1;

  #pragma unroll
  for (int q = 0; q < 16; ++q) {
    const float v0 = acc0[q] + h0[q];
    const float v1 = acc1[q] + h1[q];
    float s = v0 + v1, ss = v0*v0 + v1*v1;
    #pragma unroll
    for (int o = 1; o <= 16; o <<= 1) {
      s  += __shfl_xor(s, o);
      ss += __shfl_xor(ss, o);
    }
    const float m   = s * (1.0f/64.0f);
    const float inv = rsqrtf(ss * (1.0f/64.0f) - m*m + LN_EPS);
    const int row32 = (q & 3) + 8*(q >> 2) + 4*(lane >> 5);
    const int rloc  = wave*32 + row32;
    const int row   = base + rloc;
    if (row < nrows) {
      const float u = udl[rloc];
      const int sA = (row32 & 31) + 32*b3A;
      const int sB = (row32 & 31) + 32*b3B;
      const float oldA = __uint_as_float((unsigned)afrag[bA + swz(sA, kcA)*8 + jA] << 16);
      const float oldB = __uint_as_float((unsigned)afrag[bB + swz(sB, kcB)*8 + jB] << 16);
      radial[(size_t)row*64 + cl]      = C_RES*oldA + C_NEW*u*((v0 - m)*inv*eg0 + eb0);
      radial[(size_t)row*64 + 32 + cl] = C_RES*oldB + C_NEW*u*((v1 - m)*inv*eg1 + eb1);
    }
  }
}

// ---------------- launch -----------------------------------------------------

extern "C" void kernel_launch(void* const* d_in, const int* in_sizes, int n_in,
                              void* d_out, int out_size, void* d_ws, size_t ws_size,
                              hipStream_t stream)
{
  const int*   atom_types = (const int*)  d_in[0];
  const float* env_vec    = (const float*)d_in[1];
  const float* env_len    = (const float*)d_in[2];
  const float* edge_len   = (const float*)d_in[3];
  const int*   env_idx    = (const int*)  d_in[4];
  const int*   edge_idx   = (const int*)  d_in[5];
  const float* bessel_w   = (const float*)d_in[6];
  const float* srW1 = (const float*)d_in[7];  const float* srb1 = (const float*)d_in[8];
  const float* srW2 = (const float*)d_in[9];  const float* srb2 = (const float*)d_in[10];
  const float* srW3 = (const float*)d_in[11]; const float* srb3 = (const float*)d_in[12];
  const float* rdW1 = (const float*)d_in[13]; const float* rdb1 = (const float*)d_in[14];
  const float* rdW2 = (const float*)d_in[15]; const float* rdb2 = (const float*)d_in[16];
  const float* rdW3 = (const float*)d_in[17]; const float* rdb3 = (const float*)d_in[18];
  const float* ne_emb_W = (const float*)d_in[19]; const float* ne_emb_b = (const float*)d_in[20];
  const float* ne_nln_g = (const float*)d_in[21]; const float* ne_nln_b = (const float*)d_in[22];
  const float* ne_eln_g = (const float*)d_in[23]; const float* ne_eln_b = (const float*)d_in[24];
  const float* ly_emb_W = (const float*)d_in[25]; const float* ly_emb_b = (const float*)d_in[26];
  const float* ly_hid_W1 = (const float*)d_in[27]; const float* ly_hid_b1 = (const float*)d_in[28];
  const float* ly_hid_W2 = (const float*)d_in[29]; const float* ly_hid_b2 = (const float*)d_in[30];
  const float* ly_hid_W3 = (const float*)d_in[31]; const float* ly_hid_b3 = (const float*)d_in[32];
  const float* ly_rdl_W1 = (const float*)d_in[33]; const float* ly_rdl_b1 = (const float*)d_in[34];
  const float* ly_rdl_W2 = (const float*)d_in[35]; const float* ly_rdl_b2 = (const float*)d_in[36];
  const float* ly_rdl_W3 = (const float*)d_in[37]; const float* ly_rdl_b3 = (const float*)d_in[38];
  const float* ly_nln_g = (const float*)d_in[39]; const float* ly_nln_b = (const float*)d_in[40];
  const float* ly_eln_g = (const float*)d_in[41]; const float* ly_eln_b = (const float*)d_in[42];

  const int N  = in_sizes[0];
  const int E  = in_sizes[2];
  const int E2 = in_sizes[3];

  float* out = (float*)d_out;
  float* env_radial  = out;
  float* edge_radial = env_radial + (size_t)E * 64;
  float* node_emb    = edge_radial + (size_t)E2 * 64;
  float* env_hidden  = node_emb + (size_t)N * 128;
  float* edge_hidden = env_hidden + (size_t)E * 128;

  float* ws = (float*)d_ws;
  float* ud_env  = ws;  ws += E;
  float* ud_edge = ws;  ws += E2;
  float* aggS    = ws;  ws += (size_t)N * 48;
  float* msgbuf  = ws;  ws += (size_t)E * 20;   // sval[16] | evud[3] | pad
  float* mean_r  = msgbuf;                      // reuse after msg_gather
  unsigned short* wpack  = (unsigned short*)ws; ws += 65536;   // hid: 2 x 65536 u16
  unsigned short* wpack2 = (unsigned short*)ws; ws += 20480;   // rdl: 2 x 20480 u16
  unsigned short* wpack3 = (unsigned short*)ws; ws += 9216;    // feat: 18432 u16
  int* ecnt = (int*)ws; ws += N;
  int* eoff = (int*)ws; ws += N + 1;
  int* ecur = (int*)ws; ws += N + 1;
  int* perm = (int*)ws; ws += E;

  const int gE  = (E  + 31) / 32;
  const int gE2 = (E2 + 31) / 32;
  const int gEh  = (E  + 127) / 128;
  const int gE2h = (E2 + 127) / 128;
  const int gEr  = (E  + 95) / 96;
  const int gE2r = (E2 + 95) / 96;
  const int gN32 = (N + 31) / 32;
  const int gN4w = (N * 64 + 255) / 256;

  // CSR build over env graph (i1 = env_idx[1])
  zero_int_kernel<<<256, 256, 0, stream>>>(ecnt, N);
  hist_kernel<<<(E + 255) / 256, 256, 0, stream>>>(E, env_idx, ecnt);
  scan_kernel<<<1, 1024, 0, stream>>>(ecnt, eoff, ecur, N);
  scatter_kernel<<<(E + 255) / 256, 256, 0, stream>>>(E, env_idx, ecur, perm);

  pack_hid_weights<<<512, 256, 0, stream>>>(ly_hid_W1, ly_hid_W2, ly_hid_W3, wpack);
  pack_rdl_weights<<<160, 256, 0, stream>>>(ly_rdl_W1, ly_rdl_W2, ly_rdl_W3, wpack2);
  pack_feat_weights<<<72, 256, 0, stream>>>(rdW1, rdW2, rdW3, srW1, srW2, srW3, wpack3);

  feat_mfma<1><<<gEr, 192, 0, stream>>>(E, atom_types, env_len, env_vec, env_idx, bessel_w,
      wpack3, srb1, srb2, srb3, rdb1, rdb2, rdb3,
      ne_eln_g, ne_eln_b, env_radial, ud_env, msgbuf);
  feat_mfma<0><<<gE2r, 192, 0, stream>>>(E2, atom_types, edge_len, nullptr, edge_idx, bessel_w,
      wpack3, srb1, srb2, srb3, rdb1, rdb2, rdb3,
      ne_eln_g, ne_eln_b, edge_radial, ud_edge, nullptr);

  msg_gather_kernel<<<gN4w, 256, 0, stream>>>(N, eoff, perm, msgbuf, aggS);
  node_emb_kernel<<<N, 128, 0, stream>>>(N, aggS, ecnt, ne_nln_g, ne_nln_b, node_emb);

  emb_gemm_kernel<<<gE, 256, 0, stream>>>(E, env_radial, ne_emb_W, ne_emb_b, env_idx, node_emb, env_hidden);
  emb_gemm_kernel<<<gE2, 256, 0, stream>>>(E2, edge_radial, ne_emb_W, ne_emb_b, edge_idx, node_emb, edge_hidden);

  for (int l = 0; l < 2; ++l) {
    agg_gather_kernel<<<gN4w, 256, 0, stream>>>(N, eoff, perm, env_radial, mean_r);
    node_update_gemm<<<gN32, 256, 0, stream>>>(N, mean_r, ecnt,
        ly_emb_W + (size_t)l*64*128, ly_emb_b + (size_t)l*128,
        ly_nln_g + (size_t)l*128, ly_nln_b + (size_t)l*128, node_emb);

    hid_mlp_mfma<<<gEh, 128, 0, stream>>>(E, env_idx, node_emb,
        wpack + (size_t)l*65536,
        ly_hid_b1 + (size_t)l*128, ly_hid_b2 + (size_t)l*128, ly_hid_b3 + (size_t)l*128,
        env_hidden);
    hid_mlp_mfma<<<gE2h, 128, 0, stream>>>(E2, edge_idx, node_emb,
        wpack + (size_t)l*65536,
        ly_hid_b1 + (size_t)l*128, ly_hid_b2 + (size_t)l*128, ly_hid_b3 + (size_t)l*128,
        edge_hidden);

    rdl_mfma<<<gEr, 192, 0, stream>>>(E, env_hidden, ud_env,
        wpack2 + (size_t)l*20480,
        ly_rdl_b1 + (size_t)l*64, ly_rdl_b2 + (size_t)l*64, ly_rdl_b3 + (size_t)l*64,
        ly_eln_g + (size_t)l*64, ly_eln_b + (size_t)l*64, env_radial);
    rdl_mfma<<<gE2r, 192, 0, stream>>>(E2, edge_hidden, ud_edge,
        wpack2 + (size_t)l*20480,
        ly_rdl_b1 + (size_t)l*64, ly_rdl_b2 + (size_t)l*64, ly_rdl_b3 + (size_t)l*64,
        ly_eln_g + (size_t)l*64, ly_eln_b + (size_t)l*64, edge_radial);
  }
}

// Round 6
// 1409.653 us; speedup vs baseline: 5.3621x; 1.2752x over previous
//
#include <hip/hip_runtime.h>
#include <math.h>

#define C_RES 0.89442719f
#define C_NEW 0.4472f
#define LN_EPS 1e-5f
#define BESSEL_PREF 0.6324555320336759f  // sqrt(2/5)
#define RC_INV 0.2f

typedef __attribute__((ext_vector_type(8))) short short8;
typedef __attribute__((ext_vector_type(8))) unsigned short u16x8;
typedef __attribute__((ext_vector_type(16))) float f32x16;

__device__ __forceinline__ float fast_tanh(float x) {
  float ax = fabsf(x);
  float e = __expf(2.0f * ax);
  float t = 1.0f - 2.0f / (e + 1.0f);
  return copysignf(t, x);
}

__device__ __forceinline__ unsigned short f2b(float f) {
  unsigned int u = __float_as_uint(f);
  unsigned int r = (u + 0x7FFFu + ((u >> 16) & 1u)) >> 16;
  return (unsigned short)r;
}

__device__ __forceinline__ float poly_cutoff(float x) {
  float xr = x * RC_INV;
  if (xr >= 1.0f) return 0.0f;
  float x2 = xr * xr;
  float x3 = x2 * xr;
  float x6 = x3 * x3;
  return 1.0f - 28.0f * x6 + 48.0f * x6 * xr - 21.0f * x6 * x2;
}

// A-frag slot swizzle: spreads the strided aliasing of the C/D->A scatter
// writes across banks; reads stay a permutation (conflict-free).
__device__ __forceinline__ int swz(int s, int kc) {
  return s ^ ((s >> 5) << 1) ^ ((kc & 1) << 2);
}

__global__ void zero_int_kernel(int* __restrict__ p, int n) {
  int i = blockIdx.x * blockDim.x + threadIdx.x;
  int stride = gridDim.x * blockDim.x;
  for (; i < n; i += stride) p[i] = 0;
}

// ---------------- CSR build: hist -> scan -> scatter --------------------------

__global__ void hist_kernel(int E, const int* __restrict__ idx, int* __restrict__ ecnt) {
  int t = blockIdx.x * 256 + threadIdx.x;
  if (t < E) atomicAdd(&ecnt[idx[E + t]], 1);
}

__launch_bounds__(1024)
__global__ void scan_kernel(const int* __restrict__ ecnt, int* __restrict__ eoff,
                            int* __restrict__ ecur, int n) {
  __shared__ int wsum[16];
  __shared__ int carry;
  const int tid = threadIdx.x;
  const int lane = tid & 63, wid = tid >> 6;
  if (tid == 0) carry = 0;
  __syncthreads();
  for (int b0 = 0; b0 < n; b0 += 1024) {
    const int i = b0 + tid;
    const int v = (i < n) ? ecnt[i] : 0;
    int incl = v;
    #pragma unroll
    for (int o = 1; o < 64; o <<= 1) {
      const int t = __shfl_up(incl, o);
      if (lane >= o) incl += t;
    }
    if (lane == 63) wsum[wid] = incl;
    __syncthreads();
    if (wid == 0) {
      const int wv = (lane < 16) ? wsum[lane] : 0;
      int wsc = wv;
      #pragma unroll
      for (int o = 1; o < 16; o <<= 1) {
        const int t = __shfl_up(wsc, o);
        if (lane >= o) wsc += t;
      }
      if (lane < 16) wsum[lane] = wsc - wv;  // exclusive
    }
    __syncthreads();
    const int c0 = carry;
    const int excl = c0 + wsum[wid] + incl - v;
    if (i < n) { eoff[i] = excl; ecur[i] = excl; }
    __syncthreads();
    if (tid == 1023) carry = c0 + wsum[15] + incl;
    __syncthreads();
  }
  if (tid == 0) eoff[n] = carry;
}

__global__ void scatter_kernel(int E, const int* __restrict__ idx,
                               int* __restrict__ ecur, int* __restrict__ perm) {
  int t = blockIdx.x * 256 + threadIdx.x;
  if (t < E) {
    const int pos = atomicAdd(&ecur[idx[E + t]], 1);
    perm[pos] = t;
  }
}

// ---------------- pack hidden-MLP weights into bf16 MFMA B-fragment order ----
__global__ void pack_hid_weights(const float* __restrict__ W1,
                                 const float* __restrict__ W2,
                                 const float* __restrict__ W3,
                                 unsigned short* __restrict__ out)
{
  int t = blockIdx.x * 256 + threadIdx.x;  // 0..131071
  if (t >= 131072) return;
  int l = t >> 16;
  int oidx = t & 65535;
  const float* src;
  int midx;
  if (oidx < 32768)      { src = W1 + l * 32768; midx = oidx; }
  else if (oidx < 49152) { src = W2 + l * 16384; midx = oidx - 32768; }
  else                   { src = W3 + l * 16384; midx = oidx - 49152; }
  int j = midx & 7;
  int lane = (midx >> 3) & 63;
  int blk = midx >> 9;
  int ct = blk & 3, kc = blk >> 2;
  int col = ct * 32 + (lane & 31);
  int k = kc * 16 + (lane >> 5) * 8 + j;
  out[l * 65536 + oidx] = f2b(src[k * 128 + col]);
}

// ---------------- pack radial-ResNet weights, N=64 (ct in 0..1) --------------
__global__ void pack_rdl_weights(const float* __restrict__ W1,
                                 const float* __restrict__ W2,
                                 const float* __restrict__ W3,
                                 unsigned short* __restrict__ out)
{
  int t = blockIdx.x * 256 + threadIdx.x;  // 0..40959
  if (t >= 40960) return;
  int l = t / 20480;
  int o = t - l * 20480;
  const float* src;
  int midx;
  if (o < 12288)      { src = W1 + l * 12288; midx = o; }
  else if (o < 16384) { src = W2 + l * 4096;  midx = o - 12288; }
  else                { src = W3 + l * 4096;  midx = o - 16384; }
  int j = midx & 7;
  int lane = (midx >> 3) & 63;
  int blk = midx >> 9;
  int ct = blk & 1, kc = blk >> 1;
  int col = ct * 32 + (lane & 31);
  int k = kc * 16 + (lane >> 5) * 8 + j;
  out[l * 20480 + o] = f2b(src[k * 64 + col]);
}

// ---------------- pack feature-MLP weights (rd + sr), 36 blocks --------------
__global__ void pack_feat_weights(const float* __restrict__ rdW1,
                                  const float* __restrict__ rdW2,
                                  const float* __restrict__ rdW3,
                                  const float* __restrict__ srW1,
                                  const float* __restrict__ srW2,
                                  const float* __restrict__ srW3,
                                  unsigned short* __restrict__ out)
{
  int t = blockIdx.x * 256 + threadIdx.x;  // 0..18431
  if (t >= 18432) return;
  const int blk = t >> 9, midx = t & 511;
  const int j = midx & 7, lane = (midx >> 3) & 63;
  const float* src; int kc, ct, K, NC;
  if (blk < 4)       { int b = blk;      src = rdW1; kc = b>>1; ct = b&1; K = 24; NC = 64; }
  else if (blk < 12) { int b = blk - 4;  src = rdW2; kc = b>>1; ct = b&1; K = 64; NC = 64; }
  else if (blk < 20) { int b = blk - 12; src = rdW3; kc = b>>1; ct = b&1; K = 64; NC = 64; }
  else if (blk < 24) { int b = blk - 20; src = srW1; kc = b>>1; ct = b&1; K = 24; NC = 64; }
  else if (blk < 32) { int b = blk - 24; src = srW2; kc = b>>1; ct = b&1; K = 64; NC = 64; }
  else               { int b = blk - 32; src = srW3; kc = b;    ct = 0;   K = 64; NC = 16; }
  const int col = ct * 32 + (lane & 31);
  const int k = kc * 16 + (lane >> 5) * 8 + j;
  const float v = (k < K && col < NC) ? src[k * NC + col] : 0.0f;
  out[t] = f2b(v);
}

// ---------------- pack embedding weights 64x128, 16 blocks -------------------
__global__ void pack_emb_weights(const float* __restrict__ W,
                                 unsigned short* __restrict__ out)
{
  int t = blockIdx.x * 256 + threadIdx.x;  // 0..8191
  if (t >= 8192) return;
  const int j = t & 7, lane = (t >> 3) & 63, blk = t >> 9;
  const int ct = blk & 3, kc = blk >> 2;
  const int col = ct * 32 + (lane & 31);
  const int k = kc * 16 + (lane >> 5) * 8 + j;
  out[t] = f2b(W[k * 128 + col]);
}

// ---------------- stage-A via bf16 MFMA --------------------------------------
// 96 rows/block, 192 threads (3 waves), one barrier.

#define FEAT_TRANS(BASEBLK, V0, V1) do {                                        \
    _Pragma("unroll")                                                           \
    for (int ct_ = 0; ct_ < 2; ++ct_) {                                         \
      const int colh_ = ct_*32 + cl;                                            \
      const int kc2_  = colh_ >> 4;                                             \
      const int b3_   = (colh_ >> 3) & 1;                                       \
      const int jj_   = colh_ & 7;                                              \
      const int blk_  = ((BASEBLK) + kc2_*3 + wave)*512;                        \
      _Pragma("unroll")                                                         \
      for (int q_ = 0; q_ < 16; ++q_) {                                         \
        const int row32_ = (q_ & 3) + 8*(q_ >> 2) + 4*(lane >> 5);              \
        const int s2_ = (row32_ & 31) + 32*b3_;                                 \
        const float v_ = ct_ ? (V1)[q_] : (V0)[q_];                             \
        afrag[blk_ + swz(s2_, kc2_)*8 + jj_] = f2b(fast_tanh(v_));              \
      }                                                                         \
    }                                                                           \
  } while (0)

template<int HAS_SR>
__launch_bounds__(192)
__global__ void feat_mfma(
    int nrows,
    const int* __restrict__ types, const float* __restrict__ lens,
    const float* __restrict__ vecs, const int* __restrict__ idx,
    const float* __restrict__ bessel_w,
    const unsigned short* __restrict__ wpackf,
    const float* __restrict__ srb1, const float* __restrict__ srb2,
    const float* __restrict__ srb3,
    const float* __restrict__ rdb1, const float* __restrict__ rdb2,
    const float* __restrict__ rdb3,
    const float* __restrict__ eln_g, const float* __restrict__ eln_b,
    float* __restrict__ radial_out, float* __restrict__ ud_out,
    float* __restrict__ msgbuf)
{
  __shared__ __align__(16) unsigned short afrag[30*512];  // 30KB
  __shared__ __align__(16) unsigned short wlds[36*512];   // 36KB
  __shared__ float udl[96];

  const int tid  = threadIdx.x;    // 0..191
  const int lane = tid & 63;
  const int wave = tid >> 6;
  const int base = blockIdx.x * 96;
  const int cl   = lane & 31;

  for (int i = tid; i < 2304; i += 192)
    *(u16x8*)&wlds[i*8] = *(const u16x8*)&wpackf[i*8];

  {
    const int r = tid >> 1, h = tid & 1;
    int rowc = base + r;
    const bool valid = rowc < nrows;
    if (!valid) rowc = nrows - 1;
    const int i0 = idx[rowc];
    const int i1 = idx[nrows + rowc];
    const float len = lens[rowc];
    const float ud = poly_cutoff(len);
    const int t0 = types[i0], t1 = types[i1];
    const float invl = 1.0f / len;
    const int rt = r >> 5;
    #pragma unroll
    for (int m = 0; m < 12; ++m) {
      const int k = h + m*2;
      float v;
      if (k < 4)      v = (t0 == k) ? 1.0f : 0.0f;
      else if (k < 8) v = (t1 == (k-4)) ? 1.0f : 0.0f;
      else            v = ud * BESSEL_PREF * __sinf(bessel_w[k-8] * len * RC_INV) * invl;
      const int kc = k >> 4;
      const int s_ = (r & 31) + 32*((k >> 3) & 1);
      afrag[(kc*3 + rt)*512 + swz(s_, kc)*8 + (k & 7)] = f2b(v);
    }
    #pragma unroll
    for (int m = 0; m < 4; ++m) {
      const int k = 24 + h + m*2;
      const int s_ = (r & 31) + 32*((k >> 3) & 1);
      afrag[(1*3 + rt)*512 + swz(s_, 1)*8 + (k & 7)] = 0;
    }
    if (h == 0) {
      udl[r] = ud;
      if (valid) {
        ud_out[rowc] = ud;
        if (HAS_SR) {
          msgbuf[(size_t)rowc*20 + 16] = ud * vecs[(size_t)rowc*3 + 0];
          msgbuf[(size_t)rowc*20 + 17] = ud * vecs[(size_t)rowc*3 + 1];
          msgbuf[(size_t)rowc*20 + 18] = ud * vecs[(size_t)rowc*3 + 2];
        }
      }
    }
  }
  __syncthreads();

  f32x16 acc0, acc1;

  // ======== rd path ========
  {
    const float bv0 = rdb1[cl], bv1 = rdb1[32 + cl];
    #pragma unroll
    for (int q = 0; q < 16; ++q) { acc0[q] = bv0; acc1[q] = bv1; }
  }
  #pragma unroll
  for (int kc = 0; kc < 2; ++kc) {
    const short8 a  = *(const short8*)&afrag[(kc*3 + wave)*512 + swz(lane, kc)*8];
    const short8 w0 = *(const short8*)&wlds[(kc*2 + 0)*512 + lane*8];
    const short8 w1 = *(const short8*)&wlds[(kc*2 + 1)*512 + lane*8];
    acc0 = __builtin_amdgcn_mfma_f32_32x32x16_bf16(a, w0, acc0, 0, 0, 0);
    acc1 = __builtin_amdgcn_mfma_f32_32x32x16_bf16(a, w1, acc1, 0, 0, 0);
  }
  FEAT_TRANS(6, acc0, acc1);

  {
    const float bv0 = rdb2[cl], bv1 = rdb2[32 + cl];
    #pragma unroll
    for (int q = 0; q < 16; ++q) { acc0[q] = bv0; acc1[q] = bv1; }
  }
  #pragma unroll
  for (int kc = 0; kc < 4; ++kc) {
    const short8 a  = *(const short8*)&afrag[((6 + kc*3) + wave)*512 + swz(lane, kc)*8];
    const short8 w0 = *(const short8*)&wlds[(4 + kc*2 + 0)*512 + lane*8];
    const short8 w1 = *(const short8*)&wlds[(4 + kc*2 + 1)*512 + lane*8];
    acc0 = __builtin_amdgcn_mfma_f32_32x32x16_bf16(a, w0, acc0, 0, 0, 0);
    acc1 = __builtin_amdgcn_mfma_f32_32x32x16_bf16(a, w1, acc1, 0, 0, 0);
  }
  FEAT_TRANS(18, acc0, acc1);

  {
    const float bv0 = rdb3[cl], bv1 = rdb3[32 + cl];
    #pragma unroll
    for (int q = 0; q < 16; ++q) { acc0[q] = bv0; acc1[q] = bv1; }
  }
  #pragma unroll
  for (int kc = 0; kc < 4; ++kc) {
    const short8 a  = *(const short8*)&afrag[((18 + kc*3) + wave)*512 + swz(lane, kc)*8];
    const short8 w0 = *(const short8*)&wlds[(12 + kc*2 + 0)*512 + lane*8];
    const short8 w1 = *(const short8*)&wlds[(12 + kc*2 + 1)*512 + lane*8];
    acc0 = __builtin_amdgcn_mfma_f32_32x32x16_bf16(a, w0, acc0, 0, 0, 0);
    acc1 = __builtin_amdgcn_mfma_f32_32x32x16_bf16(a, w1, acc1, 0, 0, 0);
  }
  {
    const float eg0 = eln_g[cl],      eb0 = eln_b[cl];
    const float eg1 = eln_g[32 + cl], eb1 = eln_b[32 + cl];
    #pragma unroll
    for (int q = 0; q < 16; ++q) {
      const float v0 = acc0[q], v1 = acc1[q];
      float s = v0 + v1, ss = v0*v0 + v1*v1;
      #pragma unroll
      for (int o = 1; o <= 16; o <<= 1) {
        s  += __shfl_xor(s, o);
        ss += __shfl_xor(ss, o);
      }
      const float m   = s * (1.0f/64.0f);
      const float inv = rsqrtf(ss * (1.0f/64.0f) - m*m + LN_EPS);
      const int row32 = (q & 3) + 8*(q >> 2) + 4*(lane >> 5);
      const int rloc  = wave*32 + row32;
      const int row   = base + rloc;
      if (row < nrows) {
        const float u = udl[rloc];
        radial_out[(size_t)row*64 + cl]      = ((v0 - m)*inv*eg0 + eb0) * u;
        radial_out[(size_t)row*64 + 32 + cl] = ((v1 - m)*inv*eg1 + eb1) * u;
      }
    }
  }

  // ======== sr path ========
  if (HAS_SR) {
    {
      const float bv0 = srb1[cl], bv1 = srb1[32 + cl];
      #pragma unroll
      for (int q = 0; q < 16; ++q) { acc0[q] = bv0; acc1[q] = bv1; }
    }
    #pragma unroll
    for (int kc = 0; kc < 2; ++kc) {
      const short8 a  = *(const short8*)&afrag[(kc*3 + wave)*512 + swz(lane, kc)*8];
      const short8 w0 = *(const short8*)&wlds[(20 + kc*2 + 0)*512 + lane*8];
      const short8 w1 = *(const short8*)&wlds[(20 + kc*2 + 1)*512 + lane*8];
      acc0 = __builtin_amdgcn_mfma_f32_32x32x16_bf16(a, w0, acc0, 0, 0, 0);
      acc1 = __builtin_amdgcn_mfma_f32_32x32x16_bf16(a, w1, acc1, 0, 0, 0);
    }
    FEAT_TRANS(6, acc0, acc1);

    {
      const float bv0 = srb2[cl], bv1 = srb2[32 + cl];
      #pragma unroll
      for (int q = 0; q < 16; ++q) { acc0[q] = bv0; acc1[q] = bv1; }
    }
    #pragma unroll
    for (int kc = 0; kc < 4; ++kc) {
      const short8 a  = *(const short8*)&afrag[((6 + kc*3) + wave)*512 + swz(lane, kc)*8];
      const short8 w0 = *(const short8*)&wlds[(24 + kc*2 + 0)*512 + lane*8];
      const short8 w1 = *(const short8*)&wlds[(24 + kc*2 + 1)*512 + lane*8];
      acc0 = __builtin_amdgcn_mfma_f32_32x32x16_bf16(a, w0, acc0, 0, 0, 0);
      acc1 = __builtin_amdgcn_mfma_f32_32x32x16_bf16(a, w1, acc1, 0, 0, 0);
    }
    FEAT_TRANS(18, acc0, acc1);

    {
      const float bv0 = (cl < 16) ? srb3[cl] : 0.0f;
      #pragma unroll
      for (int q = 0; q < 16; ++q) acc0[q] = bv0;
    }
    #pragma unroll
    for (int kc = 0; kc < 4; ++kc) {
      const short8 a  = *(const short8*)&afrag[((18 + kc*3) + wave)*512 + swz(lane, kc)*8];
      const short8 w0 = *(const short8*)&wlds[(32 + kc)*512 + lane*8];
      acc0 = __builtin_amdgcn_mfma_f32_32x32x16_bf16(a, w0, acc0, 0, 0, 0);
    }
    if (cl < 16) {
      #pragma unroll
      for (int q = 0; q < 16; ++q) {
        const int row32 = (q & 3) + 8*(q >> 2) + 4*(lane >> 5);
        const int rloc  = wave*32 + row32;
        const int row   = base + rloc;
        if (row < nrows) msgbuf[(size_t)row*20 + cl] = acc0[q] * udl[rloc];
      }
    }
  }
}

// ---------------- SE(2) message gather: aggS (no atomics) --------------------

__launch_bounds__(256)
__global__ void msg_gather_kernel(int N, const int* __restrict__ eoff,
                                  const int* __restrict__ perm,
                                  const float* __restrict__ msgbuf,
                                  float* __restrict__ aggS)
{
  const int w = (blockIdx.x * 256 + threadIdx.x) >> 6;
  const int lane = threadIdx.x & 63;
  if (w >= N) return;
  const int s = eoff[w], e = eoff[w + 1];
  const int d = lane / 3, c = lane - d * 3;
  float acc = 0.0f;
  for (int j = s; j < e; ++j) {
    const int ed = perm[j];
    if (lane < 48)
      acc += msgbuf[(size_t)ed*20 + d] * msgbuf[(size_t)ed*20 + 16 + c];
  }
  if (lane < 48) aggS[(size_t)w*48 + lane] = acc;
}

// ---------------- node embedding (gram + LN) ---------------------------------

__device__ __forceinline__ void block128_stats(float x, float& m, float& inv, float* red) {
  float s = x, ss = x*x;
  #pragma unroll
  for (int o = 32; o; o >>= 1) { s += __shfl_down(s, o); ss += __shfl_down(ss, o); }
  const int t = threadIdx.x;
  if ((t & 63) == 0) { red[(t >> 6)*2] = s; red[(t >> 6)*2 + 1] = ss; }
  __syncthreads();
  const float S = red[0] + red[2], SS = red[1] + red[3];
  m = S * (1.0f/128.0f);
  const float var = SS * (1.0f/128.0f) - m*m;
  inv = rsqrtf(var + LN_EPS);
}

__launch_bounds__(128)
__global__ void node_emb_kernel(int N, const float* __restrict__ aggS,
                                const int* __restrict__ ecnt,
                                const float* __restrict__ g, const float* __restrict__ b,
                                float* __restrict__ node_emb)
{
  const int n = blockIdx.x, t = threadIdx.x;
  __shared__ float S[48];
  __shared__ float red[4];
  if (t < 48) S[t] = aggS[(size_t)n*48 + t];
  __syncthreads();
  const float ic = 1.0f / fmaxf((float)ecnt[n], 1.0f);
  const int d = t >> 3, e = t & 7;
  const float x = (S[d*3+0]*S[e*3+0] + S[d*3+1]*S[e*3+1] + S[d*3+2]*S[e*3+2]) * ic * ic;
  float m, inv;
  block128_stats(x, m, inv, red);
  node_emb[(size_t)n*128 + t] = (x - m)*inv*g[t] + b[t];
}

// ---------------- per-layer aggregation: CSR gather (no atomics) -------------

__launch_bounds__(256)
__global__ void agg_gather_kernel(int N, const int* __restrict__ eoff,
                                  const int* __restrict__ perm,
                                  const float* __restrict__ radial,
                                  float* __restrict__ mean_r)
{
  const int w = (blockIdx.x * 256 + threadIdx.x) >> 6;
  const int lane = threadIdx.x & 63;
  if (w >= N) return;
  const int s = eoff[w], e = eoff[w + 1];
  float acc = 0.0f;
  for (int j = s; j < e; ++j) {
    const int ed = perm[j];
    acc += radial[(size_t)ed * 64 + lane];
  }
  const float inv = 1.0f / fmaxf((float)(e - s), 1.0f);
  mean_r[(size_t)w * 64 + lane] = acc * inv;
}

// ---------------- node update: (mean_r @ W + b) * old, LN, residual ----------

__launch_bounds__(256)
__global__ void node_update_gemm(
    int N, const float* __restrict__ mean_r, const int* __restrict__ ecnt,
    const float* __restrict__ W, const float* __restrict__ bias,
    const float* __restrict__ g, const float* __restrict__ b,
    float* __restrict__ node_emb)
{
  __shared__ __align__(16) float lw[64*128];
  __shared__ float lm[32][65];
  const int tid = threadIdx.x;
  const int base = blockIdx.x * 32;

  for (int i = tid; i < 8192; i += 256) lw[i] = W[i];
  {
    const int rr0 = tid >> 6, k = tid & 63;
    for (int rr = rr0; rr < 32; rr += 4) {
      const int n = base + rr;
      lm[rr][k] = (n < N) ? mean_r[(size_t)n*64 + k] : 0.0f;
    }
  }
  __syncthreads();

  const int r0 = (tid >> 5) * 4, j0 = (tid & 31) * 4;
  float acc[4][4];
  #pragma unroll
  for (int j = 0; j < 4; ++j) {
    const float bj = bias[j0 + j];
    acc[0][j] = bj; acc[1][j] = bj; acc[2][j] = bj; acc[3][j] = bj;
  }
  for (int k = 0; k < 64; ++k) {
    const float4 w = *(const float4*)&lw[k*128 + j0];
    const float s0 = lm[r0][k],   s1 = lm[r0+1][k];
    const float s2 = lm[r0+2][k], s3 = lm[r0+3][k];
    acc[0][0] += s0*w.x; acc[0][1] += s0*w.y; acc[0][2] += s0*w.z; acc[0][3] += s0*w.w;
    acc[1][0] += s1*w.x; acc[1][1] += s1*w.y; acc[1][2] += s1*w.z; acc[1][3] += s1*w.w;
    acc[2][0] += s2*w.x; acc[2][1] += s2*w.y; acc[2][2] += s2*w.z; acc[2][3] += s2*w.w;
    acc[3][0] += s3*w.x; acc[3][1] += s3*w.y; acc[3][2] += s3*w.z; acc[3][3] += s3*w.w;
  }

  const float g0 = g[j0], g1 = g[j0+1], g2 = g[j0+2], g3 = g[j0+3];
  const float bb0 = b[j0], bb1 = b[j0+1], bb2 = b[j0+2], bb3 = b[j0+3];
  #pragma unroll
  for (int i = 0; i < 4; ++i) {
    const int n = base + r0 + i;
    if (n >= N) continue;
    const float mask = (ecnt[n] > 0) ? 1.0f : 0.0f;
    const float4 old = *(const float4*)&node_emb[(size_t)n*128 + j0];
    const float x0 = old.x * acc[i][0] * mask;
    const float x1 = old.y * acc[i][1] * mask;
    const float x2 = old.z * acc[i][2] * mask;
    const float x3 = old.w * acc[i][3] * mask;
    float s = x0 + x1 + x2 + x3;
    float ss = x0*x0 + x1*x1 + x2*x2 + x3*x3;
    #pragma unroll
    for (int o = 1; o <= 16; o <<= 1) {
      s  += __shfl_xor(s, o);
      ss += __shfl_xor(ss, o);
    }
    const float m = s * (1.0f/128.0f);
    const float inv = rsqrtf(ss * (1.0f/128.0f) - m*m + LN_EPS);
    float4 o4;
    o4.x = C_RES*old.x + C_NEW*((x0 - m)*inv*g0 + bb0);
    o4.y = C_RES*old.y + C_NEW*((x1 - m)*inv*g1 + bb1);
    o4.z = C_RES*old.z + C_NEW*((x2 - m)*inv*g2 + bb2);
    o4.w = C_RES*old.w + C_NEW*((x3 - m)*inv*g3 + bb3);
    *(float4*)&node_emb[(size_t)n*128 + j0] = o4;
  }
}

// ---------------- embedding GEMM via MFMA ------------------------------------
// 96 rows/block, 192 threads (3 waves). radial K=64 -> 128 cols, epilogue
// multiplies by 0.5*(ne[i0]+ne[i1]) with coalesced half-wave loads.

__launch_bounds__(192)
__global__ void emb_mfma(
    int nrows,
    const float* __restrict__ radial,
    const unsigned short* __restrict__ wpck, const float* __restrict__ bias,
    const int* __restrict__ idx,
    const float* __restrict__ node_emb,
    float* __restrict__ out)
{
  __shared__ __align__(16) unsigned short afrag[12*512];  // 12KB
  __shared__ __align__(16) unsigned short wlds[16*512];   // 16KB
  __shared__ int i0l[96], i1l[96];

  const int tid = threadIdx.x, lane = tid & 63, wave = tid >> 6;
  const int base = blockIdx.x * 96, cl = lane & 31;

  for (int i = tid; i < 1024; i += 192)
    *(u16x8*)&wlds[i*8] = *(const u16x8*)&wpck[i*8];

  {
    const int r = tid >> 1, h = tid & 1;
    int rowg = base + r;
    if (rowg >= nrows) rowg = nrows - 1;
    if (h == 0) { i0l[r] = idx[rowg]; i1l[r] = idx[nrows + rowg]; }
    const float* rsrc = radial + (size_t)rowg * 64;
    #pragma unroll
    for (int g = 0; g < 4; ++g) {
      const int k = h*32 + g*8;
      const float4 v0 = *(const float4*)(rsrc + k);
      const float4 v1 = *(const float4*)(rsrc + k + 4);
      u16x8 w;
      w[0]=f2b(v0.x); w[1]=f2b(v0.y); w[2]=f2b(v0.z); w[3]=f2b(v0.w);
      w[4]=f2b(v1.x); w[5]=f2b(v1.y); w[6]=f2b(v1.z); w[7]=f2b(v1.w);
      const int kc = k >> 4;
      const int s_ = (r & 31) + 32*((k >> 3) & 1);
      *(u16x8*)&afrag[(kc*3 + (r>>5))*512 + swz(s_, kc)*8] = w;
    }
  }
  __syncthreads();

  f32x16 acc0, acc1, acc2, acc3;
  {
    const float bv0 = bias[cl], bv1 = bias[32+cl];
    const float bv2 = bias[64+cl], bv3 = bias[96+cl];
    #pragma unroll
    for (int q = 0; q < 16; ++q) { acc0[q]=bv0; acc1[q]=bv1; acc2[q]=bv2; acc3[q]=bv3; }
  }
  #pragma unroll
  for (int kc = 0; kc < 4; ++kc) {
    const short8 a  = *(const short8*)&afrag[(kc*3 + wave)*512 + swz(lane, kc)*8];
    const short8 w0 = *(const short8*)&wlds[(kc*4 + 0)*512 + lane*8];
    const short8 w1 = *(const short8*)&wlds[(kc*4 + 1)*512 + lane*8];
    const short8 w2 = *(const short8*)&wlds[(kc*4 + 2)*512 + lane*8];
    const short8 w3 = *(const short8*)&wlds[(kc*4 + 3)*512 + lane*8];
    acc0 = __builtin_amdgcn_mfma_f32_32x32x16_bf16(a, w0, acc0, 0, 0, 0);
    acc1 = __builtin_amdgcn_mfma_f32_32x32x16_bf16(a, w1, acc1, 0, 0, 0);
    acc2 = __builtin_amdgcn_mfma_f32_32x32x16_bf16(a, w2, acc2, 0, 0, 0);
    acc3 = __builtin_amdgcn_mfma_f32_32x32x16_bf16(a, w3, acc3, 0, 0, 0);
  }

  #pragma unroll
  for (int q = 0; q < 16; ++q) {
    const int row32 = (q & 3) + 8*(q >> 2) + 4*(lane >> 5);
    const int rloc  = wave*32 + row32;
    const int row   = base + rloc;
    if (row >= nrows) continue;
    const float* n0 = node_emb + (size_t)i0l[rloc]*128;
    const float* n1 = node_emb + (size_t)i1l[rloc]*128;
    float* op = out + (size_t)row*128;
    op[cl]    = acc0[q] * 0.5f * (n0[cl]    + n1[cl]);
    op[32+cl] = acc1[q] * 0.5f * (n0[32+cl] + n1[32+cl]);
    op[64+cl] = acc2[q] * 0.5f * (n0[64+cl] + n1[64+cl]);
    op[96+cl] = acc3[q] * 0.5f * (n0[96+cl] + n1[96+cl]);
  }
}

// ---------------- hidden MLP via bf16 MFMA (4 waves, 1 row-tile each) --------

__launch_bounds__(256)
__global__ void hid_mlp_mfma(
    int nrows, const int* __restrict__ idx0,
    const float* __restrict__ node_emb,
    const unsigned short* __restrict__ wpack,   // 65536 ushorts for this layer
    const float* __restrict__ b1, const float* __restrict__ b2,
    const float* __restrict__ b3,
    float* __restrict__ hidden)
{
  __shared__ __align__(16) unsigned short h_afrag[16384];  // 32KB: [rt4][kc8]*512
  __shared__ __align__(16) unsigned short xg[4096];        // 8KB:  [rt4][kcl2]*512
  __shared__ __align__(16) unsigned short wg[4096];        // 8KB:  [kcl2][ct4]*512

  const int tid  = threadIdx.x;
  const int lane = tid & 63;
  const int wave = tid >> 6;       // rt 0..3
  const int base = blockIdx.x * 128;

  const int r = tid >> 1;          // staging row 0..127
  const int h = tid & 1;
  int rowg = base + r;
  if (rowg >= nrows) rowg = nrows - 1;
  const int i0 = idx0[rowg];
  const float* xsrc0 = node_emb + (size_t)i0 * 128;
  const float* xsrc1 = hidden + (size_t)rowg * 128;

  f32x16 acc[4];

  // ---------- layer 1: K=256, 8 phases x (2 kc) ----------
  #pragma unroll
  for (int ct = 0; ct < 4; ++ct) {
    const float bv = b1[ct*32 + (lane & 31)];
    #pragma unroll
    for (int q = 0; q < 16; ++q) acc[ct][q] = bv;
  }
  for (int p = 0; p < 8; ++p) {
    __syncthreads();
    #pragma unroll
    for (int oo = 0; oo < 2; ++oo) {
      const int o = h*2 + oo;
      const int k = p*32 + o*8;
      const float* s = (k < 128) ? (xsrc0 + k) : (xsrc1 + (k - 128));
      const float4 v0 = *(const float4*)s;
      const float4 v1 = *(const float4*)(s + 4);
      u16x8 w;
      w[0]=f2b(v0.x); w[1]=f2b(v0.y); w[2]=f2b(v0.z); w[3]=f2b(v0.w);
      w[4]=f2b(v1.x); w[5]=f2b(v1.y); w[6]=f2b(v1.z); w[7]=f2b(v1.w);
      const int kc = p*2 + (o >> 1);
      const int s_ = (r & 31) + 32*(o & 1);
      *(u16x8*)&xg[ ((r>>5)*2 + (o>>1))*512 + swz(s_, kc)*8 ] = w;
    }
    #pragma unroll
    for (int i = 0; i < 2; ++i) {
      const int c = tid + i*256;
      *(u16x8*)&wg[c*8] = *(const u16x8*)&wpack[p*4096 + c*8];
    }
    __syncthreads();
    #pragma unroll
    for (int kcl = 0; kcl < 2; ++kcl) {
      const int kc = p*2 + kcl;
      const short8 a = *(const short8*)&xg[ (wave*2 + kcl)*512 + swz(lane, kc)*8 ];
      #pragma unroll
      for (int ct = 0; ct < 4; ++ct) {
        const short8 b = *(const short8*)&wg[ (kcl*4 + ct)*512 + lane*8 ];
        acc[ct] = __builtin_amdgcn_mfma_f32_32x32x16_bf16(a, b, acc[ct], 0, 0, 0);
      }
    }
  }

  // ---------- transition 1: tanh -> h_afrag ----------
  __syncthreads();
  {
    const int rt = wave;
    #pragma unroll
    for (int ct = 0; ct < 4; ++ct) {
      const int kc  = ct*2 + ((lane >> 4) & 1);
      const int oct = (lane >> 3) & 1;
      const int j   = lane & 7;
      const int xk  = (oct << 1) ^ ((kc & 1) << 2);
      const int hi  = 4*(lane >> 5);
      const int bi  = (rt*8 + kc)*512 + oct*256 + j;
      #pragma unroll
      for (int q = 0; q < 16; ++q) {
        const int m32 = (q & 3) + 8*(q >> 2) + hi;
        h_afrag[bi + (m32 ^ xk)*8] = f2b(fast_tanh(acc[ct][q]));
      }
    }
  }
  #pragma unroll
  for (int ct = 0; ct < 4; ++ct) {
    const float bv = b2[ct*32 + (lane & 31)];
    #pragma unroll
    for (int q = 0; q < 16; ++q) acc[ct][q] = bv;
  }
  __syncthreads();

  // ---------- layer 2: K=128, 4 phases x (2 kc) ----------
  for (int p = 0; p < 4; ++p) {
    __syncthreads();
    #pragma unroll
    for (int i = 0; i < 2; ++i) {
      const int c = tid + i*256;
      *(u16x8*)&wg[c*8] = *(const u16x8*)&wpack[32768 + p*4096 + c*8];
    }
    __syncthreads();
    #pragma unroll
    for (int kcl = 0; kcl < 2; ++kcl) {
      const int kc = p*2 + kcl;
      const short8 a = *(const short8*)&h_afrag[ (wave*8 + kc)*512 + swz(lane, kc)*8 ];
      #pragma unroll
      for (int ct = 0; ct < 4; ++ct) {
        const short8 b = *(const short8*)&wg[ (kcl*4 + ct)*512 + lane*8 ];
        acc[ct] = __builtin_amdgcn_mfma_f32_32x32x16_bf16(a, b, acc[ct], 0, 0, 0);
      }
    }
  }

  // ---------- transition 2: tanh -> h_afrag (overwrite) ----------
  __syncthreads();
  {
    const int rt = wave;
    #pragma unroll
    for (int ct = 0; ct < 4; ++ct) {
      const int kc  = ct*2 + ((lane >> 4) & 1);
      const int oct = (lane >> 3) & 1;
      const int j   = lane & 7;
      const int xk  = (oct << 1) ^ ((kc & 1) << 2);
      const int hi  = 4*(lane >> 5);
      const int bi  = (rt*8 + kc)*512 + oct*256 + j;
      #pragma unroll
      for (int q = 0; q < 16; ++q) {
        const int m32 = (q & 3) + 8*(q >> 2) + hi;
        h_afrag[bi + (m32 ^ xk)*8] = f2b(fast_tanh(acc[ct][q]));
      }
    }
  }
  #pragma unroll
  for (int ct = 0; ct < 4; ++ct) {
    const float bv = b3[ct*32 + (lane & 31)];
    #pragma unroll
    for (int q = 0; q < 16; ++q) acc[ct][q] = bv;
  }
  __syncthreads();

  // ---------- layer 3: K=128 ----------
  for (int p = 0; p < 4; ++p) {
    __syncthreads();
    #pragma unroll
    for (int i = 0; i < 2; ++i) {
      const int c = tid + i*256;
      *(u16x8*)&wg[c*8] = *(const u16x8*)&wpack[49152 + p*4096 + c*8];
    }
    __syncthreads();
    #pragma unroll
    for (int kcl = 0; kcl < 2; ++kcl) {
      const int kc = p*2 + kcl;
      const short8 a = *(const short8*)&h_afrag[ (wave*8 + kc)*512 + swz(lane, kc)*8 ];
      #pragma unroll
      for (int ct = 0; ct < 4; ++ct) {
        const short8 b = *(const short8*)&wg[ (kcl*4 + ct)*512 + lane*8 ];
        acc[ct] = __builtin_amdgcn_mfma_f32_32x32x16_bf16(a, b, acc[ct], 0, 0, 0);
      }
    }
  }

  // ---------- epilogue: store f32 ----------
  #pragma unroll
  for (int ct = 0; ct < 4; ++ct) {
    const int col = ct*32 + (lane & 31);
    #pragma unroll
    for (int q = 0; q < 16; ++q) {
      const int row = base + wave*32 + (q & 3) + 8*(q >> 2) + 4*(lane >> 5);
      if (row < nrows) hidden[(size_t)row*128 + col] = acc[ct][q];
    }
  }
}

// ---------------- radial ResNet via bf16 MFMA --------------------------------

__launch_bounds__(192)
__global__ void rdl_mfma(
    int nrows,
    const float* __restrict__ hidden, const float* __restrict__ ud,
    const unsigned short* __restrict__ wpack,   // 20480 ushorts this layer
    const float* __restrict__ b1, const float* __restrict__ b2,
    const float* __restrict__ b3,
    const float* __restrict__ eln_g, const float* __restrict__ eln_b,
    float* __restrict__ radial)
{
  __shared__ __align__(16) unsigned short afrag[36*512];  // 36KB
  __shared__ __align__(16) unsigned short wlds[40*512];   // 40KB
  __shared__ float udl[96];

  const int tid  = threadIdx.x;    // 0..191
  const int lane = tid & 63;
  const int wave = tid >> 6;       // rt
  const int base = blockIdx.x * 96;
  const int cl   = lane & 31;

  for (int i = tid; i < 2560; i += 192) {
    *(u16x8*)&wlds[i*8] = *(const u16x8*)&wpack[i*8];
  }
  {
    const int r  = tid >> 1;       // 0..95
    const int kh = tid & 1;
    int rowg = base + r;
    if (rowg >= nrows) rowg = nrows - 1;
    const float* rsrc = radial + (size_t)rowg * 64;
    const float* hsrc = hidden + (size_t)rowg * 128;
    if (kh == 0) udl[r] = ud[rowg];
    #pragma unroll
    for (int g = 0; g < 12; ++g) {
      const int k = kh*96 + g*8;
      const float* s = (k < 64) ? (rsrc + k) : (hsrc + (k - 64));
      const float4 v0 = *(const float4*)s;
      const float4 v1 = *(const float4*)(s + 4);
      u16x8 w;
      w[0]=f2b(v0.x); w[1]=f2b(v0.y); w[2]=f2b(v0.z); w[3]=f2b(v0.w);
      w[4]=f2b(v1.x); w[5]=f2b(v1.y); w[6]=f2b(v1.z); w[7]=f2b(v1.w);
      const int kc = k >> 4;
      const int s_ = (r & 31) + 32*((k >> 3) & 1);
      *(u16x8*)&afrag[(kc*3 + (r>>5))*512 + swz(s_, kc)*8] = w;
    }
  }
  __syncthreads();   // the only block-wide barrier

  f32x16 acc0, acc1;
  {
    const float bv0 = b1[cl], bv1 = b1[32 + cl];
    #pragma unroll
    for (int q = 0; q < 16; ++q) { acc0[q] = bv0; acc1[q] = bv1; }
  }
  #pragma unroll
  for (int kc = 0; kc < 12; ++kc) {
    const short8 a  = *(const short8*)&afrag[(kc*3 + wave)*512 + swz(lane, kc)*8];
    const short8 w0 = *(const short8*)&wlds[(kc*2 + 0)*512 + lane*8];
    const short8 w1 = *(const short8*)&wlds[(kc*2 + 1)*512 + lane*8];
    acc0 = __builtin_amdgcn_mfma_f32_32x32x16_bf16(a, w0, acc0, 0, 0, 0);
    acc1 = __builtin_amdgcn_mfma_f32_32x32x16_bf16(a, w1, acc1, 0, 0, 0);
  }

  #pragma unroll
  for (int ct = 0; ct < 2; ++ct) {
    const int colh = ct*32 + cl;
    const int kc2  = colh >> 4;
    const int b3_  = (colh >> 3) & 1;
    const int jj   = colh & 7;
    const int blk  = ((4 + kc2)*3 + wave)*512;
    #pragma unroll
    for (int q = 0; q < 16; ++q) {
      const int row32 = (q & 3) + 8*(q >> 2) + 4*(lane >> 5);
      const int s_ = (row32 & 31) + 32*b3_;
      const float v = ct ? acc1[q] : acc0[q];
      afrag[blk + swz(s_, kc2)*8 + jj] = f2b(fast_tanh(v));
    }
  }

  f32x16 h0, h1;
  {
    const float bv0 = b2[cl], bv1 = b2[32 + cl];
    #pragma unroll
    for (int q = 0; q < 16; ++q) { h0[q] = bv0; h1[q] = bv1; }
  }
  #pragma unroll
  for (int kc = 0; kc < 4; ++kc) {
    const short8 a  = *(const short8*)&afrag[((4 + kc)*3 + wave)*512 + swz(lane, kc)*8];
    const short8 w0 = *(const short8*)&wlds[(24 + kc*2 + 0)*512 + lane*8];
    const short8 w1 = *(const short8*)&wlds[(24 + kc*2 + 1)*512 + lane*8];
    h0 = __builtin_amdgcn_mfma_f32_32x32x16_bf16(a, w0, h0, 0, 0, 0);
    h1 = __builtin_amdgcn_mfma_f32_32x32x16_bf16(a, w1, h1, 0, 0, 0);
  }

  #pragma unroll
  for (int ct = 0; ct < 2; ++ct) {
    const int colh = ct*32 + cl;
    const int kc2  = colh >> 4;
    const int b3_  = (colh >> 3) & 1;
    const int jj   = colh & 7;
    const int blk  = ((8 + kc2)*3 + wave)*512;
    #pragma unroll
    for (int q = 0; q < 16; ++q) {
      const int row32 = (q & 3) + 8*(q >> 2) + 4*(lane >> 5);
      const int s_ = (row32 & 31) + 32*b3_;
      const float v = ct ? h1[q] : h0[q];
      afrag[blk + swz(s_, kc2)*8 + jj] = f2b(fast_tanh(v));
    }
  }

  {
    const float bv0 = b3[cl], bv1 = b3[32 + cl];
    #pragma unroll
    for (int q = 0; q < 16; ++q) { acc0[q] = bv0; acc1[q] = bv1; }
  }
  #pragma unroll
  for (int kc = 0; kc < 4; ++kc) {
    const short8 a  = *(const short8*)&afrag[((8 + kc)*3 + wave)*512 + swz(lane, kc)*8];
    const short8 w0 = *(const short8*)&wlds[(32 + kc*2 + 0)*512 + lane*8];
    const short8 w1 = *(const short8*)&wlds[(32 + kc*2 + 1)*512 + lane*8];
    acc0 = __builtin_amdgcn_mfma_f32_32x32x16_bf16(a, w0, acc0, 0, 0, 0);
    acc1 = __builtin_amdgcn_mfma_f32_32x32x16_bf16(a, w1, acc1, 0, 0, 0);
  }

  const float eg0 = eln_g[cl],      eb0 = eln_b[cl];
  const float eg1 = eln_g[32 + cl], eb1 = eln_b[32 + cl];
  const int kcA = cl >> 4;
  const int kcB = (32 + cl) >> 4;
  const int jA  = cl & 7;
  const int jB  = cl & 7;
  const int bA  = (kcA*3 + wave)*512;
  const int bB  = (kcB*3 + wave)*512;
  const int b3A = (cl >> 3) & 1;
  const int b3B = ((32 + cl) >> 3) & 1;

  #pragma unroll
  for (int q = 0; q < 16; ++q) {
    const float v0 = acc0[q] + h0[q];
    const float v1 = acc1[q] + h1[q];
    float s = v0 + v1, ss = v0*v0 + v1*v1;
    #pragma unroll
    for (int o = 1; o <= 16; o <<= 1) {
      s  += __shfl_xor(s, o);
      ss += __shfl_xor(ss, o);
    }
    const float m   = s * (1.0f/64.0f);
    const float inv = rsqrtf(ss * (1.0f/64.0f) - m*m + LN_EPS);
    const int row32 = (q & 3) + 8*(q >> 2) + 4*(lane >> 5);
    const int rloc  = wave*32 + row32;
    const int row   = base + rloc;
    if (row < nrows) {
      const float u = udl[rloc];
      const int sA = (row32 & 31) + 32*b3A;
      const int sB = (row32 & 31) + 32*b3B;
      const float oldA = __uint_as_float((unsigned)afrag[bA + swz(sA, kcA)*8 + jA] << 16);
      const float oldB = __uint_as_float((unsigned)afrag[bB + swz(sB, kcB)*8 + jB] << 16);
      radial[(size_t)row*64 + cl]      = C_RES*oldA + C_NEW*u*((v0 - m)*inv*eg0 + eb0);
      radial[(size_t)row*64 + 32 + cl] = C_RES*oldB + C_NEW*u*((v1 - m)*inv*eg1 + eb1);
    }
  }
}

// ---------------- launch -----------------------------------------------------

extern "C" void kernel_launch(void* const* d_in, const int* in_sizes, int n_in,
                              void* d_out, int out_size, void* d_ws, size_t ws_size,
                              hipStream_t stream)
{
  const int*   atom_types = (const int*)  d_in[0];
  const float* env_vec    = (const float*)d_in[1];
  const float* env_len    = (const float*)d_in[2];
  const float* edge_len   = (const float*)d_in[3];
  const int*   env_idx    = (const int*)  d_in[4];
  const int*   edge_idx   = (const int*)  d_in[5];
  const float* bessel_w   = (const float*)d_in[6];
  const float* srW1 = (const float*)d_in[7];  const float* srb1 = (const float*)d_in[8];
  const float* srW2 = (const float*)d_in[9];  const float* srb2 = (const float*)d_in[10];
  const float* srW3 = (const float*)d_in[11]; const float* srb3 = (const float*)d_in[12];
  const float* rdW1 = (const float*)d_in[13]; const float* rdb1 = (const float*)d_in[14];
  const float* rdW2 = (const float*)d_in[15]; const float* rdb2 = (const float*)d_in[16];
  const float* rdW3 = (const float*)d_in[17]; const float* rdb3 = (const float*)d_in[18];
  const float* ne_emb_W = (const float*)d_in[19]; const float* ne_emb_b = (const float*)d_in[20];
  const float* ne_nln_g = (const float*)d_in[21]; const float* ne_nln_b = (const float*)d_in[22];
  const float* ne_eln_g = (const float*)d_in[23]; const float* ne_eln_b = (const float*)d_in[24];
  const float* ly_emb_W = (const float*)d_in[25]; const float* ly_emb_b = (const float*)d_in[26];
  const float* ly_hid_W1 = (const float*)d_in[27]; const float* ly_hid_b1 = (const float*)d_in[28];
  const float* ly_hid_W2 = (const float*)d_in[29]; const float* ly_hid_b2 = (const float*)d_in[30];
  const float* ly_hid_W3 = (const float*)d_in[31]; const float* ly_hid_b3 = (const float*)d_in[32];
  const float* ly_rdl_W1 = (const float*)d_in[33]; const float* ly_rdl_b1 = (const float*)d_in[34];
  const float* ly_rdl_W2 = (const float*)d_in[35]; const float* ly_rdl_b2 = (const float*)d_in[36];
  const float* ly_rdl_W3 = (const float*)d_in[37]; const float* ly_rdl_b3 = (const float*)d_in[38];
  const float* ly_nln_g = (const float*)d_in[39]; const float* ly_nln_b = (const float*)d_in[40];
  const float* ly_eln_g = (const float*)d_in[41]; const float* ly_eln_b = (const float*)d_in[42];

  const int N  = in_sizes[0];
  const int E  = in_sizes[2];
  const int E2 = in_sizes[3];

  float* out = (float*)d_out;
  float* env_radial  = out;
  float* edge_radial = env_radial + (size_t)E * 64;
  float* node_emb    = edge_radial + (size_t)E2 * 64;
  float* env_hidden  = node_emb + (size_t)N * 128;
  float* edge_hidden = env_hidden + (size_t)E * 128;

  float* ws = (float*)d_ws;
  float* ud_env  = ws;  ws += E;
  float* ud_edge = ws;  ws += E2;
  float* aggS    = ws;  ws += (size_t)N * 48;
  float* msgbuf  = ws;  ws += (size_t)E * 20;   // sval[16] | evud[3] | pad
  float* mean_r  = msgbuf;                      // reuse after msg_gather
  unsigned short* wpack  = (unsigned short*)ws; ws += 65536;   // hid: 2 x 65536 u16
  unsigned short* wpack2 = (unsigned short*)ws; ws += 20480;   // rdl: 2 x 20480 u16
  unsigned short* wpack3 = (unsigned short*)ws; ws += 9216;    // feat: 18432 u16
  unsigned short* wpackE = (unsigned short*)ws; ws += 4096;    // emb: 8192 u16
  int* ecnt = (int*)ws; ws += N;
  int* eoff = (int*)ws; ws += N + 1;
  int* ecur = (int*)ws; ws += N + 1;
  int* perm = (int*)ws; ws += E;

  const int gEh  = (E  + 127) / 128;
  const int gE2h = (E2 + 127) / 128;
  const int gEr  = (E  + 95) / 96;
  const int gE2r = (E2 + 95) / 96;
  const int gN32 = (N + 31) / 32;
  const int gN4w = (N * 64 + 255) / 256;

  // CSR build over env graph (i1 = env_idx[1])
  zero_int_kernel<<<256, 256, 0, stream>>>(ecnt, N);
  hist_kernel<<<(E + 255) / 256, 256, 0, stream>>>(E, env_idx, ecnt);
  scan_kernel<<<1, 1024, 0, stream>>>(ecnt, eoff, ecur, N);
  scatter_kernel<<<(E + 255) / 256, 256, 0, stream>>>(E, env_idx, ecur, perm);

  pack_hid_weights<<<512, 256, 0, stream>>>(ly_hid_W1, ly_hid_W2, ly_hid_W3, wpack);
  pack_rdl_weights<<<160, 256, 0, stream>>>(ly_rdl_W1, ly_rdl_W2, ly_rdl_W3, wpack2);
  pack_feat_weights<<<72, 256, 0, stream>>>(rdW1, rdW2, rdW3, srW1, srW2, srW3, wpack3);
  pack_emb_weights<<<32, 256, 0, stream>>>(ne_emb_W, wpackE);

  feat_mfma<1><<<gEr, 192, 0, stream>>>(E, atom_types, env_len, env_vec, env_idx, bessel_w,
      wpack3, srb1, srb2, srb3, rdb1, rdb2, rdb3,
      ne_eln_g, ne_eln_b, env_radial, ud_env, msgbuf);
  feat_mfma<0><<<gE2r, 192, 0, stream>>>(E2, atom_types, edge_len, nullptr, edge_idx, bessel_w,
      wpack3, srb1, srb2, srb3, rdb1, rdb2, rdb3,
      ne_eln_g, ne_eln_b, edge_radial, ud_edge, nullptr);

  msg_gather_kernel<<<gN4w, 256, 0, stream>>>(N, eoff, perm, msgbuf, aggS);
  node_emb_kernel<<<N, 128, 0, stream>>>(N, aggS, ecnt, ne_nln_g, ne_nln_b, node_emb);

  emb_mfma<<<gEr, 192, 0, stream>>>(E, env_radial, wpackE, ne_emb_b, env_idx, node_emb, env_hidden);
  emb_mfma<<<gE2r, 192, 0, stream>>>(E2, edge_radial, wpackE, ne_emb_b, edge_idx, node_emb, edge_hidden);

  for (int l = 0; l < 2; ++l) {
    agg_gather_kernel<<<gN4w, 256, 0, stream>>>(N, eoff, perm, env_radial, mean_r);
    node_update_gemm<<<gN32, 256, 0, stream>>>(N, mean_r, ecnt,
        ly_emb_W + (size_t)l*64*128, ly_emb_b + (size_t)l*128,
        ly_nln_g + (size_t)l*128, ly_nln_b + (size_t)l*128, node_emb);

    hid_mlp_mfma<<<gEh, 256, 0, stream>>>(E, env_idx, node_emb,
        wpack + (size_t)l*65536,
        ly_hid_b1 + (size_t)l*128, ly_hid_b2 + (size_t)l*128, ly_hid_b3 + (size_t)l*128,
        env_hidden);
    hid_mlp_mfma<<<gE2h, 256, 0, stream>>>(E2, edge_idx, node_emb,
        wpack + (size_t)l*65536,
        ly_hid_b1 + (size_t)l*128, ly_hid_b2 + (size_t)l*128, ly_hid_b3 + (size_t)l*128,
        edge_hidden);

    rdl_mfma<<<gEr, 192, 0, stream>>>(E, env_hidden, ud_env,
        wpack2 + (size_t)l*20480,
        ly_rdl_b1 + (size_t)l*64, ly_rdl_b2 + (size_t)l*64, ly_rdl_b3 + (size_t)l*64,
        ly_eln_g + (size_t)l*64, ly_eln_b + (size_t)l*64, env_radial);
    rdl_mfma<<<gE2r, 192, 0, stream>>>(E2, edge_hidden, ud_edge,
        wpack2 + (size_t)l*20480,
        ly_rdl_b1 + (size_t)l*64, ly_rdl_b2 + (size_t)l*64, ly_rdl_b3 + (size_t)l*64,
        ly_eln_g + (size_t)l*64, ly_eln_b + (size_t)l*64, edge_radial);
  }
}

// Round 7
// 1324.427 us; speedup vs baseline: 5.7072x; 1.0643x over previous
//
#include <hip/hip_runtime.h>
#include <math.h>

#define C_RES 0.89442719f
#define C_NEW 0.4472f
#define LN_EPS 1e-5f
#define BESSEL_PREF 0.6324555320336759f  // sqrt(2/5)
#define RC_INV 0.2f

typedef __attribute__((ext_vector_type(8))) short short8;
typedef __attribute__((ext_vector_type(8))) unsigned short u16x8;
typedef __attribute__((ext_vector_type(16))) float f32x16;

__device__ __forceinline__ float fast_tanh(float x) {
  float ax = fabsf(x);
  float e = __expf(2.0f * ax);
  float t = 1.0f - 2.0f / (e + 1.0f);
  return copysignf(t, x);
}

__device__ __forceinline__ unsigned short f2b(float f) {
  unsigned int u = __float_as_uint(f);
  unsigned int r = (u + 0x7FFFu + ((u >> 16) & 1u)) >> 16;
  return (unsigned short)r;
}

__device__ __forceinline__ u16x8 cvt8(const float* s) {
  const float4 v0 = *(const float4*)s;
  const float4 v1 = *(const float4*)(s + 4);
  u16x8 w;
  w[0]=f2b(v0.x); w[1]=f2b(v0.y); w[2]=f2b(v0.z); w[3]=f2b(v0.w);
  w[4]=f2b(v1.x); w[5]=f2b(v1.y); w[6]=f2b(v1.z); w[7]=f2b(v1.w);
  return w;
}

__device__ __forceinline__ float poly_cutoff(float x) {
  float xr = x * RC_INV;
  if (xr >= 1.0f) return 0.0f;
  float x2 = xr * xr;
  float x3 = x2 * xr;
  float x6 = x3 * x3;
  return 1.0f - 28.0f * x6 + 48.0f * x6 * xr - 21.0f * x6 * x2;
}

// A-frag slot swizzle: spreads the strided aliasing of the C/D->A scatter
// writes across banks; reads stay a permutation (conflict-free).
__device__ __forceinline__ int swz(int s, int kc) {
  return s ^ ((s >> 5) << 1) ^ ((kc & 1) << 2);
}

__global__ void zero_int_kernel(int* __restrict__ p, int n) {
  int i = blockIdx.x * blockDim.x + threadIdx.x;
  int stride = gridDim.x * blockDim.x;
  for (; i < n; i += stride) p[i] = 0;
}

// ---------------- CSR build: hist -> scan -> scatter --------------------------

__global__ void hist_kernel(int E, const int* __restrict__ idx, int* __restrict__ ecnt) {
  int t = blockIdx.x * 256 + threadIdx.x;
  if (t < E) atomicAdd(&ecnt[idx[E + t]], 1);
}

__launch_bounds__(1024)
__global__ void scan_kernel(const int* __restrict__ ecnt, int* __restrict__ eoff,
                            int* __restrict__ ecur, int n) {
  __shared__ int wsum[16];
  __shared__ int carry;
  const int tid = threadIdx.x;
  const int lane = tid & 63, wid = tid >> 6;
  if (tid == 0) carry = 0;
  __syncthreads();
  for (int b0 = 0; b0 < n; b0 += 1024) {
    const int i = b0 + tid;
    const int v = (i < n) ? ecnt[i] : 0;
    int incl = v;
    #pragma unroll
    for (int o = 1; o < 64; o <<= 1) {
      const int t = __shfl_up(incl, o);
      if (lane >= o) incl += t;
    }
    if (lane == 63) wsum[wid] = incl;
    __syncthreads();
    if (wid == 0) {
      const int wv = (lane < 16) ? wsum[lane] : 0;
      int wsc = wv;
      #pragma unroll
      for (int o = 1; o < 16; o <<= 1) {
        const int t = __shfl_up(wsc, o);
        if (lane >= o) wsc += t;
      }
      if (lane < 16) wsum[lane] = wsc - wv;  // exclusive
    }
    __syncthreads();
    const int c0 = carry;
    const int excl = c0 + wsum[wid] + incl - v;
    if (i < n) { eoff[i] = excl; ecur[i] = excl; }
    __syncthreads();
    if (tid == 1023) carry = c0 + wsum[15] + incl;
    __syncthreads();
  }
  if (tid == 0) eoff[n] = carry;
}

__global__ void scatter_kernel(int E, const int* __restrict__ idx,
                               int* __restrict__ ecur, int* __restrict__ perm) {
  int t = blockIdx.x * 256 + threadIdx.x;
  if (t < E) {
    const int pos = atomicAdd(&ecur[idx[E + t]], 1);
    perm[pos] = t;
  }
}

// ---------------- pack hidden-MLP weights into bf16 MFMA B-fragment order ----
__global__ void pack_hid_weights(const float* __restrict__ W1,
                                 const float* __restrict__ W2,
                                 const float* __restrict__ W3,
                                 unsigned short* __restrict__ out)
{
  int t = blockIdx.x * 256 + threadIdx.x;  // 0..131071
  if (t >= 131072) return;
  int l = t >> 16;
  int oidx = t & 65535;
  const float* src;
  int midx;
  if (oidx < 32768)      { src = W1 + l * 32768; midx = oidx; }
  else if (oidx < 49152) { src = W2 + l * 16384; midx = oidx - 32768; }
  else                   { src = W3 + l * 16384; midx = oidx - 49152; }
  int j = midx & 7;
  int lane = (midx >> 3) & 63;
  int blk = midx >> 9;
  int ct = blk & 3, kc = blk >> 2;
  int col = ct * 32 + (lane & 31);
  int k = kc * 16 + (lane >> 5) * 8 + j;
  out[l * 65536 + oidx] = f2b(src[k * 128 + col]);
}

// ---------------- pack radial-ResNet weights, N=64 (ct in 0..1) --------------
__global__ void pack_rdl_weights(const float* __restrict__ W1,
                                 const float* __restrict__ W2,
                                 const float* __restrict__ W3,
                                 unsigned short* __restrict__ out)
{
  int t = blockIdx.x * 256 + threadIdx.x;  // 0..40959
  if (t >= 40960) return;
  int l = t / 20480;
  int o = t - l * 20480;
  const float* src;
  int midx;
  if (o < 12288)      { src = W1 + l * 12288; midx = o; }
  else if (o < 16384) { src = W2 + l * 4096;  midx = o - 12288; }
  else                { src = W3 + l * 4096;  midx = o - 16384; }
  int j = midx & 7;
  int lane = (midx >> 3) & 63;
  int blk = midx >> 9;
  int ct = blk & 1, kc = blk >> 1;
  int col = ct * 32 + (lane & 31);
  int k = kc * 16 + (lane >> 5) * 8 + j;
  out[l * 20480 + o] = f2b(src[k * 64 + col]);
}

// ---------------- pack feature-MLP weights (rd + sr), 36 blocks --------------
__global__ void pack_feat_weights(const float* __restrict__ rdW1,
                                  const float* __restrict__ rdW2,
                                  const float* __restrict__ rdW3,
                                  const float* __restrict__ srW1,
                                  const float* __restrict__ srW2,
                                  const float* __restrict__ srW3,
                                  unsigned short* __restrict__ out)
{
  int t = blockIdx.x * 256 + threadIdx.x;  // 0..18431
  if (t >= 18432) return;
  const int blk = t >> 9, midx = t & 511;
  const int j = midx & 7, lane = (midx >> 3) & 63;
  const float* src; int kc, ct, K, NC;
  if (blk < 4)       { int b = blk;      src = rdW1; kc = b>>1; ct = b&1; K = 24; NC = 64; }
  else if (blk < 12) { int b = blk - 4;  src = rdW2; kc = b>>1; ct = b&1; K = 64; NC = 64; }
  else if (blk < 20) { int b = blk - 12; src = rdW3; kc = b>>1; ct = b&1; K = 64; NC = 64; }
  else if (blk < 24) { int b = blk - 20; src = srW1; kc = b>>1; ct = b&1; K = 24; NC = 64; }
  else if (blk < 32) { int b = blk - 24; src = srW2; kc = b>>1; ct = b&1; K = 64; NC = 64; }
  else               { int b = blk - 32; src = srW3; kc = b;    ct = 0;   K = 64; NC = 16; }
  const int col = ct * 32 + (lane & 31);
  const int k = kc * 16 + (lane >> 5) * 8 + j;
  const float v = (k < K && col < NC) ? src[k * NC + col] : 0.0f;
  out[t] = f2b(v);
}

// ---------------- pack embedding weights 64x128, 16 blocks -------------------
__global__ void pack_emb_weights(const float* __restrict__ W,
                                 unsigned short* __restrict__ out)
{
  int t = blockIdx.x * 256 + threadIdx.x;  // 0..8191
  if (t >= 8192) return;
  const int j = t & 7, lane = (t >> 3) & 63, blk = t >> 9;
  const int ct = blk & 3, kc = blk >> 2;
  const int col = ct * 32 + (lane & 31);
  const int k = kc * 16 + (lane >> 5) * 8 + j;
  out[t] = f2b(W[k * 128 + col]);
}

// ---------------- stage-A via bf16 MFMA --------------------------------------
// 96 rows/block, 192 threads (3 waves), one barrier.

#define FEAT_TRANS(BASEBLK, V0, V1) do {                                        \
    _Pragma("unroll")                                                           \
    for (int ct_ = 0; ct_ < 2; ++ct_) {                                         \
      const int colh_ = ct_*32 + cl;                                            \
      const int kc2_  = colh_ >> 4;                                             \
      const int b3_   = (colh_ >> 3) & 1;                                       \
      const int jj_   = colh_ & 7;                                              \
      const int blk_  = ((BASEBLK) + kc2_*3 + wave)*512;                        \
      _Pragma("unroll")                                                         \
      for (int q_ = 0; q_ < 16; ++q_) {                                         \
        const int row32_ = (q_ & 3) + 8*(q_ >> 2) + 4*(lane >> 5);              \
        const int s2_ = (row32_ & 31) + 32*b3_;                                 \
        const float v_ = ct_ ? (V1)[q_] : (V0)[q_];                             \
        afrag[blk_ + swz(s2_, kc2_)*8 + jj_] = f2b(fast_tanh(v_));              \
      }                                                                         \
    }                                                                           \
  } while (0)

template<int HAS_SR>
__launch_bounds__(192)
__global__ void feat_mfma(
    int nrows,
    const int* __restrict__ types, const float* __restrict__ lens,
    const float* __restrict__ vecs, const int* __restrict__ idx,
    const float* __restrict__ bessel_w,
    const unsigned short* __restrict__ wpackf,
    const float* __restrict__ srb1, const float* __restrict__ srb2,
    const float* __restrict__ srb3,
    const float* __restrict__ rdb1, const float* __restrict__ rdb2,
    const float* __restrict__ rdb3,
    const float* __restrict__ eln_g, const float* __restrict__ eln_b,
    float* __restrict__ radial_out, float* __restrict__ ud_out,
    float* __restrict__ msgbuf)
{
  __shared__ __align__(16) unsigned short afrag[30*512];  // 30KB
  __shared__ __align__(16) unsigned short wlds[36*512];   // 36KB
  __shared__ float udl[96];

  const int tid  = threadIdx.x;    // 0..191
  const int lane = tid & 63;
  const int wave = tid >> 6;
  const int base = blockIdx.x * 96;
  const int cl   = lane & 31;

  for (int i = tid; i < 2304; i += 192)
    *(u16x8*)&wlds[i*8] = *(const u16x8*)&wpackf[i*8];

  {
    const int r = tid >> 1, h = tid & 1;
    int rowc = base + r;
    const bool valid = rowc < nrows;
    if (!valid) rowc = nrows - 1;
    const int i0 = idx[rowc];
    const int i1 = idx[nrows + rowc];
    const float len = lens[rowc];
    const float ud = poly_cutoff(len);
    const int t0 = types[i0], t1 = types[i1];
    const float invl = 1.0f / len;
    const int rt = r >> 5;
    #pragma unroll
    for (int m = 0; m < 12; ++m) {
      const int k = h + m*2;
      float v;
      if (k < 4)      v = (t0 == k) ? 1.0f : 0.0f;
      else if (k < 8) v = (t1 == (k-4)) ? 1.0f : 0.0f;
      else            v = ud * BESSEL_PREF * __sinf(bessel_w[k-8] * len * RC_INV) * invl;
      const int kc = k >> 4;
      const int s_ = (r & 31) + 32*((k >> 3) & 1);
      afrag[(kc*3 + rt)*512 + swz(s_, kc)*8 + (k & 7)] = f2b(v);
    }
    #pragma unroll
    for (int m = 0; m < 4; ++m) {
      const int k = 24 + h + m*2;
      const int s_ = (r & 31) + 32*((k >> 3) & 1);
      afrag[(1*3 + rt)*512 + swz(s_, 1)*8 + (k & 7)] = 0;
    }
    if (h == 0) {
      udl[r] = ud;
      if (valid) {
        ud_out[rowc] = ud;
        if (HAS_SR) {
          msgbuf[(size_t)rowc*20 + 16] = ud * vecs[(size_t)rowc*3 + 0];
          msgbuf[(size_t)rowc*20 + 17] = ud * vecs[(size_t)rowc*3 + 1];
          msgbuf[(size_t)rowc*20 + 18] = ud * vecs[(size_t)rowc*3 + 2];
        }
      }
    }
  }
  __syncthreads();

  f32x16 acc0, acc1;

  // ======== rd path ========
  {
    const float bv0 = rdb1[cl], bv1 = rdb1[32 + cl];
    #pragma unroll
    for (int q = 0; q < 16; ++q) { acc0[q] = bv0; acc1[q] = bv1; }
  }
  #pragma unroll
  for (int kc = 0; kc < 2; ++kc) {
    const short8 a  = *(const short8*)&afrag[(kc*3 + wave)*512 + swz(lane, kc)*8];
    const short8 w0 = *(const short8*)&wlds[(kc*2 + 0)*512 + lane*8];
    const short8 w1 = *(const short8*)&wlds[(kc*2 + 1)*512 + lane*8];
    acc0 = __builtin_amdgcn_mfma_f32_32x32x16_bf16(a, w0, acc0, 0, 0, 0);
    acc1 = __builtin_amdgcn_mfma_f32_32x32x16_bf16(a, w1, acc1, 0, 0, 0);
  }
  FEAT_TRANS(6, acc0, acc1);

  {
    const float bv0 = rdb2[cl], bv1 = rdb2[32 + cl];
    #pragma unroll
    for (int q = 0; q < 16; ++q) { acc0[q] = bv0; acc1[q] = bv1; }
  }
  #pragma unroll
  for (int kc = 0; kc < 4; ++kc) {
    const short8 a  = *(const short8*)&afrag[((6 + kc*3) + wave)*512 + swz(lane, kc)*8];
    const short8 w0 = *(const short8*)&wlds[(4 + kc*2 + 0)*512 + lane*8];
    const short8 w1 = *(const short8*)&wlds[(4 + kc*2 + 1)*512 + lane*8];
    acc0 = __builtin_amdgcn_mfma_f32_32x32x16_bf16(a, w0, acc0, 0, 0, 0);
    acc1 = __builtin_amdgcn_mfma_f32_32x32x16_bf16(a, w1, acc1, 0, 0, 0);
  }
  FEAT_TRANS(18, acc0, acc1);

  {
    const float bv0 = rdb3[cl], bv1 = rdb3[32 + cl];
    #pragma unroll
    for (int q = 0; q < 16; ++q) { acc0[q] = bv0; acc1[q] = bv1; }
  }
  #pragma unroll
  for (int kc = 0; kc < 4; ++kc) {
    const short8 a  = *(const short8*)&afrag[((18 + kc*3) + wave)*512 + swz(lane, kc)*8];
    const short8 w0 = *(const short8*)&wlds[(12 + kc*2 + 0)*512 + lane*8];
    const short8 w1 = *(const short8*)&wlds[(12 + kc*2 + 1)*512 + lane*8];
    acc0 = __builtin_amdgcn_mfma_f32_32x32x16_bf16(a, w0, acc0, 0, 0, 0);
    acc1 = __builtin_amdgcn_mfma_f32_32x32x16_bf16(a, w1, acc1, 0, 0, 0);
  }
  {
    const float eg0 = eln_g[cl],      eb0 = eln_b[cl];
    const float eg1 = eln_g[32 + cl], eb1 = eln_b[32 + cl];
    #pragma unroll
    for (int q = 0; q < 16; ++q) {
      const float v0 = acc0[q], v1 = acc1[q];
      float s = v0 + v1, ss = v0*v0 + v1*v1;
      #pragma unroll
      for (int o = 1; o <= 16; o <<= 1) {
        s  += __shfl_xor(s, o);
        ss += __shfl_xor(ss, o);
      }
      const float m   = s * (1.0f/64.0f);
      const float inv = rsqrtf(ss * (1.0f/64.0f) - m*m + LN_EPS);
      const int row32 = (q & 3) + 8*(q >> 2) + 4*(lane >> 5);
      const int rloc  = wave*32 + row32;
      const int row   = base + rloc;
      if (row < nrows) {
        const float u = udl[rloc];
        radial_out[(size_t)row*64 + cl]      = ((v0 - m)*inv*eg0 + eb0) * u;
        radial_out[(size_t)row*64 + 32 + cl] = ((v1 - m)*inv*eg1 + eb1) * u;
      }
    }
  }

  // ======== sr path ========
  if (HAS_SR) {
    {
      const float bv0 = srb1[cl], bv1 = srb1[32 + cl];
      #pragma unroll
      for (int q = 0; q < 16; ++q) { acc0[q] = bv0; acc1[q] = bv1; }
    }
    #pragma unroll
    for (int kc = 0; kc < 2; ++kc) {
      const short8 a  = *(const short8*)&afrag[(kc*3 + wave)*512 + swz(lane, kc)*8];
      const short8 w0 = *(const short8*)&wlds[(20 + kc*2 + 0)*512 + lane*8];
      const short8 w1 = *(const short8*)&wlds[(20 + kc*2 + 1)*512 + lane*8];
      acc0 = __builtin_amdgcn_mfma_f32_32x32x16_bf16(a, w0, acc0, 0, 0, 0);
      acc1 = __builtin_amdgcn_mfma_f32_32x32x16_bf16(a, w1, acc1, 0, 0, 0);
    }
    FEAT_TRANS(6, acc0, acc1);

    {
      const float bv0 = srb2[cl], bv1 = srb2[32 + cl];
      #pragma unroll
      for (int q = 0; q < 16; ++q) { acc0[q] = bv0; acc1[q] = bv1; }
    }
    #pragma unroll
    for (int kc = 0; kc < 4; ++kc) {
      const short8 a  = *(const short8*)&afrag[((6 + kc*3) + wave)*512 + swz(lane, kc)*8];
      const short8 w0 = *(const short8*)&wlds[(24 + kc*2 + 0)*512 + lane*8];
      const short8 w1 = *(const short8*)&wlds[(24 + kc*2 + 1)*512 + lane*8];
      acc0 = __builtin_amdgcn_mfma_f32_32x32x16_bf16(a, w0, acc0, 0, 0, 0);
      acc1 = __builtin_amdgcn_mfma_f32_32x32x16_bf16(a, w1, acc1, 0, 0, 0);
    }
    FEAT_TRANS(18, acc0, acc1);

    {
      const float bv0 = (cl < 16) ? srb3[cl] : 0.0f;
      #pragma unroll
      for (int q = 0; q < 16; ++q) acc0[q] = bv0;
    }
    #pragma unroll
    for (int kc = 0; kc < 4; ++kc) {
      const short8 a  = *(const short8*)&afrag[((18 + kc*3) + wave)*512 + swz(lane, kc)*8];
      const short8 w0 = *(const short8*)&wlds[(32 + kc)*512 + lane*8];
      acc0 = __builtin_amdgcn_mfma_f32_32x32x16_bf16(a, w0, acc0, 0, 0, 0);
    }
    if (cl < 16) {
      #pragma unroll
      for (int q = 0; q < 16; ++q) {
        const int row32 = (q & 3) + 8*(q >> 2) + 4*(lane >> 5);
        const int rloc  = wave*32 + row32;
        const int row   = base + rloc;
        if (row < nrows) msgbuf[(size_t)row*20 + cl] = acc0[q] * udl[rloc];
      }
    }
  }
}

// ---------------- SE(2) message gather: aggS (no atomics) --------------------

__launch_bounds__(256)
__global__ void msg_gather_kernel(int N, const int* __restrict__ eoff,
                                  const int* __restrict__ perm,
                                  const float* __restrict__ msgbuf,
                                  float* __restrict__ aggS)
{
  const int w = (blockIdx.x * 256 + threadIdx.x) >> 6;
  const int lane = threadIdx.x & 63;
  if (w >= N) return;
  const int s = eoff[w], e = eoff[w + 1];
  const int d = lane / 3, c = lane - d * 3;
  float acc = 0.0f;
  for (int j = s; j < e; ++j) {
    const int ed = perm[j];
    if (lane < 48)
      acc += msgbuf[(size_t)ed*20 + d] * msgbuf[(size_t)ed*20 + 16 + c];
  }
  if (lane < 48) aggS[(size_t)w*48 + lane] = acc;
}

// ---------------- node embedding (gram + LN) ---------------------------------

__device__ __forceinline__ void block128_stats(float x, float& m, float& inv, float* red) {
  float s = x, ss = x*x;
  #pragma unroll
  for (int o = 32; o; o >>= 1) { s += __shfl_down(s, o); ss += __shfl_down(ss, o); }
  const int t = threadIdx.x;
  if ((t & 63) == 0) { red[(t >> 6)*2] = s; red[(t >> 6)*2 + 1] = ss; }
  __syncthreads();
  const float S = red[0] + red[2], SS = red[1] + red[3];
  m = S * (1.0f/128.0f);
  const float var = SS * (1.0f/128.0f) - m*m;
  inv = rsqrtf(var + LN_EPS);
}

__launch_bounds__(128)
__global__ void node_emb_kernel(int N, const float* __restrict__ aggS,
                                const int* __restrict__ ecnt,
                                const float* __restrict__ g, const float* __restrict__ b,
                                float* __restrict__ node_emb)
{
  const int n = blockIdx.x, t = threadIdx.x;
  __shared__ float S[48];
  __shared__ float red[4];
  if (t < 48) S[t] = aggS[(size_t)n*48 + t];
  __syncthreads();
  const float ic = 1.0f / fmaxf((float)ecnt[n], 1.0f);
  const int d = t >> 3, e = t & 7;
  const float x = (S[d*3+0]*S[e*3+0] + S[d*3+1]*S[e*3+1] + S[d*3+2]*S[e*3+2]) * ic * ic;
  float m, inv;
  block128_stats(x, m, inv, red);
  node_emb[(size_t)n*128 + t] = (x - m)*inv*g[t] + b[t];
}

// ---------------- per-layer aggregation: CSR gather (no atomics) -------------

__launch_bounds__(256)
__global__ void agg_gather_kernel(int N, const int* __restrict__ eoff,
                                  const int* __restrict__ perm,
                                  const float* __restrict__ radial,
                                  float* __restrict__ mean_r)
{
  const int w = (blockIdx.x * 256 + threadIdx.x) >> 6;
  const int lane = threadIdx.x & 63;
  if (w >= N) return;
  const int s = eoff[w], e = eoff[w + 1];
  float acc = 0.0f;
  for (int j = s; j < e; ++j) {
    const int ed = perm[j];
    acc += radial[(size_t)ed * 64 + lane];
  }
  const float inv = 1.0f / fmaxf((float)(e - s), 1.0f);
  mean_r[(size_t)w * 64 + lane] = acc * inv;
}

// ---------------- node update: (mean_r @ W + b) * old, LN, residual ----------

__launch_bounds__(256)
__global__ void node_update_gemm(
    int N, const float* __restrict__ mean_r, const int* __restrict__ ecnt,
    const float* __restrict__ W, const float* __restrict__ bias,
    const float* __restrict__ g, const float* __restrict__ b,
    float* __restrict__ node_emb)
{
  __shared__ __align__(16) float lw[64*128];
  __shared__ float lm[32][65];
  const int tid = threadIdx.x;
  const int base = blockIdx.x * 32;

  for (int i = tid; i < 8192; i += 256) lw[i] = W[i];
  {
    const int rr0 = tid >> 6, k = tid & 63;
    for (int rr = rr0; rr < 32; rr += 4) {
      const int n = base + rr;
      lm[rr][k] = (n < N) ? mean_r[(size_t)n*64 + k] : 0.0f;
    }
  }
  __syncthreads();

  const int r0 = (tid >> 5) * 4, j0 = (tid & 31) * 4;
  float acc[4][4];
  #pragma unroll
  for (int j = 0; j < 4; ++j) {
    const float bj = bias[j0 + j];
    acc[0][j] = bj; acc[1][j] = bj; acc[2][j] = bj; acc[3][j] = bj;
  }
  for (int k = 0; k < 64; ++k) {
    const float4 w = *(const float4*)&lw[k*128 + j0];
    const float s0 = lm[r0][k],   s1 = lm[r0+1][k];
    const float s2 = lm[r0+2][k], s3 = lm[r0+3][k];
    acc[0][0] += s0*w.x; acc[0][1] += s0*w.y; acc[0][2] += s0*w.z; acc[0][3] += s0*w.w;
    acc[1][0] += s1*w.x; acc[1][1] += s1*w.y; acc[1][2] += s1*w.z; acc[1][3] += s1*w.w;
    acc[2][0] += s2*w.x; acc[2][1] += s2*w.y; acc[2][2] += s2*w.z; acc[2][3] += s2*w.w;
    acc[3][0] += s3*w.x; acc[3][1] += s3*w.y; acc[3][2] += s3*w.z; acc[3][3] += s3*w.w;
  }

  const float g0 = g[j0], g1 = g[j0+1], g2 = g[j0+2], g3 = g[j0+3];
  const float bb0 = b[j0], bb1 = b[j0+1], bb2 = b[j0+2], bb3 = b[j0+3];
  #pragma unroll
  for (int i = 0; i < 4; ++i) {
    const int n = base + r0 + i;
    if (n >= N) continue;
    const float mask = (ecnt[n] > 0) ? 1.0f : 0.0f;
    const float4 old = *(const float4*)&node_emb[(size_t)n*128 + j0];
    const float x0 = old.x * acc[i][0] * mask;
    const float x1 = old.y * acc[i][1] * mask;
    const float x2 = old.z * acc[i][2] * mask;
    const float x3 = old.w * acc[i][3] * mask;
    float s = x0 + x1 + x2 + x3;
    float ss = x0*x0 + x1*x1 + x2*x2 + x3*x3;
    #pragma unroll
    for (int o = 1; o <= 16; o <<= 1) {
      s  += __shfl_xor(s, o);
      ss += __shfl_xor(ss, o);
    }
    const float m = s * (1.0f/128.0f);
    const float inv = rsqrtf(ss * (1.0f/128.0f) - m*m + LN_EPS);
    float4 o4;
    o4.x = C_RES*old.x + C_NEW*((x0 - m)*inv*g0 + bb0);
    o4.y = C_RES*old.y + C_NEW*((x1 - m)*inv*g1 + bb1);
    o4.z = C_RES*old.z + C_NEW*((x2 - m)*inv*g2 + bb2);
    o4.w = C_RES*old.w + C_NEW*((x3 - m)*inv*g3 + bb3);
    *(float4*)&node_emb[(size_t)n*128 + j0] = o4;
  }
}

// ---------------- embedding GEMM via MFMA ------------------------------------

__launch_bounds__(192)
__global__ void emb_mfma(
    int nrows,
    const float* __restrict__ radial,
    const unsigned short* __restrict__ wpck, const float* __restrict__ bias,
    const int* __restrict__ idx,
    const float* __restrict__ node_emb,
    float* __restrict__ out)
{
  __shared__ __align__(16) unsigned short afrag[12*512];  // 12KB
  __shared__ __align__(16) unsigned short wlds[16*512];   // 16KB
  __shared__ int i0l[96], i1l[96];

  const int tid = threadIdx.x, lane = tid & 63, wave = tid >> 6;
  const int base = blockIdx.x * 96, cl = lane & 31;

  for (int i = tid; i < 1024; i += 192)
    *(u16x8*)&wlds[i*8] = *(const u16x8*)&wpck[i*8];

  {
    const int r = tid >> 1, h = tid & 1;
    int rowg = base + r;
    if (rowg >= nrows) rowg = nrows - 1;
    if (h == 0) { i0l[r] = idx[rowg]; i1l[r] = idx[nrows + rowg]; }
    const float* rsrc = radial + (size_t)rowg * 64;
    #pragma unroll
    for (int g = 0; g < 4; ++g) {
      const int k = h*32 + g*8;
      const u16x8 w = cvt8(rsrc + k);
      const int kc = k >> 4;
      const int s_ = (r & 31) + 32*((k >> 3) & 1);
      *(u16x8*)&afrag[(kc*3 + (r>>5))*512 + swz(s_, kc)*8] = w;
    }
  }
  __syncthreads();

  f32x16 acc0, acc1, acc2, acc3;
  {
    const float bv0 = bias[cl], bv1 = bias[32+cl];
    const float bv2 = bias[64+cl], bv3 = bias[96+cl];
    #pragma unroll
    for (int q = 0; q < 16; ++q) { acc0[q]=bv0; acc1[q]=bv1; acc2[q]=bv2; acc3[q]=bv3; }
  }
  #pragma unroll
  for (int kc = 0; kc < 4; ++kc) {
    const short8 a  = *(const short8*)&afrag[(kc*3 + wave)*512 + swz(lane, kc)*8];
    const short8 w0 = *(const short8*)&wlds[(kc*4 + 0)*512 + lane*8];
    const short8 w1 = *(const short8*)&wlds[(kc*4 + 1)*512 + lane*8];
    const short8 w2 = *(const short8*)&wlds[(kc*4 + 2)*512 + lane*8];
    const short8 w3 = *(const short8*)&wlds[(kc*4 + 3)*512 + lane*8];
    acc0 = __builtin_amdgcn_mfma_f32_32x32x16_bf16(a, w0, acc0, 0, 0, 0);
    acc1 = __builtin_amdgcn_mfma_f32_32x32x16_bf16(a, w1, acc1, 0, 0, 0);
    acc2 = __builtin_amdgcn_mfma_f32_32x32x16_bf16(a, w2, acc2, 0, 0, 0);
    acc3 = __builtin_amdgcn_mfma_f32_32x32x16_bf16(a, w3, acc3, 0, 0, 0);
  }

  #pragma unroll
  for (int q = 0; q < 16; ++q) {
    const int row32 = (q & 3) + 8*(q >> 2) + 4*(lane >> 5);
    const int rloc  = wave*32 + row32;
    const int row   = base + rloc;
    if (row >= nrows) continue;
    const float* n0 = node_emb + (size_t)i0l[rloc]*128;
    const float* n1 = node_emb + (size_t)i1l[rloc]*128;
    float* op = out + (size_t)row*128;
    op[cl]    = acc0[q] * 0.5f * (n0[cl]    + n1[cl]);
    op[32+cl] = acc1[q] * 0.5f * (n0[32+cl] + n1[32+cl]);
    op[64+cl] = acc2[q] * 0.5f * (n0[64+cl] + n1[64+cl]);
    op[96+cl] = acc3[q] * 0.5f * (n0[96+cl] + n1[96+cl]);
  }
}

// ---------------- FUSED hidden-MLP + radial-ResNet per layer -----------------
// 128 rows/block, 256 threads (4 waves, wave = row-tile). hid: 3 layers with
// phase-staged weights (wg 8KB); new hidden written to global AND scattered
// (no tanh) into afragH as rdl A-frags; rdl: 3 layers + in-register LN
// epilogue reading old radial from afragR. All transitions wave-local.

__launch_bounds__(256)
__global__ void hidrdl_mfma(
    int nrows, const int* __restrict__ idx0,
    const float* __restrict__ node_emb,
    const float* __restrict__ ud,
    const unsigned short* __restrict__ wpackh,  // hid: 65536 u16 this layer
    const float* __restrict__ hb1, const float* __restrict__ hb2,
    const float* __restrict__ hb3,
    const unsigned short* __restrict__ wpackr,  // rdl: 20480 u16 this layer
    const float* __restrict__ rb1, const float* __restrict__ rb2,
    const float* __restrict__ rb3,
    const float* __restrict__ eln_g, const float* __restrict__ eln_b,
    float* __restrict__ hidden,    // in: hidden_prev, out: hidden_new
    float* __restrict__ radial)    // in: radial_prev, out: radial_new
{
  __shared__ __align__(16) unsigned short afragH[16384];  // 32KB: (rt*8+h)*512
  __shared__ __align__(16) unsigned short afragR[8192];   // 16KB: (rt*4+kc)*512
  __shared__ __align__(16) unsigned short xg[4096];       // 8KB:  (rt*2+kcl)*512
  __shared__ __align__(16) unsigned short wg[4096];       // 8KB
  __shared__ float udl[128];

  const int tid  = threadIdx.x;
  const int lane = tid & 63;
  const int wave = tid >> 6;       // rt 0..3
  const int base = blockIdx.x * 128;
  const int cl   = lane & 31;

  // ---- initial staging (rows are wave-local: r>>5 == wave) ----
  const int r = tid >> 1, h2 = tid & 1;
  int rowg = base + r;
  if (rowg >= nrows) rowg = nrows - 1;
  const int rt0 = r >> 5;
  {
    const float* hsrc = hidden + (size_t)rowg * 128;
    const float* rsrc = radial + (size_t)rowg * 64;
    if (h2 == 0) udl[r] = ud[rowg];
    #pragma unroll
    for (int g = 0; g < 4; ++g) {       // old hidden -> afragH (h 0..7)
      const int k = h2*64 + g*16;
      #pragma unroll
      for (int gg = 0; gg < 2; ++gg) {
        const int kk = k + gg*8;
        const u16x8 w = cvt8(hsrc + kk);
        const int h = kk >> 4;
        const int s_ = (r & 31) + 32*((kk >> 3) & 1);
        *(u16x8*)&afragH[(rt0*8 + h)*512 + swz(s_, h)*8] = w;
      }
    }
    #pragma unroll
    for (int g = 0; g < 4; ++g) {       // radial -> afragR (kc 0..3)
      const int k = h2*32 + g*8;
      const u16x8 w = cvt8(rsrc + k);
      const int kc = k >> 4;
      const int s_ = (r & 31) + 32*((k >> 3) & 1);
      *(u16x8*)&afragR[(rt0*4 + kc)*512 + swz(s_, kc)*8] = w;
    }
  }
  const float* xsrc0 = node_emb + (size_t)idx0[rowg] * 128;

  f32x16 acc[4];

  // ========= hid layer 1: K=256 (kc 0..7 node_emb via xg, kc 8..15 afragH) ===
  #pragma unroll
  for (int ct = 0; ct < 4; ++ct) {
    const float bv = hb1[ct*32 + cl];
    #pragma unroll
    for (int q = 0; q < 16; ++q) acc[ct][q] = bv;
  }
  for (int p = 0; p < 8; ++p) {
    __syncthreads();
    if (p < 4) {
      #pragma unroll
      for (int oo = 0; oo < 2; ++oo) {
        const int o = h2*2 + oo;
        const int k = p*32 + o*8;
        const u16x8 w = cvt8(xsrc0 + k);
        const int kc = p*2 + (o >> 1);
        const int s_ = (r & 31) + 32*(o & 1);
        *(u16x8*)&xg[ (rt0*2 + (o>>1))*512 + swz(s_, kc)*8 ] = w;
      }
    }
    #pragma unroll
    for (int i = 0; i < 2; ++i) {
      const int c = tid + i*256;
      *(u16x8*)&wg[c*8] = *(const u16x8*)&wpackh[p*4096 + c*8];
    }
    __syncthreads();
    #pragma unroll
    for (int kcl = 0; kcl < 2; ++kcl) {
      const int kc = p*2 + kcl;
      const short8 a = (p < 4)
        ? *(const short8*)&xg[ (wave*2 + kcl)*512 + swz(lane, kc)*8 ]
        : *(const short8*)&afragH[ (wave*8 + (kc-8))*512 + swz(lane, kc-8)*8 ];
      #pragma unroll
      for (int ct = 0; ct < 4; ++ct) {
        const short8 b = *(const short8*)&wg[ (kcl*4 + ct)*512 + lane*8 ];
        acc[ct] = __builtin_amdgcn_mfma_f32_32x32x16_bf16(a, b, acc[ct], 0, 0, 0);
      }
    }
  }

  // ---- transition 1 (wave-local, tanh) -> afragH ----
  #pragma unroll
  for (int ct = 0; ct < 4; ++ct) {
    const int kc  = ct*2 + ((lane >> 4) & 1);
    const int oct = (lane >> 3) & 1;
    const int j   = lane & 7;
    const int xk  = (oct << 1) ^ ((kc & 1) << 2);
    const int hi  = 4*(lane >> 5);
    const int bi  = (wave*8 + kc)*512 + oct*256 + j;
    #pragma unroll
    for (int q = 0; q < 16; ++q) {
      const int m32 = (q & 3) + 8*(q >> 2) + hi;
      afragH[bi + (m32 ^ xk)*8] = f2b(fast_tanh(acc[ct][q]));
    }
  }

  // ========= hid layer 2: K=128 =========
  #pragma unroll
  for (int ct = 0; ct < 4; ++ct) {
    const float bv = hb2[ct*32 + cl];
    #pragma unroll
    for (int q = 0; q < 16; ++q) acc[ct][q] = bv;
  }
  for (int p = 0; p < 4; ++p) {
    __syncthreads();
    #pragma unroll
    for (int i = 0; i < 2; ++i) {
      const int c = tid + i*256;
      *(u16x8*)&wg[c*8] = *(const u16x8*)&wpackh[32768 + p*4096 + c*8];
    }
    __syncthreads();
    #pragma unroll
    for (int kcl = 0; kcl < 2; ++kcl) {
      const int kc = p*2 + kcl;
      const short8 a = *(const short8*)&afragH[ (wave*8 + kc)*512 + swz(lane, kc)*8 ];
      #pragma unroll
      for (int ct = 0; ct < 4; ++ct) {
        const short8 b = *(const short8*)&wg[ (kcl*4 + ct)*512 + lane*8 ];
        acc[ct] = __builtin_amdgcn_mfma_f32_32x32x16_bf16(a, b, acc[ct], 0, 0, 0);
      }
    }
  }

  // ---- transition 2 (wave-local, tanh) -> afragH ----
  #pragma unroll
  for (int ct = 0; ct < 4; ++ct) {
    const int kc  = ct*2 + ((lane >> 4) & 1);
    const int oct = (lane >> 3) & 1;
    const int j   = lane & 7;
    const int xk  = (oct << 1) ^ ((kc & 1) << 2);
    const int hi  = 4*(lane >> 5);
    const int bi  = (wave*8 + kc)*512 + oct*256 + j;
    #pragma unroll
    for (int q = 0; q < 16; ++q) {
      const int m32 = (q & 3) + 8*(q >> 2) + hi;
      afragH[bi + (m32 ^ xk)*8] = f2b(fast_tanh(acc[ct][q]));
    }
  }

  // ========= hid layer 3: K=128 =========
  #pragma unroll
  for (int ct = 0; ct < 4; ++ct) {
    const float bv = hb3[ct*32 + cl];
    #pragma unroll
    for (int q = 0; q < 16; ++q) acc[ct][q] = bv;
  }
  for (int p = 0; p < 4; ++p) {
    __syncthreads();
    #pragma unroll
    for (int i = 0; i < 2; ++i) {
      const int c = tid + i*256;
      *(u16x8*)&wg[c*8] = *(const u16x8*)&wpackh[49152 + p*4096 + c*8];
    }
    __syncthreads();
    #pragma unroll
    for (int kcl = 0; kcl < 2; ++kcl) {
      const int kc = p*2 + kcl;
      const short8 a = *(const short8*)&afragH[ (wave*8 + kc)*512 + swz(lane, kc)*8 ];
      #pragma unroll
      for (int ct = 0; ct < 4; ++ct) {
        const short8 b = *(const short8*)&wg[ (kcl*4 + ct)*512 + lane*8 ];
        acc[ct] = __builtin_amdgcn_mfma_f32_32x32x16_bf16(a, b, acc[ct], 0, 0, 0);
      }
    }
  }

  // ---- hid epilogue: global write + scatter (no tanh) -> afragH ----
  #pragma unroll
  for (int ct = 0; ct < 4; ++ct) {
    const int col = ct*32 + cl;
    #pragma unroll
    for (int q = 0; q < 16; ++q) {
      const int row = base + wave*32 + (q & 3) + 8*(q >> 2) + 4*(lane >> 5);
      if (row < nrows) hidden[(size_t)row*128 + col] = acc[ct][q];
    }
  }
  #pragma unroll
  for (int ct = 0; ct < 4; ++ct) {
    const int kc  = ct*2 + ((lane >> 4) & 1);
    const int oct = (lane >> 3) & 1;
    const int j   = lane & 7;
    const int xk  = (oct << 1) ^ ((kc & 1) << 2);
    const int hi  = 4*(lane >> 5);
    const int bi  = (wave*8 + kc)*512 + oct*256 + j;
    #pragma unroll
    for (int q = 0; q < 16; ++q) {
      const int m32 = (q & 3) + 8*(q >> 2) + hi;
      afragH[bi + (m32 ^ xk)*8] = f2b(acc[ct][q]);
    }
  }

  // ========= rdl layer 1: K=192 (kc 0..3 afragR, kc 4..11 afragH) =========
  f32x16 racc0, racc1;
  {
    const float bv0 = rb1[cl], bv1 = rb1[32 + cl];
    #pragma unroll
    for (int q = 0; q < 16; ++q) { racc0[q] = bv0; racc1[q] = bv1; }
  }
  for (int t = 0; t < 3; ++t) {
    __syncthreads();
    #pragma unroll
    for (int i = 0; i < 2; ++i) {
      const int c = tid + i*256;
      *(u16x8*)&wg[c*8] = *(const u16x8*)&wpackr[t*4096 + c*8];
    }
    __syncthreads();
    #pragma unroll
    for (int kk = 0; kk < 4; ++kk) {
      const int kc = t*4 + kk;
      const short8 a = (kc < 4)
        ? *(const short8*)&afragR[ (wave*4 + kc)*512 + swz(lane, kc)*8 ]
        : *(const short8*)&afragH[ (wave*8 + (kc-4))*512 + swz(lane, kc-4)*8 ];
      const short8 w0 = *(const short8*)&wg[ (kk*2 + 0)*512 + lane*8 ];
      const short8 w1 = *(const short8*)&wg[ (kk*2 + 1)*512 + lane*8 ];
      racc0 = __builtin_amdgcn_mfma_f32_32x32x16_bf16(a, w0, racc0, 0, 0, 0);
      racc1 = __builtin_amdgcn_mfma_f32_32x32x16_bf16(a, w1, racc1, 0, 0, 0);
    }
  }

  // ---- rdl transition 1 (tanh) -> afragH h 0..3 (wave-local) ----
  #pragma unroll
  for (int ct = 0; ct < 2; ++ct) {
    const int colh = ct*32 + cl;
    const int kc2  = colh >> 4;
    const int b3_  = (colh >> 3) & 1;
    const int jj   = colh & 7;
    const int blk  = (wave*8 + kc2)*512;
    #pragma unroll
    for (int q = 0; q < 16; ++q) {
      const int row32 = (q & 3) + 8*(q >> 2) + 4*(lane >> 5);
      const int s_ = (row32 & 31) + 32*b3_;
      const float v = ct ? racc1[q] : racc0[q];
      afragH[blk + swz(s_, kc2)*8 + jj] = f2b(fast_tanh(v));
    }
  }

  // ========= rdl layer 2: K=64 (no tanh on out; h kept in regs) =========
  f32x16 rh0, rh1;
  {
    const float bv0 = rb2[cl], bv1 = rb2[32 + cl];
    #pragma unroll
    for (int q = 0; q < 16; ++q) { rh0[q] = bv0; rh1[q] = bv1; }
  }
  __syncthreads();
  #pragma unroll
  for (int i = 0; i < 2; ++i) {
    const int c = tid + i*256;
    *(u16x8*)&wg[c*8] = *(const u16x8*)&wpackr[24*512 + c*8];
  }
  __syncthreads();
  #pragma unroll
  for (int kc = 0; kc < 4; ++kc) {
    const short8 a  = *(const short8*)&afragH[ (wave*8 + kc)*512 + swz(lane, kc)*8 ];
    const short8 w0 = *(const short8*)&wg[ (kc*2 + 0)*512 + lane*8 ];
    const short8 w1 = *(const short8*)&wg[ (kc*2 + 1)*512 + lane*8 ];
    rh0 = __builtin_amdgcn_mfma_f32_32x32x16_bf16(a, w0, rh0, 0, 0, 0);
    rh1 = __builtin_amdgcn_mfma_f32_32x32x16_bf16(a, w1, rh1, 0, 0, 0);
  }

  // ---- rdl transition 2: tanh(h) -> afragH h 4..7 (wave-local) ----
  #pragma unroll
  for (int ct = 0; ct < 2; ++ct) {
    const int colh = ct*32 + cl;
    const int kc2  = colh >> 4;
    const int b3_  = (colh >> 3) & 1;
    const int jj   = colh & 7;
    const int blk  = (wave*8 + 4 + kc2)*512;
    #pragma unroll
    for (int q = 0; q < 16; ++q) {
      const int row32 = (q & 3) + 8*(q >> 2) + 4*(lane >> 5);
      const int s_ = (row32 & 31) + 32*b3_;
      const float v = ct ? rh1[q] : rh0[q];
      afragH[blk + swz(s_, kc2)*8 + jj] = f2b(fast_tanh(v));
    }
  }

  // ========= rdl layer 3: K=64 =========
  {
    const float bv0 = rb3[cl], bv1 = rb3[32 + cl];
    #pragma unroll
    for (int q = 0; q < 16; ++q) { racc0[q] = bv0; racc1[q] = bv1; }
  }
  __syncthreads();
  #pragma unroll
  for (int i = 0; i < 2; ++i) {
    const int c = tid + i*256;
    *(u16x8*)&wg[c*8] = *(const u16x8*)&wpackr[32*512 + c*8];
  }
  __syncthreads();
  #pragma unroll
  for (int kc = 0; kc < 4; ++kc) {
    const short8 a  = *(const short8*)&afragH[ (wave*8 + 4 + kc)*512 + swz(lane, kc)*8 ];
    const short8 w0 = *(const short8*)&wg[ (kc*2 + 0)*512 + lane*8 ];
    const short8 w1 = *(const short8*)&wg[ (kc*2 + 1)*512 + lane*8 ];
    racc0 = __builtin_amdgcn_mfma_f32_32x32x16_bf16(a, w0, racc0, 0, 0, 0);
    racc1 = __builtin_amdgcn_mfma_f32_32x32x16_bf16(a, w1, racc1, 0, 0, 0);
  }

  // ---- rdl epilogue: +h, LN (shfl butterfly), residual-scale, store ----
  const float eg0 = eln_g[cl],      eb0 = eln_b[cl];
  const float eg1 = eln_g[32 + cl], eb1 = eln_b[32 + cl];
  const int kcA = cl >> 4;
  const int kcB = (32 + cl) >> 4;
  const int jA  = cl & 7;
  const int bA  = (wave*4 + kcA)*512;
  const int bB  = (wave*4 + kcB)*512;
  const int b3A = (cl >> 3) & 1;
  const int b3B = ((32 + cl) >> 3) & 1;

  #pragma unroll
  for (int q = 0; q < 16; ++q) {
    const float v0 = racc0[q] + rh0[q];
    const float v1 = racc1[q] + rh1[q];
    float s = v0 + v1, ss = v0*v0 + v1*v1;
    #pragma unroll
    for (int o = 1; o <= 16; o <<= 1) {
      s  += __shfl_xor(s, o);
      ss += __shfl_xor(ss, o);
    }
    const float m   = s * (1.0f/64.0f);
    const float inv = rsqrtf(ss * (1.0f/64.0f) - m*m + LN_EPS);
    const int row32 = (q & 3) + 8*(q >> 2) + 4*(lane >> 5);
    const int rloc  = wave*32 + row32;
    const int row   = base + rloc;
    if (row < nrows) {
      const float u = udl[rloc];
      const int sA = (row32 & 31) + 32*b3A;
      const int sB = (row32 & 31) + 32*b3B;
      const float oldA = __uint_as_float((unsigned)afragR[bA + swz(sA, kcA)*8 + jA] << 16);
      const float oldB = __uint_as_float((unsigned)afragR[bB + swz(sB, kcB)*8 + jA] << 16);
      radial[(size_t)row*64 + cl]      = C_RES*oldA + C_NEW*u*((v0 - m)*inv*eg0 + eb0);
      radial[(size_t)row*64 + 32 + cl] = C_RES*oldB + C_NEW*u*((v1 - m)*inv*eg1 + eb1);
    }
  }
}

// ---------------- launch -----------------------------------------------------

extern "C" void kernel_launch(void* const* d_in, const int* in_sizes, int n_in,
                              void* d_out, int out_size, void* d_ws, size_t ws_size,
                              hipStream_t stream)
{
  const int*   atom_types = (const int*)  d_in[0];
  const float* env_vec    = (const float*)d_in[1];
  const float* env_len    = (const float*)d_in[2];
  const float* edge_len   = (const float*)d_in[3];
  const int*   env_idx    = (const int*)  d_in[4];
  const int*   edge_idx   = (const int*)  d_in[5];
  const float* bessel_w   = (const float*)d_in[6];
  const float* srW1 = (const float*)d_in[7];  const float* srb1 = (const float*)d_in[8];
  const float* srW2 = (const float*)d_in[9];  const float* srb2 = (const float*)d_in[10];
  const float* srW3 = (const float*)d_in[11]; const float* srb3 = (const float*)d_in[12];
  const float* rdW1 = (const float*)d_in[13]; const float* rdb1 = (const float*)d_in[14];
  const float* rdW2 = (const float*)d_in[15]; const float* rdb2 = (const float*)d_in[16];
  const float* rdW3 = (const float*)d_in[17]; const float* rdb3 = (const float*)d_in[18];
  const float* ne_emb_W = (const float*)d_in[19]; const float* ne_emb_b = (const float*)d_in[20];
  const float* ne_nln_g = (const float*)d_in[21]; const float* ne_nln_b = (const float*)d_in[22];
  const float* ne_eln_g = (const float*)d_in[23]; const float* ne_eln_b = (const float*)d_in[24];
  const float* ly_emb_W = (const float*)d_in[25]; const float* ly_emb_b = (const float*)d_in[26];
  const float* ly_hid_W1 = (const float*)d_in[27]; const float* ly_hid_b1 = (const float*)d_in[28];
  const float* ly_hid_W2 = (const float*)d_in[29]; const float* ly_hid_b2 = (const float*)d_in[30];
  const float* ly_hid_W3 = (const float*)d_in[31]; const float* ly_hid_b3 = (const float*)d_in[32];
  const float* ly_rdl_W1 = (const float*)d_in[33]; const float* ly_rdl_b1 = (const float*)d_in[34];
  const float* ly_rdl_W2 = (const float*)d_in[35]; const float* ly_rdl_b2 = (const float*)d_in[36];
  const float* ly_rdl_W3 = (const float*)d_in[37]; const float* ly_rdl_b3 = (const float*)d_in[38];
  const float* ly_nln_g = (const float*)d_in[39]; const float* ly_nln_b = (const float*)d_in[40];
  const float* ly_eln_g = (const float*)d_in[41]; const float* ly_eln_b = (const float*)d_in[42];

  const int N  = in_sizes[0];
  const int E  = in_sizes[2];
  const int E2 = in_sizes[3];

  float* out = (float*)d_out;
  float* env_radial  = out;
  float* edge_radial = env_radial + (size_t)E * 64;
  float* node_emb    = edge_radial + (size_t)E2 * 64;
  float* env_hidden  = node_emb + (size_t)N * 128;
  float* edge_hidden = env_hidden + (size_t)E * 128;

  float* ws = (float*)d_ws;
  float* ud_env  = ws;  ws += E;
  float* ud_edge = ws;  ws += E2;
  float* aggS    = ws;  ws += (size_t)N * 48;
  float* msgbuf  = ws;  ws += (size_t)E * 20;   // sval[16] | evud[3] | pad
  float* mean_r  = msgbuf;                      // reuse after msg_gather
  unsigned short* wpack  = (unsigned short*)ws; ws += 65536;   // hid: 2 x 65536 u16
  unsigned short* wpack2 = (unsigned short*)ws; ws += 20480;   // rdl: 2 x 20480 u16
  unsigned short* wpack3 = (unsigned short*)ws; ws += 9216;    // feat: 18432 u16
  unsigned short* wpackE = (unsigned short*)ws; ws += 4096;    // emb: 8192 u16
  int* ecnt = (int*)ws; ws += N;
  int* eoff = (int*)ws; ws += N + 1;
  int* ecur = (int*)ws; ws += N + 1;
  int* perm = (int*)ws; ws += E;

  const int gEr  = (E  + 95) / 96;
  const int gE2r = (E2 + 95) / 96;
  const int gEf  = (E  + 127) / 128;
  const int gE2f = (E2 + 127) / 128;
  const int gN32 = (N + 31) / 32;
  const int gN4w = (N * 64 + 255) / 256;

  // CSR build over env graph (i1 = env_idx[1])
  zero_int_kernel<<<256, 256, 0, stream>>>(ecnt, N);
  hist_kernel<<<(E + 255) / 256, 256, 0, stream>>>(E, env_idx, ecnt);
  scan_kernel<<<1, 1024, 0, stream>>>(ecnt, eoff, ecur, N);
  scatter_kernel<<<(E + 255) / 256, 256, 0, stream>>>(E, env_idx, ecur, perm);

  pack_hid_weights<<<512, 256, 0, stream>>>(ly_hid_W1, ly_hid_W2, ly_hid_W3, wpack);
  pack_rdl_weights<<<160, 256, 0, stream>>>(ly_rdl_W1, ly_rdl_W2, ly_rdl_W3, wpack2);
  pack_feat_weights<<<72, 256, 0, stream>>>(rdW1, rdW2, rdW3, srW1, srW2, srW3, wpack3);
  pack_emb_weights<<<32, 256, 0, stream>>>(ne_emb_W, wpackE);

  feat_mfma<1><<<gEr, 192, 0, stream>>>(E, atom_types, env_len, env_vec, env_idx, bessel_w,
      wpack3, srb1, srb2, srb3, rdb1, rdb2, rdb3,
      ne_eln_g, ne_eln_b, env_radial, ud_env, msgbuf);
  feat_mfma<0><<<gE2r, 192, 0, stream>>>(E2, atom_types, edge_len, nullptr, edge_idx, bessel_w,
      wpack3, srb1, srb2, srb3, rdb1, rdb2, rdb3,
      ne_eln_g, ne_eln_b, edge_radial, ud_edge, nullptr);

  msg_gather_kernel<<<gN4w, 256, 0, stream>>>(N, eoff, perm, msgbuf, aggS);
  node_emb_kernel<<<N, 128, 0, stream>>>(N, aggS, ecnt, ne_nln_g, ne_nln_b, node_emb);

  emb_mfma<<<gEr, 192, 0, stream>>>(E, env_radial, wpackE, ne_emb_b, env_idx, node_emb, env_hidden);
  emb_mfma<<<gE2r, 192, 0, stream>>>(E2, edge_radial, wpackE, ne_emb_b, edge_idx, node_emb, edge_hidden);

  for (int l = 0; l < 2; ++l) {
    agg_gather_kernel<<<gN4w, 256, 0, stream>>>(N, eoff, perm, env_radial, mean_r);
    node_update_gemm<<<gN32, 256, 0, stream>>>(N, mean_r, ecnt,
        ly_emb_W + (size_t)l*64*128, ly_emb_b + (size_t)l*128,
        ly_nln_g + (size_t)l*128, ly_nln_b + (size_t)l*128, node_emb);

    hidrdl_mfma<<<gEf, 256, 0, stream>>>(E, env_idx, node_emb, ud_env,
        wpack + (size_t)l*65536,
        ly_hid_b1 + (size_t)l*128, ly_hid_b2 + (size_t)l*128, ly_hid_b3 + (size_t)l*128,
        wpack2 + (size_t)l*20480,
        ly_rdl_b1 + (size_t)l*64, ly_rdl_b2 + (size_t)l*64, ly_rdl_b3 + (size_t)l*64,
        ly_eln_g + (size_t)l*64, ly_eln_b + (size_t)l*64,
        env_hidden, env_radial);
    hidrdl_mfma<<<gE2f, 256, 0, stream>>>(E2, edge_idx, node_emb, ud_edge,
        wpack + (size_t)l*65536,
        ly_hid_b1 + (size_t)l*128, ly_hid_b2 + (size_t)l*128, ly_hid_b3 + (size_t)l*128,
        wpack2 + (size_t)l*20480,
        ly_rdl_b1 + (size_t)l*64, ly_rdl_b2 + (size_t)l*64, ly_rdl_b3 + (size_t)l*64,
        ly_eln_g + (size_t)l*64, ly_eln_b + (size_t)l*64,
        edge_hidden, edge_radial);
  }
}

// Round 8
// 1311.869 us; speedup vs baseline: 5.7618x; 1.0096x over previous
//
#include <hip/hip_runtime.h>
#include <math.h>

#define C_RES 0.89442719f
#define C_NEW 0.4472f
#define LN_EPS 1e-5f
#define BESSEL_PREF 0.6324555320336759f  // sqrt(2/5)
#define RC_INV 0.2f

typedef __attribute__((ext_vector_type(8))) short short8;
typedef __attribute__((ext_vector_type(8))) unsigned short u16x8;
typedef __attribute__((ext_vector_type(16))) float f32x16;

__device__ __forceinline__ float fast_tanh(float x) {
  float ax = fabsf(x);
  float e = __expf(2.0f * ax);
  float t = 1.0f - 2.0f / (e + 1.0f);
  return copysignf(t, x);
}

__device__ __forceinline__ unsigned short f2b(float f) {
  unsigned int u = __float_as_uint(f);
  unsigned int r = (u + 0x7FFFu + ((u >> 16) & 1u)) >> 16;
  return (unsigned short)r;
}

__device__ __forceinline__ u16x8 cvt8(const float* s) {
  const float4 v0 = *(const float4*)s;
  const float4 v1 = *(const float4*)(s + 4);
  u16x8 w;
  w[0]=f2b(v0.x); w[1]=f2b(v0.y); w[2]=f2b(v0.z); w[3]=f2b(v0.w);
  w[4]=f2b(v1.x); w[5]=f2b(v1.y); w[6]=f2b(v1.z); w[7]=f2b(v1.w);
  return w;
}

__device__ __forceinline__ short8 cvt8s(const float* s) {
  const float4 v0 = *(const float4*)s;
  const float4 v1 = *(const float4*)(s + 4);
  short8 w;
  w[0]=(short)f2b(v0.x); w[1]=(short)f2b(v0.y); w[2]=(short)f2b(v0.z); w[3]=(short)f2b(v0.w);
  w[4]=(short)f2b(v1.x); w[5]=(short)f2b(v1.y); w[6]=(short)f2b(v1.z); w[7]=(short)f2b(v1.w);
  return w;
}

__device__ __forceinline__ float poly_cutoff(float x) {
  float xr = x * RC_INV;
  if (xr >= 1.0f) return 0.0f;
  float x2 = xr * xr;
  float x3 = x2 * xr;
  float x6 = x3 * x3;
  return 1.0f - 28.0f * x6 + 48.0f * x6 * xr - 21.0f * x6 * x2;
}

// A-frag slot swizzle: spreads the strided aliasing of the C/D->A scatter
// writes across banks; reads stay a permutation (conflict-free).
__device__ __forceinline__ int swz(int s, int kc) {
  return s ^ ((s >> 5) << 1) ^ ((kc & 1) << 2);
}

__global__ void zero_int_kernel(int* __restrict__ p, int n) {
  int i = blockIdx.x * blockDim.x + threadIdx.x;
  int stride = gridDim.x * blockDim.x;
  for (; i < n; i += stride) p[i] = 0;
}

// ---------------- CSR build: hist -> scan -> scatter --------------------------

__global__ void hist_kernel(int E, const int* __restrict__ idx, int* __restrict__ ecnt) {
  int t = blockIdx.x * 256 + threadIdx.x;
  if (t < E) atomicAdd(&ecnt[idx[E + t]], 1);
}

__launch_bounds__(1024)
__global__ void scan_kernel(const int* __restrict__ ecnt, int* __restrict__ eoff,
                            int* __restrict__ ecur, int n) {
  __shared__ int wsum[16];
  __shared__ int carry;
  const int tid = threadIdx.x;
  const int lane = tid & 63, wid = tid >> 6;
  if (tid == 0) carry = 0;
  __syncthreads();
  for (int b0 = 0; b0 < n; b0 += 1024) {
    const int i = b0 + tid;
    const int v = (i < n) ? ecnt[i] : 0;
    int incl = v;
    #pragma unroll
    for (int o = 1; o < 64; o <<= 1) {
      const int t = __shfl_up(incl, o);
      if (lane >= o) incl += t;
    }
    if (lane == 63) wsum[wid] = incl;
    __syncthreads();
    if (wid == 0) {
      const int wv = (lane < 16) ? wsum[lane] : 0;
      int wsc = wv;
      #pragma unroll
      for (int o = 1; o < 16; o <<= 1) {
        const int t = __shfl_up(wsc, o);
        if (lane >= o) wsc += t;
      }
      if (lane < 16) wsum[lane] = wsc - wv;  // exclusive
    }
    __syncthreads();
    const int c0 = carry;
    const int excl = c0 + wsum[wid] + incl - v;
    if (i < n) { eoff[i] = excl; ecur[i] = excl; }
    __syncthreads();
    if (tid == 1023) carry = c0 + wsum[15] + incl;
    __syncthreads();
  }
  if (tid == 0) eoff[n] = carry;
}

__global__ void scatter_kernel(int E, const int* __restrict__ idx,
                               int* __restrict__ ecur, int* __restrict__ perm) {
  int t = blockIdx.x * 256 + threadIdx.x;
  if (t < E) {
    const int pos = atomicAdd(&ecur[idx[E + t]], 1);
    perm[pos] = t;
  }
}

// ---------------- pack hidden-MLP weights into bf16 MFMA B-fragment order ----
__global__ void pack_hid_weights(const float* __restrict__ W1,
                                 const float* __restrict__ W2,
                                 const float* __restrict__ W3,
                                 unsigned short* __restrict__ out)
{
  int t = blockIdx.x * 256 + threadIdx.x;  // 0..131071
  if (t >= 131072) return;
  int l = t >> 16;
  int oidx = t & 65535;
  const float* src;
  int midx;
  if (oidx < 32768)      { src = W1 + l * 32768; midx = oidx; }
  else if (oidx < 49152) { src = W2 + l * 16384; midx = oidx - 32768; }
  else                   { src = W3 + l * 16384; midx = oidx - 49152; }
  int j = midx & 7;
  int lane = (midx >> 3) & 63;
  int blk = midx >> 9;
  int ct = blk & 3, kc = blk >> 2;
  int col = ct * 32 + (lane & 31);
  int k = kc * 16 + (lane >> 5) * 8 + j;
  out[l * 65536 + oidx] = f2b(src[k * 128 + col]);
}

// ---------------- pack radial-ResNet weights, N=64 (ct in 0..1) --------------
__global__ void pack_rdl_weights(const float* __restrict__ W1,
                                 const float* __restrict__ W2,
                                 const float* __restrict__ W3,
                                 unsigned short* __restrict__ out)
{
  int t = blockIdx.x * 256 + threadIdx.x;  // 0..40959
  if (t >= 40960) return;
  int l = t / 20480;
  int o = t - l * 20480;
  const float* src;
  int midx;
  if (o < 12288)      { src = W1 + l * 12288; midx = o; }
  else if (o < 16384) { src = W2 + l * 4096;  midx = o - 12288; }
  else                { src = W3 + l * 4096;  midx = o - 16384; }
  int j = midx & 7;
  int lane = (midx >> 3) & 63;
  int blk = midx >> 9;
  int ct = blk & 1, kc = blk >> 1;
  int col = ct * 32 + (lane & 31);
  int k = kc * 16 + (lane >> 5) * 8 + j;
  out[l * 20480 + o] = f2b(src[k * 64 + col]);
}

// ---------------- pack feature-MLP weights (rd + sr), 36 blocks --------------
__global__ void pack_feat_weights(const float* __restrict__ rdW1,
                                  const float* __restrict__ rdW2,
                                  const float* __restrict__ rdW3,
                                  const float* __restrict__ srW1,
                                  const float* __restrict__ srW2,
                                  const float* __restrict__ srW3,
                                  unsigned short* __restrict__ out)
{
  int t = blockIdx.x * 256 + threadIdx.x;  // 0..18431
  if (t >= 18432) return;
  const int blk = t >> 9, midx = t & 511;
  const int j = midx & 7, lane = (midx >> 3) & 63;
  const float* src; int kc, ct, K, NC;
  if (blk < 4)       { int b = blk;      src = rdW1; kc = b>>1; ct = b&1; K = 24; NC = 64; }
  else if (blk < 12) { int b = blk - 4;  src = rdW2; kc = b>>1; ct = b&1; K = 64; NC = 64; }
  else if (blk < 20) { int b = blk - 12; src = rdW3; kc = b>>1; ct = b&1; K = 64; NC = 64; }
  else if (blk < 24) { int b = blk - 20; src = srW1; kc = b>>1; ct = b&1; K = 24; NC = 64; }
  else if (blk < 32) { int b = blk - 24; src = srW2; kc = b>>1; ct = b&1; K = 64; NC = 64; }
  else               { int b = blk - 32; src = srW3; kc = b;    ct = 0;   K = 64; NC = 16; }
  const int col = ct * 32 + (lane & 31);
  const int k = kc * 16 + (lane >> 5) * 8 + j;
  const float v = (k < K && col < NC) ? src[k * NC + col] : 0.0f;
  out[t] = f2b(v);
}

// ---------------- pack embedding weights 64x128, 16 blocks -------------------
__global__ void pack_emb_weights(const float* __restrict__ W,
                                 unsigned short* __restrict__ out)
{
  int t = blockIdx.x * 256 + threadIdx.x;  // 0..8191
  if (t >= 8192) return;
  const int j = t & 7, lane = (t >> 3) & 63, blk = t >> 9;
  const int ct = blk & 3, kc = blk >> 2;
  const int col = ct * 32 + (lane & 31);
  const int k = kc * 16 + (lane >> 5) * 8 + j;
  out[t] = f2b(W[k * 128 + col]);
}

// ---------------- stage-A via bf16 MFMA --------------------------------------
// 96 rows/block, 192 threads (3 waves), one barrier.

#define FEAT_TRANS(BASEBLK, V0, V1) do {                                        \
    _Pragma("unroll")                                                           \
    for (int ct_ = 0; ct_ < 2; ++ct_) {                                         \
      const int colh_ = ct_*32 + cl;                                            \
      const int kc2_  = colh_ >> 4;                                             \
      const int b3_   = (colh_ >> 3) & 1;                                       \
      const int jj_   = colh_ & 7;                                              \
      const int blk_  = ((BASEBLK) + kc2_*3 + wave)*512;                        \
      _Pragma("unroll")                                                         \
      for (int q_ = 0; q_ < 16; ++q_) {                                         \
        const int row32_ = (q_ & 3) + 8*(q_ >> 2) + 4*(lane >> 5);              \
        const int s2_ = (row32_ & 31) + 32*b3_;                                 \
        const float v_ = ct_ ? (V1)[q_] : (V0)[q_];                             \
        afrag[blk_ + swz(s2_, kc2_)*8 + jj_] = f2b(fast_tanh(v_));              \
      }                                                                         \
    }                                                                           \
  } while (0)

template<int HAS_SR>
__launch_bounds__(192)
__global__ void feat_mfma(
    int nrows,
    const int* __restrict__ types, const float* __restrict__ lens,
    const float* __restrict__ vecs, const int* __restrict__ idx,
    const float* __restrict__ bessel_w,
    const unsigned short* __restrict__ wpackf,
    const float* __restrict__ srb1, const float* __restrict__ srb2,
    const float* __restrict__ srb3,
    const float* __restrict__ rdb1, const float* __restrict__ rdb2,
    const float* __restrict__ rdb3,
    const float* __restrict__ eln_g, const float* __restrict__ eln_b,
    float* __restrict__ radial_out, float* __restrict__ ud_out,
    float* __restrict__ msgbuf)
{
  __shared__ __align__(16) unsigned short afrag[30*512];  // 30KB
  __shared__ __align__(16) unsigned short wlds[36*512];   // 36KB
  __shared__ float udl[96];

  const int tid  = threadIdx.x;    // 0..191
  const int lane = tid & 63;
  const int wave = tid >> 6;
  const int base = blockIdx.x * 96;
  const int cl   = lane & 31;

  for (int i = tid; i < 2304; i += 192)
    *(u16x8*)&wlds[i*8] = *(const u16x8*)&wpackf[i*8];

  {
    const int r = tid >> 1, h = tid & 1;
    int rowc = base + r;
    const bool valid = rowc < nrows;
    if (!valid) rowc = nrows - 1;
    const int i0 = idx[rowc];
    const int i1 = idx[nrows + rowc];
    const float len = lens[rowc];
    const float ud = poly_cutoff(len);
    const int t0 = types[i0], t1 = types[i1];
    const float invl = 1.0f / len;
    const int rt = r >> 5;
    #pragma unroll
    for (int m = 0; m < 12; ++m) {
      const int k = h + m*2;
      float v;
      if (k < 4)      v = (t0 == k) ? 1.0f : 0.0f;
      else if (k < 8) v = (t1 == (k-4)) ? 1.0f : 0.0f;
      else            v = ud * BESSEL_PREF * __sinf(bessel_w[k-8] * len * RC_INV) * invl;
      const int kc = k >> 4;
      const int s_ = (r & 31) + 32*((k >> 3) & 1);
      afrag[(kc*3 + rt)*512 + swz(s_, kc)*8 + (k & 7)] = f2b(v);
    }
    #pragma unroll
    for (int m = 0; m < 4; ++m) {
      const int k = 24 + h + m*2;
      const int s_ = (r & 31) + 32*((k >> 3) & 1);
      afrag[(1*3 + rt)*512 + swz(s_, 1)*8 + (k & 7)] = 0;
    }
    if (h == 0) {
      udl[r] = ud;
      if (valid) {
        ud_out[rowc] = ud;
        if (HAS_SR) {
          msgbuf[(size_t)rowc*20 + 16] = ud * vecs[(size_t)rowc*3 + 0];
          msgbuf[(size_t)rowc*20 + 17] = ud * vecs[(size_t)rowc*3 + 1];
          msgbuf[(size_t)rowc*20 + 18] = ud * vecs[(size_t)rowc*3 + 2];
        }
      }
    }
  }
  __syncthreads();

  f32x16 acc0, acc1;

  // ======== rd path ========
  {
    const float bv0 = rdb1[cl], bv1 = rdb1[32 + cl];
    #pragma unroll
    for (int q = 0; q < 16; ++q) { acc0[q] = bv0; acc1[q] = bv1; }
  }
  #pragma unroll
  for (int kc = 0; kc < 2; ++kc) {
    const short8 a  = *(const short8*)&afrag[(kc*3 + wave)*512 + swz(lane, kc)*8];
    const short8 w0 = *(const short8*)&wlds[(kc*2 + 0)*512 + lane*8];
    const short8 w1 = *(const short8*)&wlds[(kc*2 + 1)*512 + lane*8];
    acc0 = __builtin_amdgcn_mfma_f32_32x32x16_bf16(a, w0, acc0, 0, 0, 0);
    acc1 = __builtin_amdgcn_mfma_f32_32x32x16_bf16(a, w1, acc1, 0, 0, 0);
  }
  FEAT_TRANS(6, acc0, acc1);

  {
    const float bv0 = rdb2[cl], bv1 = rdb2[32 + cl];
    #pragma unroll
    for (int q = 0; q < 16; ++q) { acc0[q] = bv0; acc1[q] = bv1; }
  }
  #pragma unroll
  for (int kc = 0; kc < 4; ++kc) {
    const short8 a  = *(const short8*)&afrag[((6 + kc*3) + wave)*512 + swz(lane, kc)*8];
    const short8 w0 = *(const short8*)&wlds[(4 + kc*2 + 0)*512 + lane*8];
    const short8 w1 = *(const short8*)&wlds[(4 + kc*2 + 1)*512 + lane*8];
    acc0 = __builtin_amdgcn_mfma_f32_32x32x16_bf16(a, w0, acc0, 0, 0, 0);
    acc1 = __builtin_amdgcn_mfma_f32_32x32x16_bf16(a, w1, acc1, 0, 0, 0);
  }
  FEAT_TRANS(18, acc0, acc1);

  {
    const float bv0 = rdb3[cl], bv1 = rdb3[32 + cl];
    #pragma unroll
    for (int q = 0; q < 16; ++q) { acc0[q] = bv0; acc1[q] = bv1; }
  }
  #pragma unroll
  for (int kc = 0; kc < 4; ++kc) {
    const short8 a  = *(const short8*)&afrag[((18 + kc*3) + wave)*512 + swz(lane, kc)*8];
    const short8 w0 = *(const short8*)&wlds[(12 + kc*2 + 0)*512 + lane*8];
    const short8 w1 = *(const short8*)&wlds[(12 + kc*2 + 1)*512 + lane*8];
    acc0 = __builtin_amdgcn_mfma_f32_32x32x16_bf16(a, w0, acc0, 0, 0, 0);
    acc1 = __builtin_amdgcn_mfma_f32_32x32x16_bf16(a, w1, acc1, 0, 0, 0);
  }
  {
    const float eg0 = eln_g[cl],      eb0 = eln_b[cl];
    const float eg1 = eln_g[32 + cl], eb1 = eln_b[32 + cl];
    #pragma unroll
    for (int q = 0; q < 16; ++q) {
      const float v0 = acc0[q], v1 = acc1[q];
      float s = v0 + v1, ss = v0*v0 + v1*v1;
      #pragma unroll
      for (int o = 1; o <= 16; o <<= 1) {
        s  += __shfl_xor(s, o);
        ss += __shfl_xor(ss, o);
      }
      const float m   = s * (1.0f/64.0f);
      const float inv = rsqrtf(ss * (1.0f/64.0f) - m*m + LN_EPS);
      const int row32 = (q & 3) + 8*(q >> 2) + 4*(lane >> 5);
      const int rloc  = wave*32 + row32;
      const int row   = base + rloc;
      if (row < nrows) {
        const float u = udl[rloc];
        radial_out[(size_t)row*64 + cl]      = ((v0 - m)*inv*eg0 + eb0) * u;
        radial_out[(size_t)row*64 + 32 + cl] = ((v1 - m)*inv*eg1 + eb1) * u;
      }
    }
  }

  // ======== sr path ========
  if (HAS_SR) {
    {
      const float bv0 = srb1[cl], bv1 = srb1[32 + cl];
      #pragma unroll
      for (int q = 0; q < 16; ++q) { acc0[q] = bv0; acc1[q] = bv1; }
    }
    #pragma unroll
    for (int kc = 0; kc < 2; ++kc) {
      const short8 a  = *(const short8*)&afrag[(kc*3 + wave)*512 + swz(lane, kc)*8];
      const short8 w0 = *(const short8*)&wlds[(20 + kc*2 + 0)*512 + lane*8];
      const short8 w1 = *(const short8*)&wlds[(20 + kc*2 + 1)*512 + lane*8];
      acc0 = __builtin_amdgcn_mfma_f32_32x32x16_bf16(a, w0, acc0, 0, 0, 0);
      acc1 = __builtin_amdgcn_mfma_f32_32x32x16_bf16(a, w1, acc1, 0, 0, 0);
    }
    FEAT_TRANS(6, acc0, acc1);

    {
      const float bv0 = srb2[cl], bv1 = srb2[32 + cl];
      #pragma unroll
      for (int q = 0; q < 16; ++q) { acc0[q] = bv0; acc1[q] = bv1; }
    }
    #pragma unroll
    for (int kc = 0; kc < 4; ++kc) {
      const short8 a  = *(const short8*)&afrag[((6 + kc*3) + wave)*512 + swz(lane, kc)*8];
      const short8 w0 = *(const short8*)&wlds[(24 + kc*2 + 0)*512 + lane*8];
      const short8 w1 = *(const short8*)&wlds[(24 + kc*2 + 1)*512 + lane*8];
      acc0 = __builtin_amdgcn_mfma_f32_32x32x16_bf16(a, w0, acc0, 0, 0, 0);
      acc1 = __builtin_amdgcn_mfma_f32_32x32x16_bf16(a, w1, acc1, 0, 0, 0);
    }
    FEAT_TRANS(18, acc0, acc1);

    {
      const float bv0 = (cl < 16) ? srb3[cl] : 0.0f;
      #pragma unroll
      for (int q = 0; q < 16; ++q) acc0[q] = bv0;
    }
    #pragma unroll
    for (int kc = 0; kc < 4; ++kc) {
      const short8 a  = *(const short8*)&afrag[((18 + kc*3) + wave)*512 + swz(lane, kc)*8];
      const short8 w0 = *(const short8*)&wlds[(32 + kc)*512 + lane*8];
      acc0 = __builtin_amdgcn_mfma_f32_32x32x16_bf16(a, w0, acc0, 0, 0, 0);
    }
    if (cl < 16) {
      #pragma unroll
      for (int q = 0; q < 16; ++q) {
        const int row32 = (q & 3) + 8*(q >> 2) + 4*(lane >> 5);
        const int rloc  = wave*32 + row32;
        const int row   = base + rloc;
        if (row < nrows) msgbuf[(size_t)row*20 + cl] = acc0[q] * udl[rloc];
      }
    }
  }
}

// ---------------- SE(2) message gather: aggS (no atomics) --------------------

__launch_bounds__(256)
__global__ void msg_gather_kernel(int N, const int* __restrict__ eoff,
                                  const int* __restrict__ perm,
                                  const float* __restrict__ msgbuf,
                                  float* __restrict__ aggS)
{
  const int w = (blockIdx.x * 256 + threadIdx.x) >> 6;
  const int lane = threadIdx.x & 63;
  if (w >= N) return;
  const int s = eoff[w], e = eoff[w + 1];
  const int d = lane / 3, c = lane - d * 3;
  float acc = 0.0f;
  for (int j = s; j < e; ++j) {
    const int ed = perm[j];
    if (lane < 48)
      acc += msgbuf[(size_t)ed*20 + d] * msgbuf[(size_t)ed*20 + 16 + c];
  }
  if (lane < 48) aggS[(size_t)w*48 + lane] = acc;
}

// ---------------- node embedding (gram + LN) ---------------------------------

__device__ __forceinline__ void block128_stats(float x, float& m, float& inv, float* red) {
  float s = x, ss = x*x;
  #pragma unroll
  for (int o = 32; o; o >>= 1) { s += __shfl_down(s, o); ss += __shfl_down(ss, o); }
  const int t = threadIdx.x;
  if ((t & 63) == 0) { red[(t >> 6)*2] = s; red[(t >> 6)*2 + 1] = ss; }
  __syncthreads();
  const float S = red[0] + red[2], SS = red[1] + red[3];
  m = S * (1.0f/128.0f);
  const float var = SS * (1.0f/128.0f) - m*m;
  inv = rsqrtf(var + LN_EPS);
}

__launch_bounds__(128)
__global__ void node_emb_kernel(int N, const float* __restrict__ aggS,
                                const int* __restrict__ ecnt,
                                const float* __restrict__ g, const float* __restrict__ b,
                                float* __restrict__ node_emb)
{
  const int n = blockIdx.x, t = threadIdx.x;
  __shared__ float S[48];
  __shared__ float red[4];
  if (t < 48) S[t] = aggS[(size_t)n*48 + t];
  __syncthreads();
  const float ic = 1.0f / fmaxf((float)ecnt[n], 1.0f);
  const int d = t >> 3, e = t & 7;
  const float x = (S[d*3+0]*S[e*3+0] + S[d*3+1]*S[e*3+1] + S[d*3+2]*S[e*3+2]) * ic * ic;
  float m, inv;
  block128_stats(x, m, inv, red);
  node_emb[(size_t)n*128 + t] = (x - m)*inv*g[t] + b[t];
}

// ---------------- per-layer aggregation: CSR gather (no atomics) -------------

__launch_bounds__(256)
__global__ void agg_gather_kernel(int N, const int* __restrict__ eoff,
                                  const int* __restrict__ perm,
                                  const float* __restrict__ radial,
                                  float* __restrict__ mean_r)
{
  const int w = (blockIdx.x * 256 + threadIdx.x) >> 6;
  const int lane = threadIdx.x & 63;
  if (w >= N) return;
  const int s = eoff[w], e = eoff[w + 1];
  float acc = 0.0f;
  for (int j = s; j < e; ++j) {
    const int ed = perm[j];
    acc += radial[(size_t)ed * 64 + lane];
  }
  const float inv = 1.0f / fmaxf((float)(e - s), 1.0f);
  mean_r[(size_t)w * 64 + lane] = acc * inv;
}

// ---------------- node update: (mean_r @ W + b) * old, LN, residual ----------

__launch_bounds__(256)
__global__ void node_update_gemm(
    int N, const float* __restrict__ mean_r, const int* __restrict__ ecnt,
    const float* __restrict__ W, const float* __restrict__ bias,
    const float* __restrict__ g, const float* __restrict__ b,
    float* __restrict__ node_emb)
{
  __shared__ __align__(16) float lw[64*128];
  __shared__ float lm[32][65];
  const int tid = threadIdx.x;
  const int base = blockIdx.x * 32;

  for (int i = tid; i < 8192; i += 256) lw[i] = W[i];
  {
    const int rr0 = tid >> 6, k = tid & 63;
    for (int rr = rr0; rr < 32; rr += 4) {
      const int n = base + rr;
      lm[rr][k] = (n < N) ? mean_r[(size_t)n*64 + k] : 0.0f;
    }
  }
  __syncthreads();

  const int r0 = (tid >> 5) * 4, j0 = (tid & 31) * 4;
  float acc[4][4];
  #pragma unroll
  for (int j = 0; j < 4; ++j) {
    const float bj = bias[j0 + j];
    acc[0][j] = bj; acc[1][j] = bj; acc[2][j] = bj; acc[3][j] = bj;
  }
  for (int k = 0; k < 64; ++k) {
    const float4 w = *(const float4*)&lw[k*128 + j0];
    const float s0 = lm[r0][k],   s1 = lm[r0+1][k];
    const float s2 = lm[r0+2][k], s3 = lm[r0+3][k];
    acc[0][0] += s0*w.x; acc[0][1] += s0*w.y; acc[0][2] += s0*w.z; acc[0][3] += s0*w.w;
    acc[1][0] += s1*w.x; acc[1][1] += s1*w.y; acc[1][2] += s1*w.z; acc[1][3] += s1*w.w;
    acc[2][0] += s2*w.x; acc[2][1] += s2*w.y; acc[2][2] += s2*w.z; acc[2][3] += s2*w.w;
    acc[3][0] += s3*w.x; acc[3][1] += s3*w.y; acc[3][2] += s3*w.z; acc[3][3] += s3*w.w;
  }

  const float g0 = g[j0], g1 = g[j0+1], g2 = g[j0+2], g3 = g[j0+3];
  const float bb0 = b[j0], bb1 = b[j0+1], bb2 = b[j0+2], bb3 = b[j0+3];
  #pragma unroll
  for (int i = 0; i < 4; ++i) {
    const int n = base + r0 + i;
    if (n >= N) continue;
    const float mask = (ecnt[n] > 0) ? 1.0f : 0.0f;
    const float4 old = *(const float4*)&node_emb[(size_t)n*128 + j0];
    const float x0 = old.x * acc[i][0] * mask;
    const float x1 = old.y * acc[i][1] * mask;
    const float x2 = old.z * acc[i][2] * mask;
    const float x3 = old.w * acc[i][3] * mask;
    float s = x0 + x1 + x2 + x3;
    float ss = x0*x0 + x1*x1 + x2*x2 + x3*x3;
    #pragma unroll
    for (int o = 1; o <= 16; o <<= 1) {
      s  += __shfl_xor(s, o);
      ss += __shfl_xor(ss, o);
    }
    const float m = s * (1.0f/128.0f);
    const float inv = rsqrtf(ss * (1.0f/128.0f) - m*m + LN_EPS);
    float4 o4;
    o4.x = C_RES*old.x + C_NEW*((x0 - m)*inv*g0 + bb0);
    o4.y = C_RES*old.y + C_NEW*((x1 - m)*inv*g1 + bb1);
    o4.z = C_RES*old.z + C_NEW*((x2 - m)*inv*g2 + bb2);
    o4.w = C_RES*old.w + C_NEW*((x3 - m)*inv*g3 + bb3);
    *(float4*)&node_emb[(size_t)n*128 + j0] = o4;
  }
}

// ---------------- embedding GEMM via MFMA ------------------------------------

__launch_bounds__(192)
__global__ void emb_mfma(
    int nrows,
    const float* __restrict__ radial,
    const unsigned short* __restrict__ wpck, const float* __restrict__ bias,
    const int* __restrict__ idx,
    const float* __restrict__ node_emb,
    float* __restrict__ out)
{
  __shared__ __align__(16) unsigned short afrag[12*512];  // 12KB
  __shared__ __align__(16) unsigned short wlds[16*512];   // 16KB
  __shared__ int i0l[96], i1l[96];

  const int tid = threadIdx.x, lane = tid & 63, wave = tid >> 6;
  const int base = blockIdx.x * 96, cl = lane & 31;

  for (int i = tid; i < 1024; i += 192)
    *(u16x8*)&wlds[i*8] = *(const u16x8*)&wpck[i*8];

  {
    const int r = tid >> 1, h = tid & 1;
    int rowg = base + r;
    if (rowg >= nrows) rowg = nrows - 1;
    if (h == 0) { i0l[r] = idx[rowg]; i1l[r] = idx[nrows + rowg]; }
    const float* rsrc = radial + (size_t)rowg * 64;
    #pragma unroll
    for (int g = 0; g < 4; ++g) {
      const int k = h*32 + g*8;
      const u16x8 w = cvt8(rsrc + k);
      const int kc = k >> 4;
      const int s_ = (r & 31) + 32*((k >> 3) & 1);
      *(u16x8*)&afrag[(kc*3 + (r>>5))*512 + swz(s_, kc)*8] = w;
    }
  }
  __syncthreads();

  f32x16 acc0, acc1, acc2, acc3;
  {
    const float bv0 = bias[cl], bv1 = bias[32+cl];
    const float bv2 = bias[64+cl], bv3 = bias[96+cl];
    #pragma unroll
    for (int q = 0; q < 16; ++q) { acc0[q]=bv0; acc1[q]=bv1; acc2[q]=bv2; acc3[q]=bv3; }
  }
  #pragma unroll
  for (int kc = 0; kc < 4; ++kc) {
    const short8 a  = *(const short8*)&afrag[(kc*3 + wave)*512 + swz(lane, kc)*8];
    const short8 w0 = *(const short8*)&wlds[(kc*4 + 0)*512 + lane*8];
    const short8 w1 = *(const short8*)&wlds[(kc*4 + 1)*512 + lane*8];
    const short8 w2 = *(const short8*)&wlds[(kc*4 + 2)*512 + lane*8];
    const short8 w3 = *(const short8*)&wlds[(kc*4 + 3)*512 + lane*8];
    acc0 = __builtin_amdgcn_mfma_f32_32x32x16_bf16(a, w0, acc0, 0, 0, 0);
    acc1 = __builtin_amdgcn_mfma_f32_32x32x16_bf16(a, w1, acc1, 0, 0, 0);
    acc2 = __builtin_amdgcn_mfma_f32_32x32x16_bf16(a, w2, acc2, 0, 0, 0);
    acc3 = __builtin_amdgcn_mfma_f32_32x32x16_bf16(a, w3, acc3, 0, 0, 0);
  }

  #pragma unroll
  for (int q = 0; q < 16; ++q) {
    const int row32 = (q & 3) + 8*(q >> 2) + 4*(lane >> 5);
    const int rloc  = wave*32 + row32;
    const int row   = base + rloc;
    if (row >= nrows) continue;
    const float* n0 = node_emb + (size_t)i0l[rloc]*128;
    const float* n1 = node_emb + (size_t)i1l[rloc]*128;
    float* op = out + (size_t)row*128;
    op[cl]    = acc0[q] * 0.5f * (n0[cl]    + n1[cl]);
    op[32+cl] = acc1[q] * 0.5f * (n0[32+cl] + n1[32+cl]);
    op[64+cl] = acc2[q] * 0.5f * (n0[64+cl] + n1[64+cl]);
    op[96+cl] = acc3[q] * 0.5f * (n0[96+cl] + n1[96+cl]);
  }
}

// ---------------- FUSED hidden-MLP + radial-ResNet per layer -----------------
// 128 rows/block, 256 threads (4 waves, wave = row-tile). A-operands for
// node_emb / hidden_prev / radial come straight from per-lane global loads
// (converted in-register); LDS holds only cross-lane transition fragments
// (afragH 32KB) + double-buffered weights (wg 2x8KB) -> 48KB, 3 blocks/CU,
// one barrier per weight phase (21 total).

#define STAGE_WG(SRC, OFFU16, B) do {                                           \
    _Pragma("unroll")                                                           \
    for (int i_ = 0; i_ < 2; ++i_) {                                            \
      const int c_ = tid + i_*256;                                              \
      *(u16x8*)&wg[B][c_*8] = *(const u16x8*)&(SRC)[(OFFU16) + c_*8];           \
    }                                                                           \
  } while (0)

__launch_bounds__(256, 3)
__global__ void hidrdl_mfma(
    int nrows, const int* __restrict__ idx0,
    const float* __restrict__ node_emb,
    const float* __restrict__ ud,
    const unsigned short* __restrict__ wpackh,  // hid: 65536 u16 this layer
    const float* __restrict__ hb1, const float* __restrict__ hb2,
    const float* __restrict__ hb3,
    const unsigned short* __restrict__ wpackr,  // rdl: 20480 u16 this layer
    const float* __restrict__ rb1, const float* __restrict__ rb2,
    const float* __restrict__ rb3,
    const float* __restrict__ eln_g, const float* __restrict__ eln_b,
    float* __restrict__ hidden,    // in: hidden_prev, out: hidden_new
    float* __restrict__ radial)    // in: radial_prev, out: radial_new
{
  __shared__ __align__(16) unsigned short afragH[16384];  // 32KB: (wave*8+kc)*512
  __shared__ __align__(16) unsigned short wg[2][4096];    // 16KB

  const int tid  = threadIdx.x;
  const int lane = tid & 63;
  const int wave = tid >> 6;       // rt 0..3
  const int base = blockIdx.x * 128;
  const int cl   = lane & 31;
  const int khalf = lane >> 5;

  int lrow = base + wave*32 + cl;
  if (lrow >= nrows) lrow = nrows - 1;
  const int i0 = idx0[lrow];
  const float* nsrc = node_emb + (size_t)i0 * 128;
  const float* hsrc = hidden + (size_t)lrow * 128;
  const float* rsrc = radial + (size_t)lrow * 64;

  // per-lane A fragments: lane holds row (lane&31), k-half (lane>>5)
  short8 aN[8], aH[8];
  #pragma unroll
  for (int kc = 0; kc < 8; ++kc) aN[kc] = cvt8s(nsrc + kc*16 + khalf*8);
  #pragma unroll
  for (int kc = 0; kc < 8; ++kc) aH[kc] = cvt8s(hsrc + kc*16 + khalf*8);

  f32x16 acc[4];

  // ========= hid layer 1: K=256, phases 0..7 =========
  #pragma unroll
  for (int ct = 0; ct < 4; ++ct) {
    const float bv = hb1[ct*32 + cl];
    #pragma unroll
    for (int q = 0; q < 16; ++q) acc[ct][q] = bv;
  }
  STAGE_WG(wpackh, 0, 0);
  __syncthreads();
  #pragma unroll
  for (int p = 0; p < 8; ++p) {
    if (p < 7) STAGE_WG(wpackh, (p+1)*4096, (p+1)&1);
    else       STAGE_WG(wpackh, 32768, 0);
    #pragma unroll
    for (int kcl = 0; kcl < 2; ++kcl) {
      const int kc = p*2 + kcl;
      const short8 a = (kc < 8) ? aN[kc] : aH[kc-8];
      #pragma unroll
      for (int ct = 0; ct < 4; ++ct) {
        const short8 b = *(const short8*)&wg[p&1][ (kcl*4 + ct)*512 + lane*8 ];
        acc[ct] = __builtin_amdgcn_mfma_f32_32x32x16_bf16(a, b, acc[ct], 0, 0, 0);
      }
    }
    __syncthreads();
  }

  // ---- transition 1 (wave-local, tanh) -> afragH ----
  #pragma unroll
  for (int ct = 0; ct < 4; ++ct) {
    const int kc  = ct*2 + ((lane >> 4) & 1);
    const int oct = (lane >> 3) & 1;
    const int j   = lane & 7;
    const int xk  = (oct << 1) ^ ((kc & 1) << 2);
    const int hi  = 4*(lane >> 5);
    const int bi  = (wave*8 + kc)*512 + oct*256 + j;
    #pragma unroll
    for (int q = 0; q < 16; ++q) {
      const int m32 = (q & 3) + 8*(q >> 2) + hi;
      afragH[bi + (m32 ^ xk)*8] = f2b(fast_tanh(acc[ct][q]));
    }
  }

  // ========= hid layer 2: K=128, phases 8..11 =========
  #pragma unroll
  for (int ct = 0; ct < 4; ++ct) {
    const float bv = hb2[ct*32 + cl];
    #pragma unroll
    for (int q = 0; q < 16; ++q) acc[ct][q] = bv;
  }
  #pragma unroll
  for (int p = 0; p < 4; ++p) {
    if (p < 3) STAGE_WG(wpackh, 32768 + (p+1)*4096, (p+1)&1);
    else       STAGE_WG(wpackh, 49152, 0);
    #pragma unroll
    for (int kcl = 0; kcl < 2; ++kcl) {
      const int kc = p*2 + kcl;
      const short8 a = *(const short8*)&afragH[ (wave*8 + kc)*512 + swz(lane, kc)*8 ];
      #pragma unroll
      for (int ct = 0; ct < 4; ++ct) {
        const short8 b = *(const short8*)&wg[p&1][ (kcl*4 + ct)*512 + lane*8 ];
        acc[ct] = __builtin_amdgcn_mfma_f32_32x32x16_bf16(a, b, acc[ct], 0, 0, 0);
      }
    }
    __syncthreads();
  }

  // ---- transition 2 (wave-local, tanh) -> afragH ----
  #pragma unroll
  for (int ct = 0; ct < 4; ++ct) {
    const int kc  = ct*2 + ((lane >> 4) & 1);
    const int oct = (lane >> 3) & 1;
    const int j   = lane & 7;
    const int xk  = (oct << 1) ^ ((kc & 1) << 2);
    const int hi  = 4*(lane >> 5);
    const int bi  = (wave*8 + kc)*512 + oct*256 + j;
    #pragma unroll
    for (int q = 0; q < 16; ++q) {
      const int m32 = (q & 3) + 8*(q >> 2) + hi;
      afragH[bi + (m32 ^ xk)*8] = f2b(fast_tanh(acc[ct][q]));
    }
  }

  // ========= hid layer 3: K=128, phases 12..15 =========
  #pragma unroll
  for (int ct = 0; ct < 4; ++ct) {
    const float bv = hb3[ct*32 + cl];
    #pragma unroll
    for (int q = 0; q < 16; ++q) acc[ct][q] = bv;
  }
  #pragma unroll
  for (int p = 0; p < 4; ++p) {
    if (p < 3) STAGE_WG(wpackh, 49152 + (p+1)*4096, (p+1)&1);
    else       STAGE_WG(wpackr, 0, 0);
    #pragma unroll
    for (int kcl = 0; kcl < 2; ++kcl) {
      const int kc = p*2 + kcl;
      const short8 a = *(const short8*)&afragH[ (wave*8 + kc)*512 + swz(lane, kc)*8 ];
      #pragma unroll
      for (int ct = 0; ct < 4; ++ct) {
        const short8 b = *(const short8*)&wg[p&1][ (kcl*4 + ct)*512 + lane*8 ];
        acc[ct] = __builtin_amdgcn_mfma_f32_32x32x16_bf16(a, b, acc[ct], 0, 0, 0);
      }
    }
    __syncthreads();
  }

  // ---- hid epilogue: global write + scatter (no tanh) -> afragH ----
  #pragma unroll
  for (int ct = 0; ct < 4; ++ct) {
    const int col = ct*32 + cl;
    #pragma unroll
    for (int q = 0; q < 16; ++q) {
      const int row = base + wave*32 + (q & 3) + 8*(q >> 2) + 4*khalf;
      if (row < nrows) hidden[(size_t)row*128 + col] = acc[ct][q];
    }
  }
  #pragma unroll
  for (int ct = 0; ct < 4; ++ct) {
    const int kc  = ct*2 + ((lane >> 4) & 1);
    const int oct = (lane >> 3) & 1;
    const int j   = lane & 7;
    const int xk  = (oct << 1) ^ ((kc & 1) << 2);
    const int hi  = 4*(lane >> 5);
    const int bi  = (wave*8 + kc)*512 + oct*256 + j;
    #pragma unroll
    for (int q = 0; q < 16; ++q) {
      const int m32 = (q & 3) + 8*(q >> 2) + hi;
      afragH[bi + (m32 ^ xk)*8] = f2b(acc[ct][q]);
    }
  }

  // radial A-fragments (per-lane)
  short8 aR[4];
  #pragma unroll
  for (int kc = 0; kc < 4; ++kc) aR[kc] = cvt8s(rsrc + kc*16 + khalf*8);

  // ========= rdl layer 1: K=192, phases 16..18 =========
  f32x16 racc0, racc1;
  {
    const float bv0 = rb1[cl], bv1 = rb1[32 + cl];
    #pragma unroll
    for (int q = 0; q < 16; ++q) { racc0[q] = bv0; racc1[q] = bv1; }
  }
  #pragma unroll
  for (int t = 0; t < 3; ++t) {
    if (t < 2) STAGE_WG(wpackr, (t+1)*4096, (t+1)&1);
    else       STAGE_WG(wpackr, 12288, 1);
    #pragma unroll
    for (int kk = 0; kk < 4; ++kk) {
      const int kc = t*4 + kk;
      const short8 a = (kc < 4) ? aR[kc]
        : *(const short8*)&afragH[ (wave*8 + (kc-4))*512 + swz(lane, kc-4)*8 ];
      const short8 w0 = *(const short8*)&wg[t&1][ (kk*2 + 0)*512 + lane*8 ];
      const short8 w1 = *(const short8*)&wg[t&1][ (kk*2 + 1)*512 + lane*8 ];
      racc0 = __builtin_amdgcn_mfma_f32_32x32x16_bf16(a, w0, racc0, 0, 0, 0);
      racc1 = __builtin_amdgcn_mfma_f32_32x32x16_bf16(a, w1, racc1, 0, 0, 0);
    }
    __syncthreads();
  }

  // ---- rdl transition 1 (tanh) -> afragH blocks 0..3 (wave-local) ----
  #pragma unroll
  for (int ct = 0; ct < 2; ++ct) {
    const int colh = ct*32 + cl;
    const int kc2  = colh >> 4;
    const int b3_  = (colh >> 3) & 1;
    const int jj   = colh & 7;
    const int blk  = (wave*8 + kc2)*512;
    #pragma unroll
    for (int q = 0; q < 16; ++q) {
      const int row32 = (q & 3) + 8*(q >> 2) + 4*khalf;
      const int s_ = (row32 & 31) + 32*b3_;
      const float v = ct ? racc1[q] : racc0[q];
      afragH[blk + swz(s_, kc2)*8 + jj] = f2b(fast_tanh(v));
    }
  }

  // ========= rdl layer 2: K=64 (phase 19, buf 1) =========
  f32x16 rh0, rh1;
  {
    const float bv0 = rb2[cl], bv1 = rb2[32 + cl];
    #pragma unroll
    for (int q = 0; q < 16; ++q) { rh0[q] = bv0; rh1[q] = bv1; }
  }
  STAGE_WG(wpackr, 16384, 0);
  #pragma unroll
  for (int kc = 0; kc < 4; ++kc) {
    const short8 a  = *(const short8*)&afragH[ (wave*8 + kc)*512 + swz(lane, kc)*8 ];
    const short8 w0 = *(const short8*)&wg[1][ (kc*2 + 0)*512 + lane*8 ];
    const short8 w1 = *(const short8*)&wg[1][ (kc*2 + 1)*512 + lane*8 ];
    rh0 = __builtin_amdgcn_mfma_f32_32x32x16_bf16(a, w0, rh0, 0, 0, 0);
    rh1 = __builtin_amdgcn_mfma_f32_32x32x16_bf16(a, w1, rh1, 0, 0, 0);
  }
  __syncthreads();

  // ---- rdl transition 2: tanh(h) -> afragH blocks 4..7 (wave-local) ----
  #pragma unroll
  for (int ct = 0; ct < 2; ++ct) {
    const int colh = ct*32 + cl;
    const int kc2  = colh >> 4;
    const int b3_  = (colh >> 3) & 1;
    const int jj   = colh & 7;
    const int blk  = (wave*8 + 4 + kc2)*512;
    #pragma unroll
    for (int q = 0; q < 16; ++q) {
      const int row32 = (q & 3) + 8*(q >> 2) + 4*khalf;
      const int s_ = (row32 & 31) + 32*b3_;
      const float v = ct ? rh1[q] : rh0[q];
      afragH[blk + swz(s_, kc2)*8 + jj] = f2b(fast_tanh(v));
    }
  }

  // ========= rdl layer 3: K=64 (phase 20, buf 0) =========
  {
    const float bv0 = rb3[cl], bv1 = rb3[32 + cl];
    #pragma unroll
    for (int q = 0; q < 16; ++q) { racc0[q] = bv0; racc1[q] = bv1; }
  }
  #pragma unroll
  for (int kc = 0; kc < 4; ++kc) {
    const short8 a  = *(const short8*)&afragH[ (wave*8 + 4 + kc)*512 + swz(lane, kc)*8 ];
    const short8 w0 = *(const short8*)&wg[0][ (kc*2 + 0)*512 + lane*8 ];
    const short8 w1 = *(const short8*)&wg[0][ (kc*2 + 1)*512 + lane*8 ];
    racc0 = __builtin_amdgcn_mfma_f32_32x32x16_bf16(a, w0, racc0, 0, 0, 0);
    racc1 = __builtin_amdgcn_mfma_f32_32x32x16_bf16(a, w1, racc1, 0, 0, 0);
  }

  // ---- rdl epilogue: +h, LN (shfl butterfly), residual-scale, store ----
  const float eg0 = eln_g[cl],      eb0 = eln_b[cl];
  const float eg1 = eln_g[32 + cl], eb1 = eln_b[32 + cl];
  const float* rtile = radial + (size_t)(base + wave*32) * 64;

  #pragma unroll
  for (int q = 0; q < 16; ++q) {
    const float v0 = racc0[q] + rh0[q];
    const float v1 = racc1[q] + rh1[q];
    float s = v0 + v1, ss = v0*v0 + v1*v1;
    #pragma unroll
    for (int o = 1; o <= 16; o <<= 1) {
      s  += __shfl_xor(s, o);
      ss += __shfl_xor(ss, o);
    }
    const float m   = s * (1.0f/64.0f);
    const float inv = rsqrtf(ss * (1.0f/64.0f) - m*m + LN_EPS);
    const int row32 = (q & 3) + 8*(q >> 2) + 4*khalf;
    const int row   = base + wave*32 + row32;
    if (row < nrows) {
      const float u = ud[row];
      const float oldA = rtile[row32*64 + cl];
      const float oldB = rtile[row32*64 + 32 + cl];
      radial[(size_t)row*64 + cl]      = C_RES*oldA + C_NEW*u*((v0 - m)*inv*eg0 + eb0);
      radial[(size_t)row*64 + 32 + cl] = C_RES*oldB + C_NEW*u*((v1 - m)*inv*eg1 + eb1);
    }
  }
}

// ---------------- launch -----------------------------------------------------

extern "C" void kernel_launch(void* const* d_in, const int* in_sizes, int n_in,
                              void* d_out, int out_size, void* d_ws, size_t ws_size,
                              hipStream_t stream)
{
  const int*   atom_types = (const int*)  d_in[0];
  const float* env_vec    = (const float*)d_in[1];
  const float* env_len    = (const float*)d_in[2];
  const float* edge_len   = (const float*)d_in[3];
  const int*   env_idx    = (const int*)  d_in[4];
  const int*   edge_idx   = (const int*)  d_in[5];
  const float* bessel_w   = (const float*)d_in[6];
  const float* srW1 = (const float*)d_in[7];  const float* srb1 = (const float*)d_in[8];
  const float* srW2 = (const float*)d_in[9];  const float* srb2 = (const float*)d_in[10];
  const float* srW3 = (const float*)d_in[11]; const float* srb3 = (const float*)d_in[12];
  const float* rdW1 = (const float*)d_in[13]; const float* rdb1 = (const float*)d_in[14];
  const float* rdW2 = (const float*)d_in[15]; const float* rdb2 = (const float*)d_in[16];
  const float* rdW3 = (const float*)d_in[17]; const float* rdb3 = (const float*)d_in[18];
  const float* ne_emb_W = (const float*)d_in[19]; const float* ne_emb_b = (const float*)d_in[20];
  const float* ne_nln_g = (const float*)d_in[21]; const float* ne_nln_b = (const float*)d_in[22];
  const float* ne_eln_g = (const float*)d_in[23]; const float* ne_eln_b = (const float*)d_in[24];
  const float* ly_emb_W = (const float*)d_in[25]; const float* ly_emb_b = (const float*)d_in[26];
  const float* ly_hid_W1 = (const float*)d_in[27]; const float* ly_hid_b1 = (const float*)d_in[28];
  const float* ly_hid_W2 = (const float*)d_in[29]; const float* ly_hid_b2 = (const float*)d_in[30];
  const float* ly_hid_W3 = (const float*)d_in[31]; const float* ly_hid_b3 = (const float*)d_in[32];
  const float* ly_rdl_W1 = (const float*)d_in[33]; const float* ly_rdl_b1 = (const float*)d_in[34];
  const float* ly_rdl_W2 = (const float*)d_in[35]; const float* ly_rdl_b2 = (const float*)d_in[36];
  const float* ly_rdl_W3 = (const float*)d_in[37]; const float* ly_rdl_b3 = (const float*)d_in[38];
  const float* ly_nln_g = (const float*)d_in[39]; const float* ly_nln_b = (const float*)d_in[40];
  const float* ly_eln_g = (const float*)d_in[41]; const float* ly_eln_b = (const float*)d_in[42];

  const int N  = in_sizes[0];
  const int E  = in_sizes[2];
  const int E2 = in_sizes[3];

  float* out = (float*)d_out;
  float* env_radial  = out;
  float* edge_radial = env_radial + (size_t)E * 64;
  float* node_emb    = edge_radial + (size_t)E2 * 64;
  float* env_hidden  = node_emb + (size_t)N * 128;
  float* edge_hidden = env_hidden + (size_t)E * 128;

  float* ws = (float*)d_ws;
  float* ud_env  = ws;  ws += E;
  float* ud_edge = ws;  ws += E2;
  float* aggS    = ws;  ws += (size_t)N * 48;
  float* msgbuf  = ws;  ws += (size_t)E * 20;   // sval[16] | evud[3] | pad
  float* mean_r  = msgbuf;                      // reuse after msg_gather
  unsigned short* wpack  = (unsigned short*)ws; ws += 65536;   // hid: 2 x 65536 u16
  unsigned short* wpack2 = (unsigned short*)ws; ws += 20480;   // rdl: 2 x 20480 u16
  unsigned short* wpack3 = (unsigned short*)ws; ws += 9216;    // feat: 18432 u16
  unsigned short* wpackE = (unsigned short*)ws; ws += 4096;    // emb: 8192 u16
  int* ecnt = (int*)ws; ws += N;
  int* eoff = (int*)ws; ws += N + 1;
  int* ecur = (int*)ws; ws += N + 1;
  int* perm = (int*)ws; ws += E;

  const int gEr  = (E  + 95) / 96;
  const int gE2r = (E2 + 95) / 96;
  const int gEf  = (E  + 127) / 128;
  const int gE2f = (E2 + 127) / 128;
  const int gN32 = (N + 31) / 32;
  const int gN4w = (N * 64 + 255) / 256;

  // CSR build over env graph (i1 = env_idx[1])
  zero_int_kernel<<<256, 256, 0, stream>>>(ecnt, N);
  hist_kernel<<<(E + 255) / 256, 256, 0, stream>>>(E, env_idx, ecnt);
  scan_kernel<<<1, 1024, 0, stream>>>(ecnt, eoff, ecur, N);
  scatter_kernel<<<(E + 255) / 256, 256, 0, stream>>>(E, env_idx, ecur, perm);

  pack_hid_weights<<<512, 256, 0, stream>>>(ly_hid_W1, ly_hid_W2, ly_hid_W3, wpack);
  pack_rdl_weights<<<160, 256, 0, stream>>>(ly_rdl_W1, ly_rdl_W2, ly_rdl_W3, wpack2);
  pack_feat_weights<<<72, 256, 0, stream>>>(rdW1, rdW2, rdW3, srW1, srW2, srW3, wpack3);
  pack_emb_weights<<<32, 256, 0, stream>>>(ne_emb_W, wpackE);

  feat_mfma<1><<<gEr, 192, 0, stream>>>(E, atom_types, env_len, env_vec, env_idx, bessel_w,
      wpack3, srb1, srb2, srb3, rdb1, rdb2, rdb3,
      ne_eln_g, ne_eln_b, env_radial, ud_env, msgbuf);
  feat_mfma<0><<<gE2r, 192, 0, stream>>>(E2, atom_types, edge_len, nullptr, edge_idx, bessel_w,
      wpack3, srb1, srb2, srb3, rdb1, rdb2, rdb3,
      ne_eln_g, ne_eln_b, edge_radial, ud_edge, nullptr);

  msg_gather_kernel<<<gN4w, 256, 0, stream>>>(N, eoff, perm, msgbuf, aggS);
  node_emb_kernel<<<N, 128, 0, stream>>>(N, aggS, ecnt, ne_nln_g, ne_nln_b, node_emb);

  emb_mfma<<<gEr, 192, 0, stream>>>(E, env_radial, wpackE, ne_emb_b, env_idx, node_emb, env_hidden);
  emb_mfma<<<gE2r, 192, 0, stream>>>(E2, edge_radial, wpackE, ne_emb_b, edge_idx, node_emb, edge_hidden);

  for (int l = 0; l < 2; ++l) {
    agg_gather_kernel<<<gN4w, 256, 0, stream>>>(N, eoff, perm, env_radial, mean_r);
    node_update_gemm<<<gN32, 256, 0, stream>>>(N, mean_r, ecnt,
        ly_emb_W + (size_t)l*64*128, ly_emb_b + (size_t)l*128,
        ly_nln_g + (size_t)l*128, ly_nln_b + (size_t)l*128, node_emb);

    hidrdl_mfma<<<gEf, 256, 0, stream>>>(E, env_idx, node_emb, ud_env,
        wpack + (size_t)l*65536,
        ly_hid_b1 + (size_t)l*128, ly_hid_b2 + (size_t)l*128, ly_hid_b3 + (size_t)l*128,
        wpack2 + (size_t)l*20480,
        ly_rdl_b1 + (size_t)l*64, ly_rdl_b2 + (size_t)l*64, ly_rdl_b3 + (size_t)l*64,
        ly_eln_g + (size_t)l*64, ly_eln_b + (size_t)l*64,
        env_hidden, env_radial);
    hidrdl_mfma<<<gE2f, 256, 0, stream>>>(E2, edge_idx, node_emb, ud_edge,
        wpack + (size_t)l*65536,
        ly_hid_b1 + (size_t)l*128, ly_hid_b2 + (size_t)l*128, ly_hid_b3 + (size_t)l*128,
        wpack2 + (size_t)l*20480,
        ly_rdl_b1 + (size_t)l*64, ly_rdl_b2 + (size_t)l*64, ly_rdl_b3 + (size_t)l*64,
        ly_eln_g + (size_t)l*64, ly_eln_b + (size_t)l*64,
        edge_hidden, edge_radial);
  }
}